// Round 2
// baseline (4370.607 us; speedup 1.0000x reference)
//
#include <hip/hip_runtime.h>
#include <hip/hip_bf16.h>

typedef __hip_bfloat16 bf16;
typedef unsigned short u16;
typedef unsigned int u32;

// ======== dtype policy: reference is pure float32 -> all I/O fp32 ========
typedef float IN_T;    // flip to bf16 if harness proves otherwise
typedef float OUT_T;

constexpr int N_ = 2, H_ = 96, W_ = 96, HW_ = H_ * W_;
constexpr int CIN_ = 256, CH_ = 64, C2_ = 128;
constexpr int K9_ = 9, K2_ = 49;   // dcn taps, ncf taps
constexpr int PIX = 8;             // pixels per dcn block

__device__ __forceinline__ float ldf(const float* p) { return *p; }
__device__ __forceinline__ float ldf(const bf16* p) { return __bfloat162float(*p); }
__device__ __forceinline__ void stf(float* p, float v) { *p = v; }
__device__ __forceinline__ void stf(bf16* p, float v) { *p = __float2bfloat16(v); }
__device__ __forceinline__ float sigm(float v) { return 1.0f / (1.0f + __expf(-v)); }

// ---------------- generic direct 3x3 SAME conv ----------------
template <typename TIN, typename TOUT, int IC, int OC>
__global__ __launch_bounds__(256) void conv3x3(const TIN* __restrict__ in,
                                               const IN_T* __restrict__ w,
                                               const IN_T* __restrict__ b,
                                               TOUT* __restrict__ out) {
    int idx = blockIdx.x * 256 + threadIdx.x;
    if (idx >= N_ * OC * HW_) return;
    int x = idx % W_;
    int y = (idx / W_) % H_;
    int oc = (idx / HW_) % OC;
    int n = idx / (HW_ * OC);
    const TIN* inp = in + (size_t)n * IC * HW_;
    const IN_T* wr = w + (size_t)oc * IC * 9;
    float acc = ldf(b + oc);
    for (int ic = 0; ic < IC; ++ic) {
        const TIN* ip = inp + (size_t)ic * HW_;
        const IN_T* wp = wr + ic * 9;
#pragma unroll
        for (int ky = 0; ky < 3; ++ky) {
            int yy = y + ky - 1;
            if (yy < 0 || yy >= H_) continue;
            const TIN* rp = ip + yy * W_;
#pragma unroll
            for (int kx = 0; kx < 3; ++kx) {
                int xx = x + kx - 1;
                if (xx < 0 || xx >= W_) continue;
                acc += ldf(rp + xx) * ldf(wp + ky * 3 + kx);
            }
        }
    }
    stf(out + idx, acc);
}

// ---------------- concat 64+64 -> 128 channels ----------------
__global__ __launch_bounds__(256) void concat2(const float* __restrict__ A, const float* __restrict__ B,
                                               float* __restrict__ dst) {
    int idx = blockIdx.x * 256 + threadIdx.x;
    if (idx >= N_ * C2_ * HW_) return;
    int r = idx % HW_;
    int c = (idx / HW_) % C2_;
    int n = idx / (HW_ * C2_);
    float v = (c < CH_) ? A[((size_t)n * CH_ + c) * HW_ + r]
                        : B[((size_t)n * CH_ + (c - CH_)) * HW_ + r];
    dst[idx] = v;
}

// ---------------- fused deformable conv main ----------------
// tx: (N,128,H,W) f32   om: (N,27,H,W) f32 raw offsets/mask-logits
// w: (64, 128*9) layout (o, c*9+k)   b: (64)   out: (N,64,H,W) f32 pre-activation
__global__ __launch_bounds__(256) void dcn_main(const float* __restrict__ tx,
                                                const float* __restrict__ om,
                                                const IN_T* __restrict__ w,
                                                const IN_T* __restrict__ b,
                                                float* __restrict__ out) {
    __shared__ __align__(16) float samp[PIX][C2_ * K9_];   // [p][c*9+k]  36864 B
    __shared__ float s_wy[PIX * K9_], s_wx[PIX * K9_], s_mask[PIX * K9_];
    __shared__ int s_y0[PIX * K9_], s_x0[PIX * K9_];
    __shared__ __align__(16) float red[256 * PIX];          // 8192 B

    int t = threadIdx.x;
    int pixbase = blockIdx.x * PIX;          // linear over N*HW, never crosses a row (96%8==0)
    int n = pixbase / HW_;
    int pb = pixbase % HW_;
    int y = pb / W_, x0p = pb % W_;
    const float* txn = tx + (size_t)n * C2_ * HW_;
    const float* omn = om + (size_t)n * 27 * HW_;

    // phase 0: per-(pixel,tap) sampling coords + mask
    if (t < PIX * K9_) {
        int p = t / K9_, k = t % K9_;
        int xx = x0p + p;
        int po = y * W_ + xx;
        float dy = omn[k * HW_ + po];
        float dx = omn[(K9_ + k) * HW_ + po];
        float m = sigm(omn[(2 * K9_ + k) * HW_ + po]);
        float py = (float)y + (float)(k / 3 - 1) + dy;
        float px = (float)xx + (float)(k % 3 - 1) + dx;
        float fy = floorf(py), fx = floorf(px);
        s_y0[t] = (int)fy;
        s_x0[t] = (int)fx;
        s_wy[t] = py - fy;
        s_wx[t] = px - fx;
        s_mask[t] = m;
    }
    __syncthreads();

    // phase 1: bilinear gather 8*1152 samples into LDS
    for (int it = 0; it < (PIX * C2_ * K9_) / 256; ++it) {
        int s = it * 256 + t;                // p*1152 + k*128 + c
        int p = s / (C2_ * K9_);
        int rem = s % (C2_ * K9_);
        int k = rem / C2_;
        int c = rem % C2_;
        int pk = p * K9_ + k;
        int y0 = s_y0[pk], x0 = s_x0[pk];
        float wy = s_wy[pk], wx = s_wx[pk], m = s_mask[pk];
        const float* ch = txn + (size_t)c * HW_;
        bool yv0 = (y0 >= 0) & (y0 < H_);
        bool yv1 = (y0 + 1 >= 0) & (y0 + 1 < H_);
        bool xv0 = (x0 >= 0) & (x0 < W_);
        bool xv1 = (x0 + 1 >= 0) & (x0 + 1 < W_);
        float v00 = (yv0 && xv0) ? ch[y0 * W_ + x0] : 0.f;
        float v01 = (yv0 && xv1) ? ch[y0 * W_ + x0 + 1] : 0.f;
        float v10 = (yv1 && xv0) ? ch[(y0 + 1) * W_ + x0] : 0.f;
        float v11 = (yv1 && xv1) ? ch[(y0 + 1) * W_ + x0 + 1] : 0.f;
        float v = (v00 * (1.f - wy) * (1.f - wx) + v01 * (1.f - wy) * wx +
                   v10 * wy * (1.f - wx) + v11 * wy * wx) * m;
        samp[p][c * K9_ + k] = v;
    }
    __syncthreads();

    // phase 2: per-pixel 64x1152 matvec; thread = (o, slice of 288 j's)
    int o = t & 63, slice = t >> 6;
    int jbase = slice * 288;
    const IN_T* wr = w + (size_t)o * (C2_ * K9_) + jbase;
    float acc[PIX];
#pragma unroll
    for (int p = 0; p < PIX; ++p) acc[p] = 0.f;
    for (int j4 = 0; j4 < 288; j4 += 4) {
        float4 wq = *reinterpret_cast<const float4*>(wr + j4);
        int jj = jbase + j4;
#pragma unroll
        for (int p = 0; p < PIX; ++p) {
            float4 sv = *reinterpret_cast<const float4*>(&samp[p][jj]);
            acc[p] += wq.x * sv.x + wq.y * sv.y + wq.z * sv.z + wq.w * sv.w;
        }
    }
#pragma unroll
    for (int p = 0; p < PIX; ++p) red[t * PIX + p] = acc[p];
    __syncthreads();
    if (t < 64) {
        float bias = ldf(b + t);
#pragma unroll
        for (int p = 0; p < PIX; ++p) {
            float s = bias;
#pragma unroll
            for (int sl = 0; sl < 4; ++sl) s += red[(sl * 64 + t) * PIX + p];
            out[((size_t)n * CH_ + t) * HW_ + y * W_ + x0p + p] = s;
        }
    }
}

// ---------------- ncf: correlation ----------------
__global__ __launch_bounds__(256) void ncf_corr(const float* __restrict__ f1, const float* __restrict__ f2,
                                                float* __restrict__ corr) {
    int idx = blockIdx.x * 256 + threadIdx.x;
    if (idx >= N_ * K2_ * HW_) return;
    int x = idx % W_;
    int y = (idx / W_) % H_;
    int k = (idx / HW_) % K2_;
    int n = idx / (HW_ * K2_);
    int oy = (k / 7) * 2 - 6, ox = (k % 7) * 2 - 6;
    int yy = y + oy, xx = x + ox;
    float s = 0.f;
    if (yy >= 0 && yy < H_ && xx >= 0 && xx < W_) {
        const float* a = f1 + (size_t)n * CH_ * HW_ + y * W_ + x;
        const float* c2 = f2 + (size_t)n * CH_ * HW_ + yy * W_ + xx;
        for (int c = 0; c < CH_; ++c) s += a[(size_t)c * HW_] * c2[(size_t)c * HW_];
    }
    corr[idx] = s * 0.125f;
}

// ---------------- ncf: softmax over 49 taps, in place ----------------
__global__ __launch_bounds__(256) void softmax49(float* __restrict__ corr) {
    int idx = blockIdx.x * 256 + threadIdx.x;
    if (idx >= N_ * HW_) return;
    int r = idx % HW_;
    int n = idx / HW_;
    float* base = corr + (size_t)n * K2_ * HW_ + r;
    float mx = -1e30f;
    for (int k = 0; k < K2_; ++k) mx = fmaxf(mx, base[(size_t)k * HW_]);
    float sum = 0.f;
    float e[K2_];
#pragma unroll
    for (int k = 0; k < K2_; ++k) { e[k] = __expf(base[(size_t)k * HW_] - mx); sum += e[k]; }
    float inv = 1.f / sum;
#pragma unroll
    for (int k = 0; k < K2_; ++k) base[(size_t)k * HW_] = e[k] * inv;
}

// ---------------- ncf: attn-weighted sample ----------------
__global__ __launch_bounds__(256) void ncf_sample(const float* __restrict__ attn, const float* __restrict__ f2,
                                                  float* __restrict__ out) {
    int idx = blockIdx.x * 256 + threadIdx.x;
    if (idx >= N_ * CH_ * HW_) return;
    int x = idx % W_;
    int y = (idx / W_) % H_;
    int c = (idx / HW_) % CH_;
    int n = idx / (HW_ * CH_);
    const float* ap = attn + (size_t)n * K2_ * HW_ + y * W_ + x;
    const float* fp = f2 + ((size_t)n * CH_ + c) * HW_;
    float s = 0.f;
    for (int k = 0; k < K2_; ++k) {
        int oy = (k / 7) * 2 - 6, ox = (k % 7) * 2 - 6;
        int yy = y + oy, xx = x + ox;
        if (yy >= 0 && yy < H_ && xx >= 0 && xx < W_)
            s += ap[(size_t)k * HW_] * fp[yy * W_ + xx];
    }
    out[idx] = s;
}

// ---------------- GRU gate: out = (1-sig(z))*t + sig(z)*tanh(h) ----------------
template <typename TOUT>
__global__ __launch_bounds__(256) void gatek(const float* __restrict__ zpre, const float* __restrict__ hpre,
                                             const float* __restrict__ t, TOUT* __restrict__ dst) {
    int idx = blockIdx.x * 256 + threadIdx.x;
    if (idx >= N_ * CH_ * HW_) return;
    float z = sigm(zpre[idx]);
    float xt = tanhf(hpre[idx]);
    stf(dst + idx, (1.f - z) * t[idx] + z * xt);
}

extern "C" void kernel_launch(void* const* d_in, const int* in_sizes, int n_in,
                              void* d_out, int out_size, void* d_ws, size_t ws_size,
                              hipStream_t stream) {
    const IN_T* x     = (const IN_T*)d_in[0];
    const IN_T* tpl   = (const IN_T*)d_in[1];
    const IN_T* w_in  = (const IN_T*)d_in[2];
    const IN_T* b_in  = (const IN_T*)d_in[3];
    const IN_T* w_out = (const IN_T*)d_in[4];
    const IN_T* b_out = (const IN_T*)d_in[5];
    const IN_T *pw[4], *pb[4], *pow_[4], *pob[4];
    for (int i = 0; i < 4; ++i) {           // 0=enh_z 1=enh_h 2=upd_z 3=upd_h
        pw[i]   = (const IN_T*)d_in[6 + 4 * i];
        pb[i]   = (const IN_T*)d_in[7 + 4 * i];
        pow_[i] = (const IN_T*)d_in[8 + 4 * i];
        pob[i]  = (const IN_T*)d_in[9 + 4 * i];
    }
    OUT_T* out_main = (OUT_T*)d_out;
    OUT_T* out_ntpl = out_main + (size_t)N_ * CIN_ * HW_;

    float* ws = (float*)d_ws;
    size_t off = 0;
    float* xh  = ws + off; off += (size_t)N_ * CH_ * HW_;
    float* xe  = ws + off; off += (size_t)N_ * CH_ * HW_;
    float* tx  = ws + off; off += (size_t)N_ * C2_ * HW_;
    float* om  = ws + off; off += (size_t)N_ * 27 * HW_;
    float* dz  = ws + off; off += (size_t)N_ * CH_ * HW_;
    float* dh  = ws + off; off += (size_t)N_ * CH_ * HW_;
    float* rb  = ws + off; off += (size_t)N_ * CH_ * HW_;
    float* at  = ws + off; off += (size_t)N_ * K2_ * HW_;

    auto stargru = [&](const float* x32, const float* tt, int zi, int hi, auto* dst) {
        concat2<<<9216, 256, 0, stream>>>(x32, tt, tx);
        conv3x3<float, float, C2_, 27><<<1944, 256, 0, stream>>>(tx, pow_[zi], pob[zi], om);
        dcn_main<<<(N_ * HW_) / PIX, 256, 0, stream>>>(tx, om, pw[zi], pb[zi], dz);
        ncf_corr<<<3528, 256, 0, stream>>>(tt, x32, at);
        softmax49<<<72, 256, 0, stream>>>(at);
        ncf_sample<<<4608, 256, 0, stream>>>(at, x32, rb);
        concat2<<<9216, 256, 0, stream>>>(rb, tt, tx);
        conv3x3<float, float, C2_, 27><<<1944, 256, 0, stream>>>(tx, pow_[hi], pob[hi], om);
        dcn_main<<<(N_ * HW_) / PIX, 256, 0, stream>>>(tx, om, pw[hi], pb[hi], dh);
        gatek<<<4608, 256, 0, stream>>>(dz, dh, tt, dst);
    };

    conv3x3<IN_T, float, CIN_, CH_><<<4608, 256, 0, stream>>>(x, w_in, b_in, xh);
    stargru(tpl, xh, 0, 1, xe);              // x_enh = stargru(template, xh, enh_*)
    stargru(xh, tpl, 2, 3, out_ntpl);        // new_template = stargru(xh, template, upd_*)
    conv3x3<float, OUT_T, CH_, CIN_><<<18432, 256, 0, stream>>>(xe, w_out, b_out, out_main);
}

// Round 4
// 1295.048 us; speedup vs baseline: 3.3749x; 3.3749x over previous
//
#include <hip/hip_runtime.h>
#include <hip/hip_bf16.h>

typedef __hip_bfloat16 bf16;
typedef unsigned short u16;
typedef unsigned int u32;
typedef __attribute__((ext_vector_type(8))) short short8;
typedef __attribute__((ext_vector_type(4))) float floatx4;

constexpr int N_ = 2, H_ = 96, W_ = 96, HW_ = H_ * W_;
constexpr int CIN_ = 256, CH_ = 64, C2_ = 128;
constexpr int K2_ = 49;

__device__ __forceinline__ float sigm(float v) { return 1.0f / (1.0f + __expf(-v)); }
__device__ __forceinline__ short f2b(float v) { bf16 h = __float2bfloat16(v); return *reinterpret_cast<short*>(&h); }

// ---------- bf16 weight regions inside d_ws ----------
constexpr int A_IN_OFF = 0,                         A_IN_SZ  = 64 * 2304;
constexpr int A_OUT_OFF = A_IN_OFF + A_IN_SZ,       A_OUT_SZ = 256 * 576;
constexpr int A_OFF_OFF = A_OUT_OFF + A_OUT_SZ,     A_OFF_SZ = 32 * 1152;   // 27 padded to 32
constexpr int A_DCN_OFF = A_OFF_OFF + 4 * A_OFF_SZ, A_DCN_SZ = 64 * 1152;
constexpr int A_TOT = A_DCN_OFF + 4 * A_DCN_SZ;     // 737280 shorts = 1.47 MB

// weight converter: fp32 -> bf16, permuted.
// conv-style A[m][k= tap*IC + ic] = W[m][ic][tap];  dcn A[m][k = c*9+tap] = natural
__global__ __launch_bounds__(256) void cvt_weights(
        const float* __restrict__ w_in, const float* __restrict__ w_out,
        const float* __restrict__ ow0, const float* __restrict__ ow1,
        const float* __restrict__ ow2, const float* __restrict__ ow3,
        const float* __restrict__ w0, const float* __restrict__ w1,
        const float* __restrict__ w2, const float* __restrict__ w3,
        u16* __restrict__ dst) {
    int id = blockIdx.x * 256 + threadIdx.x;
    if (id >= A_TOT) return;
    float v;
    if (id < A_OUT_OFF) {
        int l = id; int m = l / 2304, k = l % 2304; int tap = k >> 8, ic = k & 255;
        v = w_in[m * 2304 + ic * 9 + tap];
    } else if (id < A_OFF_OFF) {
        int l = id - A_OUT_OFF; int m = l / 576, k = l % 576; int tap = k / 64, ic = k & 63;
        v = w_out[m * 576 + ic * 9 + tap];
    } else if (id < A_DCN_OFF) {
        int l = id - A_OFF_OFF; int i = l / A_OFF_SZ, l2 = l % A_OFF_SZ;
        int m = l2 / 1152, k = l2 % 1152; int tap = k >> 7, ic = k & 127;
        const float* s = (i == 0) ? ow0 : (i == 1) ? ow1 : (i == 2) ? ow2 : ow3;
        v = (m < 27) ? s[m * 1152 + ic * 9 + tap] : 0.f;
    } else {
        int l = id - A_DCN_OFF; int i = l / A_DCN_SZ, l2 = l % A_DCN_SZ;
        const float* s = (i == 0) ? w0 : (i == 1) ? w1 : (i == 2) ? w2 : w3;
        v = s[l2];
    }
    u16 b; short sb = f2b(v); b = *reinterpret_cast<u16*>(&sb);
    dst[id] = b;
}

// ---------- implicit-GEMM 3x3 SAME conv, bf16 MFMA 16x16x32 ----------
template <int IC, int BM, int OCST>
__global__ __launch_bounds__(256) void conv_gemm(const float* __restrict__ X,
                                                 const u16* __restrict__ A,
                                                 const float* __restrict__ bias,
                                                 float* __restrict__ out) {
    constexpr int K = IC * 9;
    constexpr int MFR = BM / 32;
    constexpr int ICC = IC / 64;
    __shared__ __align__(16) u16 Al[BM][72];
    __shared__ __align__(16) u16 Bl[96][72];
    int t = threadIdx.x;
    int bx = blockIdx.x;
    int r = bx % 192, mt = bx / 192;
    int n = r / 96, y = r % 96;
    int w = t >> 6, lane = t & 63, lm = lane & 15, q = lane >> 4;
    int wr = w >> 1, wc = w & 1;
    int mbase = wr * (BM / 2), nbase = wc * 48;
    floatx4 acc[MFR][3];
#pragma unroll
    for (int a = 0; a < MFR; ++a)
#pragma unroll
        for (int b = 0; b < 3; ++b) acc[a][b] = {0.f, 0.f, 0.f, 0.f};

    for (int tap = 0; tap < 9; ++tap) {
        int ky = tap / 3 - 1, kx = tap % 3 - 1;
        int yy = y + ky;
        bool vrow = (yy >= 0) && (yy < 96);
        for (int icc = 0; icc < ICC; ++icc) {
            __syncthreads();
            // stage A: BM x 64 bf16
            const u16* Ag = A + (size_t)(mt * BM) * K + tap * IC + icc * 64;
#pragma unroll
            for (int i = 0; i < BM / 32; ++i) {
                int c0 = t + i * 256;
                int row = c0 >> 3, cb = c0 & 7;
                short8 vv = *reinterpret_cast<const short8*>(Ag + (size_t)row * K + cb * 8);
                *reinterpret_cast<short8*>(&Al[row][cb * 8]) = vv;
            }
            // stage B: 96 px x 64 k
            const float* Xb = X + ((size_t)(n * IC + icc * 64)) * HW_;
#pragma unroll
            for (int i = 0; i < 3; ++i) {
                int c0 = t + i * 256;
                int x = c0 % 96, kb8 = c0 / 96;
                int xx = x + kx;
                bool v = vrow && (xx >= 0) && (xx < 96);
                short8 vv;
#pragma unroll
                for (int j = 0; j < 8; ++j) {
                    float f = v ? Xb[(size_t)(kb8 * 8 + j) * HW_ + yy * 96 + xx] : 0.f;
                    vv[j] = f2b(f);
                }
                *reinterpret_cast<short8*>(&Bl[x][kb8 * 8]) = vv;
            }
            __syncthreads();
#pragma unroll
            for (int ks = 0; ks < 2; ++ks) {
                short8 af[MFR], bfv[3];
#pragma unroll
                for (int mf = 0; mf < MFR; ++mf)
                    af[mf] = *reinterpret_cast<const short8*>(&Al[mbase + mf * 16 + lm][ks * 32 + q * 8]);
#pragma unroll
                for (int nf = 0; nf < 3; ++nf)
                    bfv[nf] = *reinterpret_cast<const short8*>(&Bl[nbase + nf * 16 + lm][ks * 32 + q * 8]);
#pragma unroll
                for (int mf = 0; mf < MFR; ++mf)
#pragma unroll
                    for (int nf = 0; nf < 3; ++nf)
                        acc[mf][nf] = __builtin_amdgcn_mfma_f32_16x16x32_bf16(af[mf], bfv[nf], acc[mf][nf], 0, 0, 0);
            }
        }
    }
#pragma unroll
    for (int mf = 0; mf < MFR; ++mf) {
        int row0 = mt * BM + mbase + mf * 16 + q * 4;
#pragma unroll
        for (int nf = 0; nf < 3; ++nf) {
            int x = nbase + nf * 16 + lm;
#pragma unroll
            for (int rr = 0; rr < 4; ++rr) {
                int row = row0 + rr;
                if (row < OCST)
                    out[((size_t)(n * OCST + row)) * HW_ + y * 96 + x] = acc[mf][nf][rr] + bias[row];
            }
        }
    }
}

// ---------- fused deformable conv: bilinear-gather staging + MFMA GEMM ----------
__global__ __launch_bounds__(256) void dcn_gemm(const float* __restrict__ tx,
                                                const float* __restrict__ om,
                                                const u16* __restrict__ A,
                                                const float* __restrict__ bias,
                                                float* __restrict__ out) {
    constexpr int K = 1152;
    __shared__ __align__(16) u16 Al[64][72];
    __shared__ __align__(16) u16 Bl[96][72];
    __shared__ float s_wy[864], s_wx[864], s_m[864];
    __shared__ int s_y0[864], s_x0[864];
    int t = threadIdx.x;
    int r = blockIdx.x;
    int n = r / 96, y = r % 96;
    for (int e = t; e < 864; e += 256) {
        int k9 = e / 96, x = e % 96;
        const float* ob = om + (size_t)n * 27 * HW_ + y * 96 + x;
        float dy = ob[(size_t)k9 * HW_];
        float dx = ob[(size_t)(9 + k9) * HW_];
        float ml = ob[(size_t)(18 + k9) * HW_];
        float py = (float)y + (float)(k9 / 3 - 1) + dy;
        float px = (float)x + (float)(k9 % 3 - 1) + dx;
        float fy = floorf(py), fx = floorf(px);
        s_y0[e] = (int)fy; s_x0[e] = (int)fx;
        s_wy[e] = py - fy; s_wx[e] = px - fx; s_m[e] = sigm(ml);
    }
    int w = t >> 6, lane = t & 63, lm = lane & 15, q = lane >> 4;
    int wr = w >> 1, wc = w & 1;
    int mbase = wr * 32, nbase = wc * 48;
    floatx4 acc[2][3];
#pragma unroll
    for (int a = 0; a < 2; ++a)
#pragma unroll
        for (int b = 0; b < 3; ++b) acc[a][b] = {0.f, 0.f, 0.f, 0.f};
    const float* txn = tx + (size_t)n * C2_ * HW_;

    for (int kc = 0; kc < 18; ++kc) {
        __syncthreads();
#pragma unroll
        for (int i = 0; i < 2; ++i) {
            int c0 = t + i * 256;
            int row = c0 >> 3, cb = c0 & 7;
            short8 vv = *reinterpret_cast<const short8*>(A + (size_t)row * K + kc * 64 + cb * 8);
            *reinterpret_cast<short8*>(&Al[row][cb * 8]) = vv;
        }
#pragma unroll
        for (int i = 0; i < 3; ++i) {
            int c0 = t + i * 256;
            int x = c0 % 96, kb8 = c0 / 96;
            short8 vv;
#pragma unroll
            for (int j = 0; j < 8; ++j) {
                int kg = kc * 64 + kb8 * 8 + j;
                int c = kg / 9, k9 = kg - c * 9;
                int ce = k9 * 96 + x;
                int y0 = s_y0[ce], x0 = s_x0[ce];
                float wy = s_wy[ce], wx = s_wx[ce], m = s_m[ce];
                const float* ch = txn + (size_t)c * HW_;
                bool yv0 = (y0 >= 0) & (y0 < 96), yv1 = (y0 >= -1) & (y0 < 95);
                bool xv0 = (x0 >= 0) & (x0 < 96), xv1 = (x0 >= -1) & (x0 < 95);
                float v00 = (yv0 && xv0) ? ch[y0 * 96 + x0] : 0.f;
                float v01 = (yv0 && xv1) ? ch[y0 * 96 + x0 + 1] : 0.f;
                float v10 = (yv1 && xv0) ? ch[(y0 + 1) * 96 + x0] : 0.f;
                float v11 = (yv1 && xv1) ? ch[(y0 + 1) * 96 + x0 + 1] : 0.f;
                float val = (v00 * (1.f - wy) * (1.f - wx) + v01 * (1.f - wy) * wx +
                             v10 * wy * (1.f - wx) + v11 * wy * wx) * m;
                vv[j] = f2b(val);
            }
            *reinterpret_cast<short8*>(&Bl[x][kb8 * 8]) = vv;
        }
        __syncthreads();
#pragma unroll
        for (int ks = 0; ks < 2; ++ks) {
            short8 af[2], bfv[3];
#pragma unroll
            for (int mf = 0; mf < 2; ++mf)
                af[mf] = *reinterpret_cast<const short8*>(&Al[mbase + mf * 16 + lm][ks * 32 + q * 8]);
#pragma unroll
            for (int nf = 0; nf < 3; ++nf)
                bfv[nf] = *reinterpret_cast<const short8*>(&Bl[nbase + nf * 16 + lm][ks * 32 + q * 8]);
#pragma unroll
            for (int mf = 0; mf < 2; ++mf)
#pragma unroll
                for (int nf = 0; nf < 3; ++nf)
                    acc[mf][nf] = __builtin_amdgcn_mfma_f32_16x16x32_bf16(af[mf], bfv[nf], acc[mf][nf], 0, 0, 0);
        }
    }
#pragma unroll
    for (int mf = 0; mf < 2; ++mf) {
        int row0 = mbase + mf * 16 + q * 4;
#pragma unroll
        for (int nf = 0; nf < 3; ++nf) {
            int x = nbase + nf * 16 + lm;
#pragma unroll
            for (int rr = 0; rr < 4; ++rr) {
                int row = row0 + rr;
                out[((size_t)(n * CH_ + row)) * HW_ + y * 96 + x] = acc[mf][nf][rr] + bias[row];
            }
        }
    }
}

// ---------------- concat 64+64 -> 128 channels ----------------
__global__ __launch_bounds__(256) void concat2(const float* __restrict__ A, const float* __restrict__ B,
                                               float* __restrict__ dst) {
    int idx = blockIdx.x * 256 + threadIdx.x;
    if (idx >= N_ * C2_ * HW_) return;
    int r = idx % HW_;
    int c = (idx / HW_) % C2_;
    int n = idx / (HW_ * C2_);
    float v = (c < CH_) ? A[((size_t)n * CH_ + c) * HW_ + r]
                        : B[((size_t)n * CH_ + (c - CH_)) * HW_ + r];
    dst[idx] = v;
}

// ---------------- ncf: correlation ----------------
__global__ __launch_bounds__(256) void ncf_corr(const float* __restrict__ f1, const float* __restrict__ f2,
                                                float* __restrict__ corr) {
    int idx = blockIdx.x * 256 + threadIdx.x;
    if (idx >= N_ * K2_ * HW_) return;
    int x = idx % W_;
    int y = (idx / W_) % H_;
    int k = (idx / HW_) % K2_;
    int n = idx / (HW_ * K2_);
    int oy = (k / 7) * 2 - 6, ox = (k % 7) * 2 - 6;
    int yy = y + oy, xx = x + ox;
    float s = 0.f;
    if (yy >= 0 && yy < H_ && xx >= 0 && xx < W_) {
        const float* a = f1 + (size_t)n * CH_ * HW_ + y * W_ + x;
        const float* c2 = f2 + (size_t)n * CH_ * HW_ + yy * W_ + xx;
        for (int c = 0; c < CH_; ++c) s += a[(size_t)c * HW_] * c2[(size_t)c * HW_];
    }
    corr[idx] = s * 0.125f;
}

// ---------------- ncf: softmax over 49 taps, in place ----------------
__global__ __launch_bounds__(256) void softmax49(float* __restrict__ corr) {
    int idx = blockIdx.x * 256 + threadIdx.x;
    if (idx >= N_ * HW_) return;
    int r = idx % HW_;
    int n = idx / HW_;
    float* base = corr + (size_t)n * K2_ * HW_ + r;
    float mx = -1e30f;
    for (int k = 0; k < K2_; ++k) mx = fmaxf(mx, base[(size_t)k * HW_]);
    float sum = 0.f;
    float e[K2_];
#pragma unroll
    for (int k = 0; k < K2_; ++k) { e[k] = __expf(base[(size_t)k * HW_] - mx); sum += e[k]; }
    float inv = 1.f / sum;
#pragma unroll
    for (int k = 0; k < K2_; ++k) base[(size_t)k * HW_] = e[k] * inv;
}

// ---------------- ncf: attn-weighted sample ----------------
__global__ __launch_bounds__(256) void ncf_sample(const float* __restrict__ attn, const float* __restrict__ f2,
                                                  float* __restrict__ out) {
    int idx = blockIdx.x * 256 + threadIdx.x;
    if (idx >= N_ * CH_ * HW_) return;
    int x = idx % W_;
    int y = (idx / W_) % H_;
    int c = (idx / HW_) % CH_;
    int n = idx / (HW_ * CH_);
    const float* ap = attn + (size_t)n * K2_ * HW_ + y * W_ + x;
    const float* fp = f2 + ((size_t)n * CH_ + c) * HW_;
    float s = 0.f;
    for (int k = 0; k < K2_; ++k) {
        int oy = (k / 7) * 2 - 6, ox = (k % 7) * 2 - 6;
        int yy = y + oy, xx = x + ox;
        if (yy >= 0 && yy < H_ && xx >= 0 && xx < W_)
            s += ap[(size_t)k * HW_] * fp[yy * W_ + xx];
    }
    out[idx] = s;
}

// ---------------- GRU gate ----------------
__global__ __launch_bounds__(256) void gatek(const float* __restrict__ zpre, const float* __restrict__ hpre,
                                             const float* __restrict__ t, float* __restrict__ dst) {
    int idx = blockIdx.x * 256 + threadIdx.x;
    if (idx >= N_ * CH_ * HW_) return;
    float z = sigm(zpre[idx]);
    float xt = tanhf(hpre[idx]);
    dst[idx] = (1.f - z) * t[idx] + z * xt;
}

extern "C" void kernel_launch(void* const* d_in, const int* in_sizes, int n_in,
                              void* d_out, int out_size, void* d_ws, size_t ws_size,
                              hipStream_t stream) {
    const float* x     = (const float*)d_in[0];
    const float* tpl   = (const float*)d_in[1];
    const float* w_in  = (const float*)d_in[2];
    const float* b_in  = (const float*)d_in[3];
    const float* w_out = (const float*)d_in[4];
    const float* b_out = (const float*)d_in[5];
    const float *pw[4], *pb[4], *pow_[4], *pob[4];
    for (int i = 0; i < 4; ++i) {           // 0=enh_z 1=enh_h 2=upd_z 3=upd_h
        pw[i]   = (const float*)d_in[6 + 4 * i];
        pb[i]   = (const float*)d_in[7 + 4 * i];
        pow_[i] = (const float*)d_in[8 + 4 * i];
        pob[i]  = (const float*)d_in[9 + 4 * i];
    }
    float* out_main = (float*)d_out;
    float* out_ntpl = out_main + (size_t)N_ * CIN_ * HW_;

    // ---- workspace layout (31.9 MB total; round-2-proven bound was 38.6 MB) ----
    u16* Aws = (u16*)d_ws;
    float* fws = (float*)((char*)d_ws + (size_t)A_TOT * 2);
    size_t off = 0;
    float* xh   = fws + off; off += (size_t)N_ * CH_ * HW_;
    float* xe   = fws + off; off += (size_t)N_ * CH_ * HW_;
    float* tx   = fws + off; off += (size_t)N_ * C2_ * HW_;
    float* omat = fws + off; off += (size_t)N_ * K2_ * HW_;   // om (27ch) and at (49ch) alias
    float* dz   = fws + off; off += (size_t)N_ * CH_ * HW_;
    float* dhrb = fws + off; off += (size_t)N_ * CH_ * HW_;   // rb and dh alias

    cvt_weights<<<(A_TOT + 255) / 256, 256, 0, stream>>>(
        w_in, w_out, pow_[0], pow_[1], pow_[2], pow_[3], pw[0], pw[1], pw[2], pw[3], Aws);

    auto stargru = [&](const float* x32, const float* tt, int zi, int hi, float* dst) {
        float* om = omat;
        float* at = omat;
        float* rb = dhrb;
        float* dh = dhrb;
        concat2<<<9216, 256, 0, stream>>>(x32, tt, tx);
        conv_gemm<C2_, 32, 27><<<192, 256, 0, stream>>>(tx, Aws + A_OFF_OFF + zi * A_OFF_SZ, pob[zi], om);
        dcn_gemm<<<192, 256, 0, stream>>>(tx, om, Aws + A_DCN_OFF + zi * A_DCN_SZ, pb[zi], dz);
        ncf_corr<<<3528, 256, 0, stream>>>(tt, x32, at);       // om dead from here
        softmax49<<<72, 256, 0, stream>>>(at);
        ncf_sample<<<4608, 256, 0, stream>>>(at, x32, rb);
        concat2<<<9216, 256, 0, stream>>>(rb, tt, tx);
        conv_gemm<C2_, 32, 27><<<192, 256, 0, stream>>>(tx, Aws + A_OFF_OFF + hi * A_OFF_SZ, pob[hi], om);  // at dead
        dcn_gemm<<<192, 256, 0, stream>>>(tx, om, Aws + A_DCN_OFF + hi * A_DCN_SZ, pb[hi], dh);             // rb dead
        gatek<<<4608, 256, 0, stream>>>(dz, dh, tt, dst);
    };

    conv_gemm<CIN_, 64, 64><<<192, 256, 0, stream>>>(x, Aws + A_IN_OFF, b_in, xh);
    stargru(tpl, xh, 0, 1, xe);              // x_enh
    stargru(xh, tpl, 2, 3, out_ntpl);        // new_template
    conv_gemm<CH_, 128, 256><<<384, 256, 0, stream>>>(xe, Aws + A_OUT_OFF, b_out, out_main);
}

// Round 5
// 1083.850 us; speedup vs baseline: 4.0325x; 1.1949x over previous
//
#include <hip/hip_runtime.h>
#include <hip/hip_bf16.h>

typedef __hip_bfloat16 bf16;
typedef unsigned short u16;
typedef unsigned int u32;
typedef __attribute__((ext_vector_type(8))) short short8;
typedef __attribute__((ext_vector_type(4))) float floatx4;

constexpr int N_ = 2, H_ = 96, W_ = 96, HW_ = H_ * W_;
constexpr int CIN_ = 256, CH_ = 64, C2_ = 128;
constexpr int K2_ = 49;

__device__ __forceinline__ float sigm(float v) { return 1.0f / (1.0f + __expf(-v)); }
__device__ __forceinline__ short f2b(float v) { bf16 h = __float2bfloat16(v); return *reinterpret_cast<short*>(&h); }

// ---------- bf16 weight regions inside d_ws ----------
// conv-style A[m][k= tap*IC + ic];  dcn A[m][k = c*9+tap] (natural)
constexpr int A_IN_OFF = 0,                         A_IN_SZ  = 64 * 2304;
constexpr int A_OUT_OFF = A_IN_OFF + A_IN_SZ,       A_OUT_SZ = 256 * 576;
constexpr int A_OFF_OFF = A_OUT_OFF + A_OUT_SZ,     A_OFF_SZ = 64 * 1152;   // 27 padded to 64
constexpr int A_DCN_OFF = A_OFF_OFF + 4 * A_OFF_SZ, A_DCN_SZ = 64 * 1152;
constexpr int A_TOT = A_DCN_OFF + 4 * A_DCN_SZ;     // 884736 shorts = 1.77 MB

__global__ __launch_bounds__(256) void cvt_weights(
        const float* __restrict__ w_in, const float* __restrict__ w_out,
        const float* __restrict__ ow0, const float* __restrict__ ow1,
        const float* __restrict__ ow2, const float* __restrict__ ow3,
        const float* __restrict__ w0, const float* __restrict__ w1,
        const float* __restrict__ w2, const float* __restrict__ w3,
        u16* __restrict__ dst) {
    int id = blockIdx.x * 256 + threadIdx.x;
    if (id >= A_TOT) return;
    float v;
    if (id < A_OUT_OFF) {
        int l = id; int m = l / 2304, k = l % 2304; int tap = k >> 8, ic = k & 255;
        v = w_in[m * 2304 + ic * 9 + tap];
    } else if (id < A_OFF_OFF) {
        int l = id - A_OUT_OFF; int m = l / 576, k = l % 576; int tap = k / 64, ic = k & 63;
        v = w_out[m * 576 + ic * 9 + tap];
    } else if (id < A_DCN_OFF) {
        int l = id - A_OFF_OFF; int i = l / A_OFF_SZ, l2 = l % A_OFF_SZ;
        int m = l2 / 1152, k = l2 % 1152; int tap = k >> 7, ic = k & 127;
        const float* s = (i == 0) ? ow0 : (i == 1) ? ow1 : (i == 2) ? ow2 : ow3;
        v = (m < 27) ? s[m * 1152 + ic * 9 + tap] : 0.f;
    } else {
        int l = id - A_DCN_OFF; int i = l / A_DCN_SZ, l2 = l % A_DCN_SZ;
        const float* s = (i == 0) ? w0 : (i == 1) ? w1 : (i == 2) ? w2 : w3;
        v = s[l2];
    }
    short sb = f2b(v);
    dst[id] = *reinterpret_cast<u16*>(&sb);
}

// ---------- implicit-GEMM 3x3 SAME conv v2 ----------
// block = 64 oc x 48 px; 4 waves m-stacked (wave = 16 oc x 48 px).
// Per 64-ch chunk: stage 3 rows x 50 px window in LDS ONCE, reuse for 9 taps.
// A-fragments read straight from global (L2) into registers.
template <int IC, int OCP, int OCST>
__global__ __launch_bounds__(256) void conv_gemm(const float* __restrict__ X,
                                                 const u16* __restrict__ A,
                                                 const float* __restrict__ bias,
                                                 float* __restrict__ out) {
    constexpr int K = IC * 9;
    constexpr int ICC = IC / 64;
    __shared__ __align__(16) u16 Xl[3][50][72];   // [row][px(-1..48)][ch, pitch72]
    int t = threadIdx.x;
    int gx = blockIdx.x;
    int mt = gx / 384;
    int r = gx % 384;
    int n = r / 192;
    int rr = r % 192;
    int y = rr >> 1, px0 = (rr & 1) * 48;
    int w = t >> 6, lane = t & 63, lm = lane & 15, q = lane >> 4;
    const u16* Arow = A + (size_t)(mt * 64 + w * 16 + lm) * K + q * 8;
    floatx4 acc[3];
#pragma unroll
    for (int a = 0; a < 3; ++a) acc[a] = {0.f, 0.f, 0.f, 0.f};

    for (int icc = 0; icc < ICC; ++icc) {
        // A fragments: 9 taps x 2 k-steps, global 16B loads (latency overlaps staging)
        short8 af[9][2];
#pragma unroll
        for (int tap = 0; tap < 9; ++tap)
#pragma unroll
            for (int ks = 0; ks < 2; ++ks)
                af[tap][ks] = *reinterpret_cast<const short8*>(Arow + tap * IC + icc * 64 + ks * 32);
        __syncthreads();   // protect Xl reuse from previous chunk
        // stage 3x50x64 fp32->bf16 window
#pragma unroll
        for (int it = 0; it < 5; ++it) {
            int id = it * 256 + t;
            if (id < 1200) {
                int ch8 = id & 7;
                int tmp = id >> 3;
                int pxl = tmp % 50, row = tmp / 50;
                int xg = px0 - 1 + pxl;
                int yg = y - 1 + row;
                bool vld = (yg >= 0) && (yg < 96) && (xg >= 0) && (xg < 96);
                const float* base = X + ((size_t)(n * IC + icc * 64 + ch8 * 8)) * HW_ + yg * 96 + xg;
                short8 vv;
#pragma unroll
                for (int j = 0; j < 8; ++j) vv[j] = vld ? f2b(base[(size_t)j * HW_]) : (short)0;
                *reinterpret_cast<short8*>(&Xl[row][pxl][ch8 * 8]) = vv;
            }
        }
        __syncthreads();
        // 9 taps: pure LDS->MFMA
#pragma unroll
        for (int tap = 0; tap < 9; ++tap) {
            int ky = tap / 3, kx = tap % 3;
#pragma unroll
            for (int ks = 0; ks < 2; ++ks) {
#pragma unroll
                for (int nf = 0; nf < 3; ++nf) {
                    short8 bv = *reinterpret_cast<const short8*>(&Xl[ky][nf * 16 + lm + kx][ks * 32 + q * 8]);
                    acc[nf] = __builtin_amdgcn_mfma_f32_16x16x32_bf16(af[tap][ks], bv, acc[nf], 0, 0, 0);
                }
            }
        }
    }
    int ocb = mt * 64 + w * 16 + q * 4;
#pragma unroll
    for (int nf = 0; nf < 3; ++nf) {
        int px = px0 + nf * 16 + lm;
#pragma unroll
        for (int rr2 = 0; rr2 < 4; ++rr2) {
            int oc = ocb + rr2;
            if (oc < OCST)
                out[((size_t)(n * OCST + oc)) * HW_ + y * 96 + px] = acc[nf][rr2] + bias[oc];
        }
    }
}

// ---------- fused deformable conv v2: 48-px blocks, grid 384 ----------
__global__ __launch_bounds__(256) void dcn_gemm(const float* __restrict__ tx,
                                                const float* __restrict__ om,
                                                const u16* __restrict__ A,
                                                const float* __restrict__ bias,
                                                float* __restrict__ out) {
    __shared__ __align__(16) u16 Bl[48][72];
    __shared__ float s_wy[432], s_wx[432], s_m[432];
    __shared__ int s_y0[432], s_x0[432];
    int t = threadIdx.x;
    int r = blockIdx.x;
    int n = r / 192;
    int rr = r % 192;
    int y = rr >> 1, px0 = (rr & 1) * 48;
    // coords/mask per (tap, xl)
    for (int e = t; e < 432; e += 256) {
        int k9 = e / 48, xl = e % 48;
        int x = px0 + xl;
        const float* ob = om + (size_t)n * 27 * HW_ + y * 96 + x;
        float dy = ob[(size_t)k9 * HW_];
        float dx = ob[(size_t)(9 + k9) * HW_];
        float ml = ob[(size_t)(18 + k9) * HW_];
        float py = (float)y + (float)(k9 / 3 - 1) + dy;
        float px = (float)x + (float)(k9 % 3 - 1) + dx;
        float fy = floorf(py), fx = floorf(px);
        s_y0[e] = (int)fy; s_x0[e] = (int)fx;
        s_wy[e] = py - fy; s_wx[e] = px - fx; s_m[e] = sigm(ml);
    }
    int w = t >> 6, lane = t & 63, lm = lane & 15, q = lane >> 4;
    const u16* Arow = A + (size_t)(w * 16 + lm) * 1152 + q * 8;
    floatx4 acc[3];
#pragma unroll
    for (int a = 0; a < 3; ++a) acc[a] = {0.f, 0.f, 0.f, 0.f};
    const float* txn = tx + (size_t)n * C2_ * HW_;

    for (int kc = 0; kc < 18; ++kc) {
        short8 af[2];
#pragma unroll
        for (int ks = 0; ks < 2; ++ks)
            af[ks] = *reinterpret_cast<const short8*>(Arow + kc * 64 + ks * 32);
        __syncthreads();   // protect Bl reuse + (first iter) coord writes
#pragma unroll
        for (int i = 0; i < 2; ++i) {
            int id = i * 256 + t;
            if (id < 384) {
                int ch8 = id & 7, px = id >> 3;
                short8 vv;
#pragma unroll
                for (int j = 0; j < 8; ++j) {
                    int kg = kc * 64 + ch8 * 8 + j;
                    int c = kg / 9, k9 = kg - c * 9;
                    int ce = k9 * 48 + px;
                    int y0 = s_y0[ce], x0 = s_x0[ce];
                    float wy = s_wy[ce], wx = s_wx[ce], m = s_m[ce];
                    const float* ch = txn + (size_t)c * HW_;
                    bool yv0 = (y0 >= 0) & (y0 < 96), yv1 = (y0 >= -1) & (y0 < 95);
                    bool xv0 = (x0 >= 0) & (x0 < 96), xv1 = (x0 >= -1) & (x0 < 95);
                    float v00 = (yv0 && xv0) ? ch[y0 * 96 + x0] : 0.f;
                    float v01 = (yv0 && xv1) ? ch[y0 * 96 + x0 + 1] : 0.f;
                    float v10 = (yv1 && xv0) ? ch[(y0 + 1) * 96 + x0] : 0.f;
                    float v11 = (yv1 && xv1) ? ch[(y0 + 1) * 96 + x0 + 1] : 0.f;
                    float val = (v00 * (1.f - wy) * (1.f - wx) + v01 * (1.f - wy) * wx +
                                 v10 * wy * (1.f - wx) + v11 * wy * wx) * m;
                    vv[j] = f2b(val);
                }
                *reinterpret_cast<short8*>(&Bl[px][ch8 * 8]) = vv;
            }
        }
        __syncthreads();
#pragma unroll
        for (int ks = 0; ks < 2; ++ks)
#pragma unroll
            for (int nf = 0; nf < 3; ++nf) {
                short8 bv = *reinterpret_cast<const short8*>(&Bl[nf * 16 + lm][ks * 32 + q * 8]);
                acc[nf] = __builtin_amdgcn_mfma_f32_16x16x32_bf16(af[ks], bv, acc[nf], 0, 0, 0);
            }
    }
    int ocb = w * 16 + q * 4;
#pragma unroll
    for (int nf = 0; nf < 3; ++nf) {
        int px = px0 + nf * 16 + lm;
#pragma unroll
        for (int rr2 = 0; rr2 < 4; ++rr2) {
            int oc = ocb + rr2;
            out[((size_t)(n * CH_ + oc)) * HW_ + y * 96 + px] = acc[nf][rr2] + bias[oc];
        }
    }
}

// ---------------- concat 64+64 -> 128 channels ----------------
__global__ __launch_bounds__(256) void concat2(const float* __restrict__ A, const float* __restrict__ B,
                                               float* __restrict__ dst) {
    int idx = blockIdx.x * 256 + threadIdx.x;
    if (idx >= N_ * C2_ * HW_) return;
    int r = idx % HW_;
    int c = (idx / HW_) % C2_;
    int n = idx / (HW_ * C2_);
    float v = (c < CH_) ? A[((size_t)n * CH_ + c) * HW_ + r]
                        : B[((size_t)n * CH_ + (c - CH_)) * HW_ + r];
    dst[idx] = v;
}

// ---------------- ncf: correlation ----------------
__global__ __launch_bounds__(256) void ncf_corr(const float* __restrict__ f1, const float* __restrict__ f2,
                                                float* __restrict__ corr) {
    int idx = blockIdx.x * 256 + threadIdx.x;
    if (idx >= N_ * K2_ * HW_) return;
    int x = idx % W_;
    int y = (idx / W_) % H_;
    int k = (idx / HW_) % K2_;
    int n = idx / (HW_ * K2_);
    int oy = (k / 7) * 2 - 6, ox = (k % 7) * 2 - 6;
    int yy = y + oy, xx = x + ox;
    float s = 0.f;
    if (yy >= 0 && yy < H_ && xx >= 0 && xx < W_) {
        const float* a = f1 + (size_t)n * CH_ * HW_ + y * W_ + x;
        const float* c2 = f2 + (size_t)n * CH_ * HW_ + yy * W_ + xx;
        for (int c = 0; c < CH_; ++c) s += a[(size_t)c * HW_] * c2[(size_t)c * HW_];
    }
    corr[idx] = s * 0.125f;
}

// ---------------- ncf: softmax over 49 taps, in place ----------------
__global__ __launch_bounds__(256) void softmax49(float* __restrict__ corr) {
    int idx = blockIdx.x * 256 + threadIdx.x;
    if (idx >= N_ * HW_) return;
    int r = idx % HW_;
    int n = idx / HW_;
    float* base = corr + (size_t)n * K2_ * HW_ + r;
    float mx = -1e30f;
    for (int k = 0; k < K2_; ++k) mx = fmaxf(mx, base[(size_t)k * HW_]);
    float sum = 0.f;
    float e[K2_];
#pragma unroll
    for (int k = 0; k < K2_; ++k) { e[k] = __expf(base[(size_t)k * HW_] - mx); sum += e[k]; }
    float inv = 1.f / sum;
#pragma unroll
    for (int k = 0; k < K2_; ++k) base[(size_t)k * HW_] = e[k] * inv;
}

// ---------------- ncf: attn-weighted sample ----------------
__global__ __launch_bounds__(256) void ncf_sample(const float* __restrict__ attn, const float* __restrict__ f2,
                                                  float* __restrict__ out) {
    int idx = blockIdx.x * 256 + threadIdx.x;
    if (idx >= N_ * CH_ * HW_) return;
    int x = idx % W_;
    int y = (idx / W_) % H_;
    int c = (idx / HW_) % CH_;
    int n = idx / (HW_ * CH_);
    const float* ap = attn + (size_t)n * K2_ * HW_ + y * W_ + x;
    const float* fp = f2 + ((size_t)n * CH_ + c) * HW_;
    float s = 0.f;
    for (int k = 0; k < K2_; ++k) {
        int oy = (k / 7) * 2 - 6, ox = (k % 7) * 2 - 6;
        int yy = y + oy, xx = x + ox;
        if (yy >= 0 && yy < H_ && xx >= 0 && xx < W_)
            s += ap[(size_t)k * HW_] * fp[yy * W_ + xx];
    }
    out[idx] = s;
}

// ---------------- GRU gate ----------------
__global__ __launch_bounds__(256) void gatek(const float* __restrict__ zpre, const float* __restrict__ hpre,
                                             const float* __restrict__ t, float* __restrict__ dst) {
    int idx = blockIdx.x * 256 + threadIdx.x;
    if (idx >= N_ * CH_ * HW_) return;
    float z = sigm(zpre[idx]);
    float xt = tanhf(hpre[idx]);
    dst[idx] = (1.f - z) * t[idx] + z * xt;
}

extern "C" void kernel_launch(void* const* d_in, const int* in_sizes, int n_in,
                              void* d_out, int out_size, void* d_ws, size_t ws_size,
                              hipStream_t stream) {
    const float* x     = (const float*)d_in[0];
    const float* tpl   = (const float*)d_in[1];
    const float* w_in  = (const float*)d_in[2];
    const float* b_in  = (const float*)d_in[3];
    const float* w_out = (const float*)d_in[4];
    const float* b_out = (const float*)d_in[5];
    const float *pw[4], *pb[4], *pow_[4], *pob[4];
    for (int i = 0; i < 4; ++i) {           // 0=enh_z 1=enh_h 2=upd_z 3=upd_h
        pw[i]   = (const float*)d_in[6 + 4 * i];
        pb[i]   = (const float*)d_in[7 + 4 * i];
        pow_[i] = (const float*)d_in[8 + 4 * i];
        pob[i]  = (const float*)d_in[9 + 4 * i];
    }
    float* out_main = (float*)d_out;
    float* out_ntpl = out_main + (size_t)N_ * CIN_ * HW_;

    // ---- workspace layout (~32 MB; round-2-proven bound was 38.6 MB) ----
    u16* Aws = (u16*)d_ws;
    float* fws = (float*)((char*)d_ws + (size_t)A_TOT * 2);
    size_t off = 0;
    float* xh   = fws + off; off += (size_t)N_ * CH_ * HW_;
    float* xe   = fws + off; off += (size_t)N_ * CH_ * HW_;
    float* tx   = fws + off; off += (size_t)N_ * C2_ * HW_;
    float* omat = fws + off; off += (size_t)N_ * K2_ * HW_;   // om (27ch) / at (49ch) alias
    float* dz   = fws + off; off += (size_t)N_ * CH_ * HW_;
    float* dhrb = fws + off; off += (size_t)N_ * CH_ * HW_;   // rb / dh alias

    cvt_weights<<<(A_TOT + 255) / 256, 256, 0, stream>>>(
        w_in, w_out, pow_[0], pow_[1], pow_[2], pow_[3], pw[0], pw[1], pw[2], pw[3], Aws);

    auto stargru = [&](const float* x32, const float* tt, int zi, int hi, float* dst) {
        float* om = omat;
        float* at = omat;
        float* rb = dhrb;
        float* dh = dhrb;
        concat2<<<9216, 256, 0, stream>>>(x32, tt, tx);
        conv_gemm<C2_, 64, 27><<<384, 256, 0, stream>>>(tx, Aws + A_OFF_OFF + zi * A_OFF_SZ, pob[zi], om);
        dcn_gemm<<<384, 256, 0, stream>>>(tx, om, Aws + A_DCN_OFF + zi * A_DCN_SZ, pb[zi], dz);
        ncf_corr<<<3528, 256, 0, stream>>>(tt, x32, at);       // om dead from here
        softmax49<<<72, 256, 0, stream>>>(at);
        ncf_sample<<<4608, 256, 0, stream>>>(at, x32, rb);
        concat2<<<9216, 256, 0, stream>>>(rb, tt, tx);
        conv_gemm<C2_, 64, 27><<<384, 256, 0, stream>>>(tx, Aws + A_OFF_OFF + hi * A_OFF_SZ, pob[hi], om);  // at dead
        dcn_gemm<<<384, 256, 0, stream>>>(tx, om, Aws + A_DCN_OFF + hi * A_DCN_SZ, pb[hi], dh);             // rb dead
        gatek<<<4608, 256, 0, stream>>>(dz, dh, tt, dst);
    };

    conv_gemm<CIN_, 64, 64><<<384, 256, 0, stream>>>(x, Aws + A_IN_OFF, b_in, xh);
    stargru(tpl, xh, 0, 1, xe);              // x_enh
    stargru(xh, tpl, 2, 3, out_ntpl);        // new_template
    conv_gemm<CH_, 256, 256><<<1536, 256, 0, stream>>>(xe, Aws + A_OUT_OFF, b_out, out_main);
}

// Round 6
// 570.311 us; speedup vs baseline: 7.6636x; 1.9005x over previous
//
#include <hip/hip_runtime.h>
#include <hip/hip_bf16.h>

typedef __hip_bfloat16 bf16;
typedef unsigned short u16;
typedef unsigned int u32;
typedef __attribute__((ext_vector_type(8))) short short8;
typedef __attribute__((ext_vector_type(4))) float floatx4;

constexpr int N_ = 2, H_ = 96, W_ = 96, HW_ = H_ * W_;
constexpr int CIN_ = 256, CH_ = 64, C2_ = 128;
constexpr int K2_ = 49;

__device__ __forceinline__ float sigm(float v) { return 1.0f / (1.0f + __expf(-v)); }
__device__ __forceinline__ short f2b(float v) { bf16 h = __float2bfloat16(v); return *reinterpret_cast<short*>(&h); }
__device__ __forceinline__ float b2f(short s) {
    union { u32 i; float f; } v; v.i = ((u32)(u16)s) << 16; return v.f;
}

// ---------- bf16 weight regions inside d_ws ----------
// conv A[m][k = tap*IC + ic];  dcn A[m][k = tap*128 + c]  (both tap-major)
constexpr int A_IN_OFF = 0,                         A_IN_SZ  = 64 * 2304;
constexpr int A_OUT_OFF = A_IN_OFF + A_IN_SZ,       A_OUT_SZ = 256 * 576;
constexpr int A_OFF_OFF = A_OUT_OFF + A_OUT_SZ,     A_OFF_SZ = 64 * 1152;   // 27 padded to 64
constexpr int A_DCN_OFF = A_OFF_OFF + 4 * A_OFF_SZ, A_DCN_SZ = 64 * 1152;
constexpr int A_TOT = A_DCN_OFF + 4 * A_DCN_SZ;     // 884736 shorts = 1.77 MB

__global__ __launch_bounds__(256) void cvt_weights(
        const float* __restrict__ w_in, const float* __restrict__ w_out,
        const float* __restrict__ ow0, const float* __restrict__ ow1,
        const float* __restrict__ ow2, const float* __restrict__ ow3,
        const float* __restrict__ w0, const float* __restrict__ w1,
        const float* __restrict__ w2, const float* __restrict__ w3,
        u16* __restrict__ dst) {
    int id = blockIdx.x * 256 + threadIdx.x;
    if (id >= A_TOT) return;
    float v;
    if (id < A_OUT_OFF) {
        int l = id; int m = l / 2304, k = l % 2304; int tap = k >> 8, ic = k & 255;
        v = w_in[m * 2304 + ic * 9 + tap];
    } else if (id < A_OFF_OFF) {
        int l = id - A_OUT_OFF; int m = l / 576, k = l % 576; int tap = k / 64, ic = k & 63;
        v = w_out[m * 576 + ic * 9 + tap];
    } else if (id < A_DCN_OFF) {
        int l = id - A_OFF_OFF; int i = l / A_OFF_SZ, l2 = l % A_OFF_SZ;
        int m = l2 / 1152, k = l2 % 1152; int tap = k >> 7, ic = k & 127;
        const float* s = (i == 0) ? ow0 : (i == 1) ? ow1 : (i == 2) ? ow2 : ow3;
        v = (m < 27) ? s[m * 1152 + ic * 9 + tap] : 0.f;
    } else {
        // dcn: tap-major K: A[m][tap*128+c] = w[m][c*9+tap]
        int l = id - A_DCN_OFF; int i = l / A_DCN_SZ, l2 = l % A_DCN_SZ;
        int m = l2 / 1152, k = l2 % 1152; int tap = k >> 7, c = k & 127;
        const float* s = (i == 0) ? w0 : (i == 1) ? w1 : (i == 2) ? w2 : w3;
        v = s[m * 1152 + c * 9 + tap];
    }
    short sb = f2b(v);
    dst[id] = *reinterpret_cast<u16*>(&sb);
}

// ---------- NCHW f32 -> NHWC bf16 ----------
__global__ __launch_bounds__(256) void to_nhwc(const float* __restrict__ src, u16* __restrict__ dst, int C) {
    int id = blockIdx.x * 256 + threadIdx.x;
    int c8n = C >> 3;
    if (id >= N_ * HW_ * c8n) return;
    int c8 = id % c8n;
    int pix = id / c8n;
    int n = pix / HW_, p = pix % HW_;
    const float* s = src + ((size_t)n * C + c8 * 8) * HW_ + p;
    short8 vv;
#pragma unroll
    for (int j = 0; j < 8; ++j) vv[j] = f2b(s[(size_t)j * HW_]);
    *reinterpret_cast<short8*>(dst + (size_t)pix * C + c8 * 8) = vv;
}

// ---------- concat two NCHW f32 (64ch each) -> NHWC bf16 128ch ----------
__global__ __launch_bounds__(256) void concat_nhwc(const float* __restrict__ A, const float* __restrict__ B,
                                                   u16* __restrict__ dst) {
    int id = blockIdx.x * 256 + threadIdx.x;
    if (id >= N_ * HW_ * 16) return;
    int c8 = id & 15;
    int pix = id >> 4;
    int n = pix / HW_, p = pix % HW_;
    int c = c8 * 8;
    const float* s = (c < 64) ? A + ((size_t)n * 64 + c) * HW_ + p
                              : B + ((size_t)n * 64 + (c - 64)) * HW_ + p;
    short8 vv;
#pragma unroll
    for (int j = 0; j < 8; ++j) vv[j] = f2b(s[(size_t)j * HW_]);
    *reinterpret_cast<short8*>(dst + (size_t)pix * 128 + c) = vv;
}

// ---------- implicit-GEMM 3x3 SAME conv, NHWC bf16 input, NCHW f32 out ----------
// block = 64 oc x 48 px, 4 waves m-stacked. Staging = pure bf16 copy.
template <int IC, int OCST>
__global__ __launch_bounds__(256) void conv_gemm(const u16* __restrict__ X,
                                                 const u16* __restrict__ A,
                                                 const float* __restrict__ bias,
                                                 float* __restrict__ out) {
    constexpr int K = IC * 9;
    constexpr int ICC = IC / 64;
    __shared__ __align__(16) u16 Xl[3][50][72];   // [row][px(-1..48)][ch]
    int t = threadIdx.x;
    int gx = blockIdx.x;
    int mt = gx / 384;
    int r = gx % 384;
    int n = r / 192;
    int rr = r % 192;
    int y = rr >> 1, px0 = (rr & 1) * 48;
    int w = t >> 6, lane = t & 63, lm = lane & 15, q = lane >> 4;
    const u16* Arow = A + (size_t)(mt * 64 + w * 16 + lm) * K + q * 8;
    floatx4 acc[3];
#pragma unroll
    for (int a = 0; a < 3; ++a) acc[a] = {0.f, 0.f, 0.f, 0.f};
    const short8 zz = {0, 0, 0, 0, 0, 0, 0, 0};

    for (int icc = 0; icc < ICC; ++icc) {
        short8 af[9][2];
#pragma unroll
        for (int tap = 0; tap < 9; ++tap)
#pragma unroll
            for (int ks = 0; ks < 2; ++ks)
                af[tap][ks] = *reinterpret_cast<const short8*>(Arow + tap * IC + icc * 64 + ks * 32);
        __syncthreads();
#pragma unroll
        for (int it = 0; it < 5; ++it) {
            int id = it * 256 + t;
            if (id < 1200) {
                int ch8 = id & 7;
                int tmp = id >> 3;
                int pxl = tmp % 50, row = tmp / 50;
                int xg = px0 - 1 + pxl;
                int yg = y - 1 + row;
                bool vld = (yg >= 0) && (yg < 96) && (xg >= 0) && (xg < 96);
                short8 vv = zz;
                if (vld)
                    vv = *reinterpret_cast<const short8*>(
                        X + ((size_t)(n * HW_ + yg * 96 + xg)) * IC + icc * 64 + ch8 * 8);
                *reinterpret_cast<short8*>(&Xl[row][pxl][ch8 * 8]) = vv;
            }
        }
        __syncthreads();
#pragma unroll
        for (int tap = 0; tap < 9; ++tap) {
            int ky = tap / 3, kx = tap % 3;
#pragma unroll
            for (int ks = 0; ks < 2; ++ks) {
#pragma unroll
                for (int nf = 0; nf < 3; ++nf) {
                    short8 bv = *reinterpret_cast<const short8*>(&Xl[ky][nf * 16 + lm + kx][ks * 32 + q * 8]);
                    acc[nf] = __builtin_amdgcn_mfma_f32_16x16x32_bf16(af[tap][ks], bv, acc[nf], 0, 0, 0);
                }
            }
        }
    }
    int ocb = mt * 64 + w * 16 + q * 4;
#pragma unroll
    for (int nf = 0; nf < 3; ++nf) {
        int px = px0 + nf * 16 + lm;
#pragma unroll
        for (int rr2 = 0; rr2 < 4; ++rr2) {
            int oc = ocb + rr2;
            if (oc < OCST)
                out[((size_t)(n * OCST + oc)) * HW_ + y * 96 + px] = acc[nf][rr2] + bias[oc];
        }
    }
}

// ---------- fused deformable conv v3: NHWC bf16 gather, tap-major K ----------
__global__ __launch_bounds__(256) void dcn_gemm(const u16* __restrict__ txh,
                                                const float* __restrict__ om,
                                                const u16* __restrict__ A,
                                                const float* __restrict__ bias,
                                                float* __restrict__ out) {
    __shared__ __align__(16) u16 Bl[48][72];
    __shared__ float s_wy[432], s_wx[432], s_m[432];
    __shared__ int s_y0[432], s_x0[432];
    int t = threadIdx.x;
    int r = blockIdx.x;
    int n = r / 192;
    int rr = r % 192;
    int y = rr >> 1, px0 = (rr & 1) * 48;
    for (int e = t; e < 432; e += 256) {
        int k9 = e / 48, xl = e % 48;
        int x = px0 + xl;
        const float* ob = om + (size_t)n * 27 * HW_ + y * 96 + x;
        float dy = ob[(size_t)k9 * HW_];
        float dx = ob[(size_t)(9 + k9) * HW_];
        float ml = ob[(size_t)(18 + k9) * HW_];
        float py = (float)y + (float)(k9 / 3 - 1) + dy;
        float px = (float)x + (float)(k9 % 3 - 1) + dx;
        float fy = floorf(py), fx = floorf(px);
        s_y0[e] = (int)fy; s_x0[e] = (int)fx;
        s_wy[e] = py - fy; s_wx[e] = px - fx; s_m[e] = sigm(ml);
    }
    int w = t >> 6, lane = t & 63, lm = lane & 15, q = lane >> 4;
    const u16* Arow = A + (size_t)(w * 16 + lm) * 1152 + q * 8;
    floatx4 acc[3];
#pragma unroll
    for (int a = 0; a < 3; ++a) acc[a] = {0.f, 0.f, 0.f, 0.f};
    const u16* txn = txh + (size_t)n * HW_ * 128;
    const short8 zz = {0, 0, 0, 0, 0, 0, 0, 0};

    for (int kc = 0; kc < 18; ++kc) {
        int tap = kc >> 1, c0 = (kc & 1) * 64;
        short8 af[2];
#pragma unroll
        for (int ks = 0; ks < 2; ++ks)
            af[ks] = *reinterpret_cast<const short8*>(Arow + kc * 64 + ks * 32);
        __syncthreads();   // protect Bl reuse + (first iter) coord writes
#pragma unroll
        for (int i = 0; i < 2; ++i) {
            int id = i * 256 + t;
            if (id < 384) {
                int px = id >> 3, ch8 = id & 7;
                int ce = tap * 48 + px;
                int y0 = s_y0[ce], x0 = s_x0[ce];
                float wy = s_wy[ce], wx = s_wx[ce], m = s_m[ce];
                float w00 = (1.f - wy) * (1.f - wx) * m;
                float w01 = (1.f - wy) * wx * m;
                float w10 = wy * (1.f - wx) * m;
                float w11 = wy * wx * m;
                bool yv0 = (y0 >= 0) & (y0 < 96), yv1 = (y0 >= -1) & (y0 < 95);
                bool xv0 = (x0 >= 0) & (x0 < 96), xv1 = (x0 >= -1) & (x0 < 95);
                const u16* base = txn + (long)(y0 * 96 + x0) * 128 + c0 + ch8 * 8;
                short8 v00 = (yv0 && xv0) ? *reinterpret_cast<const short8*>(base) : zz;
                short8 v01 = (yv0 && xv1) ? *reinterpret_cast<const short8*>(base + 128) : zz;
                short8 v10 = (yv1 && xv0) ? *reinterpret_cast<const short8*>(base + 96 * 128) : zz;
                short8 v11 = (yv1 && xv1) ? *reinterpret_cast<const short8*>(base + 96 * 128 + 128) : zz;
                short8 vv;
#pragma unroll
                for (int j = 0; j < 8; ++j) {
                    float f = b2f(v00[j]) * w00 + b2f(v01[j]) * w01 +
                              b2f(v10[j]) * w10 + b2f(v11[j]) * w11;
                    vv[j] = f2b(f);
                }
                *reinterpret_cast<short8*>(&Bl[px][ch8 * 8]) = vv;
            }
        }
        __syncthreads();
#pragma unroll
        for (int ks = 0; ks < 2; ++ks)
#pragma unroll
            for (int nf = 0; nf < 3; ++nf) {
                short8 bv = *reinterpret_cast<const short8*>(&Bl[nf * 16 + lm][ks * 32 + q * 8]);
                acc[nf] = __builtin_amdgcn_mfma_f32_16x16x32_bf16(af[ks], bv, acc[nf], 0, 0, 0);
            }
    }
    int ocb = w * 16 + q * 4;
#pragma unroll
    for (int nf = 0; nf < 3; ++nf) {
        int px = px0 + nf * 16 + lm;
#pragma unroll
        for (int rr2 = 0; rr2 < 4; ++rr2) {
            int oc = ocb + rr2;
            out[((size_t)(n * CH_ + oc)) * HW_ + y * 96 + px] = acc[nf][rr2] + bias[oc];
        }
    }
}

// ---------------- ncf: correlation ----------------
__global__ __launch_bounds__(256) void ncf_corr(const float* __restrict__ f1, const float* __restrict__ f2,
                                                float* __restrict__ corr) {
    int idx = blockIdx.x * 256 + threadIdx.x;
    if (idx >= N_ * K2_ * HW_) return;
    int x = idx % W_;
    int y = (idx / W_) % H_;
    int k = (idx / HW_) % K2_;
    int n = idx / (HW_ * K2_);
    int oy = (k / 7) * 2 - 6, ox = (k % 7) * 2 - 6;
    int yy = y + oy, xx = x + ox;
    float s = 0.f;
    if (yy >= 0 && yy < H_ && xx >= 0 && xx < W_) {
        const float* a = f1 + (size_t)n * CH_ * HW_ + y * W_ + x;
        const float* c2 = f2 + (size_t)n * CH_ * HW_ + yy * W_ + xx;
        for (int c = 0; c < CH_; ++c) s += a[(size_t)c * HW_] * c2[(size_t)c * HW_];
    }
    corr[idx] = s * 0.125f;
}

// ---------------- ncf: softmax over 49 taps, in place ----------------
__global__ __launch_bounds__(256) void softmax49(float* __restrict__ corr) {
    int idx = blockIdx.x * 256 + threadIdx.x;
    if (idx >= N_ * HW_) return;
    int r = idx % HW_;
    int n = idx / HW_;
    float* base = corr + (size_t)n * K2_ * HW_ + r;
    float mx = -1e30f;
    for (int k = 0; k < K2_; ++k) mx = fmaxf(mx, base[(size_t)k * HW_]);
    float sum = 0.f;
    float e[K2_];
#pragma unroll
    for (int k = 0; k < K2_; ++k) { e[k] = __expf(base[(size_t)k * HW_] - mx); sum += e[k]; }
    float inv = 1.f / sum;
#pragma unroll
    for (int k = 0; k < K2_; ++k) base[(size_t)k * HW_] = e[k] * inv;
}

// ---------------- ncf: attn-weighted sample ----------------
__global__ __launch_bounds__(256) void ncf_sample(const float* __restrict__ attn, const float* __restrict__ f2,
                                                  float* __restrict__ out) {
    int idx = blockIdx.x * 256 + threadIdx.x;
    if (idx >= N_ * CH_ * HW_) return;
    int x = idx % W_;
    int y = (idx / W_) % H_;
    int c = (idx / HW_) % CH_;
    int n = idx / (HW_ * CH_);
    const float* ap = attn + (size_t)n * K2_ * HW_ + y * W_ + x;
    const float* fp = f2 + ((size_t)n * CH_ + c) * HW_;
    float s = 0.f;
    for (int k = 0; k < K2_; ++k) {
        int oy = (k / 7) * 2 - 6, ox = (k % 7) * 2 - 6;
        int yy = y + oy, xx = x + ox;
        if (yy >= 0 && yy < H_ && xx >= 0 && xx < W_)
            s += ap[(size_t)k * HW_] * fp[yy * W_ + xx];
    }
    out[idx] = s;
}

// ---------------- GRU gate -> NCHW f32 (final template output) ----------------
__global__ __launch_bounds__(256) void gatek_nchw(const float* __restrict__ zpre, const float* __restrict__ hpre,
                                                  const float* __restrict__ t, float* __restrict__ dst) {
    int idx = blockIdx.x * 256 + threadIdx.x;
    if (idx >= N_ * CH_ * HW_) return;
    float z = sigm(zpre[idx]);
    float xt = tanhf(hpre[idx]);
    dst[idx] = (1.f - z) * t[idx] + z * xt;
}

// ---------------- GRU gate -> NHWC bf16 (feeds conv_out) ----------------
__global__ __launch_bounds__(256) void gatek_nhwc(const float* __restrict__ zpre, const float* __restrict__ hpre,
                                                  const float* __restrict__ t, u16* __restrict__ dst) {
    int id = blockIdx.x * 256 + threadIdx.x;
    if (id >= N_ * HW_ * 8) return;
    int c8 = id & 7;
    int pix = id >> 3;
    int n = pix / HW_, p = pix % HW_;
    short8 vv;
#pragma unroll
    for (int j = 0; j < 8; ++j) {
        size_t idx = ((size_t)n * CH_ + c8 * 8 + j) * HW_ + p;
        float z = sigm(zpre[idx]);
        float xt = tanhf(hpre[idx]);
        vv[j] = f2b((1.f - z) * t[idx] + z * xt);
    }
    *reinterpret_cast<short8*>(dst + (size_t)pix * CH_ + c8 * 8) = vv;
}

extern "C" void kernel_launch(void* const* d_in, const int* in_sizes, int n_in,
                              void* d_out, int out_size, void* d_ws, size_t ws_size,
                              hipStream_t stream) {
    const float* x     = (const float*)d_in[0];
    const float* tpl   = (const float*)d_in[1];
    const float* w_in  = (const float*)d_in[2];
    const float* b_in  = (const float*)d_in[3];
    const float* w_out = (const float*)d_in[4];
    const float* b_out = (const float*)d_in[5];
    const float *pw[4], *pb[4], *pow_[4], *pob[4];
    for (int i = 0; i < 4; ++i) {           // 0=enh_z 1=enh_h 2=upd_z 3=upd_h
        pw[i]   = (const float*)d_in[6 + 4 * i];
        pb[i]   = (const float*)d_in[7 + 4 * i];
        pow_[i] = (const float*)d_in[8 + 4 * i];
        pob[i]  = (const float*)d_in[9 + 4 * i];
    }
    float* out_main = (float*)d_out;
    float* out_ntpl = out_main + (size_t)N_ * CIN_ * HW_;

    // ---- workspace layout (~36 MB; round-2-proven bound 38.6 MB) ----
    u16* Aws = (u16*)d_ws;
    u16* xT  = Aws + A_TOT;                       // NHWC bf16 (N,96,96,256)
    u16* txh = xT + (size_t)N_ * HW_ * CIN_;      // NHWC bf16 (N,96,96,128)
    u16* xeh = txh + (size_t)N_ * HW_ * C2_;      // NHWC bf16 (N,96,96,64)
    float* fws = (float*)(xeh + (size_t)N_ * HW_ * CH_);
    size_t off = 0;
    float* xh   = fws + off; off += (size_t)N_ * CH_ * HW_;
    float* omat = fws + off; off += (size_t)N_ * K2_ * HW_;   // om (27ch) / at (49ch) alias
    float* dz   = fws + off; off += (size_t)N_ * CH_ * HW_;
    float* dhrb = fws + off; off += (size_t)N_ * CH_ * HW_;   // rb / dh alias

    cvt_weights<<<(A_TOT + 255) / 256, 256, 0, stream>>>(
        w_in, w_out, pow_[0], pow_[1], pow_[2], pow_[3], pw[0], pw[1], pw[2], pw[3], Aws);
    to_nhwc<<<2304, 256, 0, stream>>>(x, xT, CIN_);

    auto stargru = [&](const float* x32, const float* tt, int zi, int hi, float* dstf, u16* dsth) {
        float* om = omat;
        float* at = omat;
        float* rb = dhrb;
        float* dh = dhrb;
        concat_nhwc<<<1152, 256, 0, stream>>>(x32, tt, txh);
        conv_gemm<C2_, 27><<<384, 256, 0, stream>>>(txh, Aws + A_OFF_OFF + zi * A_OFF_SZ, pob[zi], om);
        dcn_gemm<<<384, 256, 0, stream>>>(txh, om, Aws + A_DCN_OFF + zi * A_DCN_SZ, pb[zi], dz);
        ncf_corr<<<3528, 256, 0, stream>>>(tt, x32, at);       // om dead from here
        softmax49<<<72, 256, 0, stream>>>(at);
        ncf_sample<<<4608, 256, 0, stream>>>(at, x32, rb);
        concat_nhwc<<<1152, 256, 0, stream>>>(rb, tt, txh);
        conv_gemm<C2_, 27><<<384, 256, 0, stream>>>(txh, Aws + A_OFF_OFF + hi * A_OFF_SZ, pob[hi], om);  // at dead
        dcn_gemm<<<384, 256, 0, stream>>>(txh, om, Aws + A_DCN_OFF + hi * A_DCN_SZ, pb[hi], dh);          // rb dead
        if (dsth) gatek_nhwc<<<576, 256, 0, stream>>>(dz, dh, tt, dsth);
        else      gatek_nchw<<<4608, 256, 0, stream>>>(dz, dh, tt, dstf);
    };

    conv_gemm<CIN_, 64><<<384, 256, 0, stream>>>(xT, Aws + A_IN_OFF, b_in, xh);
    stargru(tpl, xh, 0, 1, nullptr, xeh);        // x_enh -> NHWC bf16 (feeds conv_out)
    stargru(xh, tpl, 2, 3, out_ntpl, nullptr);   // new_template -> NCHW f32 output
    conv_gemm<CH_, 256><<<1536, 256, 0, stream>>>(xeh, Aws + A_OUT_OFF, b_out, out_main);
}

// Round 7
// 455.385 us; speedup vs baseline: 9.5976x; 1.2524x over previous
//
#include <hip/hip_runtime.h>
#include <hip/hip_bf16.h>

typedef __hip_bfloat16 bf16;
typedef unsigned short u16;
typedef unsigned int u32;
typedef __attribute__((ext_vector_type(8))) short short8;
typedef __attribute__((ext_vector_type(4))) float floatx4;

constexpr int N_ = 2, H_ = 96, W_ = 96, HW_ = H_ * W_;
constexpr int CIN_ = 256, CH_ = 64, C2_ = 128;

__device__ __forceinline__ float sigm(float v) { return 1.0f / (1.0f + __expf(-v)); }
__device__ __forceinline__ short f2b(float v) { bf16 h = __float2bfloat16(v); return *reinterpret_cast<short*>(&h); }
__device__ __forceinline__ float b2f(short s) {
    union { u32 i; float f; } v; v.i = ((u32)(u16)s) << 16; return v.f;
}

// ---------- bf16 weight regions inside d_ws ----------
// conv A[m][k = tap*IC + ic];  dcn A[m][k = tap*128 + c]  (both tap-major)
constexpr int A_IN_OFF = 0,                         A_IN_SZ  = 64 * 2304;
constexpr int A_OUT_OFF = A_IN_OFF + A_IN_SZ,       A_OUT_SZ = 256 * 576;
constexpr int A_OFF_OFF = A_OUT_OFF + A_OUT_SZ,     A_OFF_SZ = 64 * 1152;   // 27 padded to 64
constexpr int A_DCN_OFF = A_OFF_OFF + 4 * A_OFF_SZ, A_DCN_SZ = 64 * 1152;
constexpr int A_TOT = A_DCN_OFF + 4 * A_DCN_SZ;     // 884736 shorts = 1.77 MB

__global__ __launch_bounds__(256) void cvt_weights(
        const float* __restrict__ w_in, const float* __restrict__ w_out,
        const float* __restrict__ ow0, const float* __restrict__ ow1,
        const float* __restrict__ ow2, const float* __restrict__ ow3,
        const float* __restrict__ w0, const float* __restrict__ w1,
        const float* __restrict__ w2, const float* __restrict__ w3,
        u16* __restrict__ dst) {
    int id = blockIdx.x * 256 + threadIdx.x;
    if (id >= A_TOT) return;
    float v;
    if (id < A_OUT_OFF) {
        int l = id; int m = l / 2304, k = l % 2304; int tap = k >> 8, ic = k & 255;
        v = w_in[m * 2304 + ic * 9 + tap];
    } else if (id < A_OFF_OFF) {
        int l = id - A_OUT_OFF; int m = l / 576, k = l % 576; int tap = k / 64, ic = k & 63;
        v = w_out[m * 576 + ic * 9 + tap];
    } else if (id < A_DCN_OFF) {
        int l = id - A_OFF_OFF; int i = l / A_OFF_SZ, l2 = l % A_OFF_SZ;
        int m = l2 / 1152, k = l2 % 1152; int tap = k >> 7, ic = k & 127;
        const float* s = (i == 0) ? ow0 : (i == 1) ? ow1 : (i == 2) ? ow2 : ow3;
        v = (m < 27) ? s[m * 1152 + ic * 9 + tap] : 0.f;
    } else {
        // dcn: tap-major K: A[m][tap*128+c] = w[m][c*9+tap]
        int l = id - A_DCN_OFF; int i = l / A_DCN_SZ, l2 = l % A_DCN_SZ;
        int m = l2 / 1152, k = l2 % 1152; int tap = k >> 7, c = k & 127;
        const float* s = (i == 0) ? w0 : (i == 1) ? w1 : (i == 2) ? w2 : w3;
        v = s[m * 1152 + c * 9 + tap];
    }
    short sb = f2b(v);
    dst[id] = *reinterpret_cast<u16*>(&sb);
}

// ---------- NCHW f32 -> NHWC bf16 ----------
__global__ __launch_bounds__(256) void to_nhwc(const float* __restrict__ src, u16* __restrict__ dst, int C) {
    int id = blockIdx.x * 256 + threadIdx.x;
    int c8n = C >> 3;
    if (id >= N_ * HW_ * c8n) return;
    int c8 = id % c8n;
    int pix = id / c8n;
    int n = pix / HW_, p = pix % HW_;
    const float* s = src + ((size_t)n * C + c8 * 8) * HW_ + p;
    short8 vv;
#pragma unroll
    for (int j = 0; j < 8; ++j) vv[j] = f2b(s[(size_t)j * HW_]);
    *reinterpret_cast<short8*>(dst + (size_t)pix * C + c8 * 8) = vv;
}

// ---------- concat two NCHW f32 (64ch each) -> NHWC bf16 128ch ----------
__global__ __launch_bounds__(256) void concat_nhwc(const float* __restrict__ A, const float* __restrict__ B,
                                                   u16* __restrict__ dst) {
    int id = blockIdx.x * 256 + threadIdx.x;
    if (id >= N_ * HW_ * 16) return;
    int c8 = id & 15;
    int pix = id >> 4;
    int n = pix / HW_, p = pix % HW_;
    int c = c8 * 8;
    const float* s = (c < 64) ? A + ((size_t)n * 64 + c) * HW_ + p
                              : B + ((size_t)n * 64 + (c - 64)) * HW_ + p;
    short8 vv;
#pragma unroll
    for (int j = 0; j < 8; ++j) vv[j] = f2b(s[(size_t)j * HW_]);
    *reinterpret_cast<short8*>(dst + (size_t)pix * 128 + c) = vv;
}

// ---------- implicit-GEMM 3x3 SAME conv, NHWC bf16 input, NCHW f32 out ----------
template <int IC, int OCST>
__global__ __launch_bounds__(256) void conv_gemm(const u16* __restrict__ X,
                                                 const u16* __restrict__ A,
                                                 const float* __restrict__ bias,
                                                 float* __restrict__ out) {
    constexpr int K = IC * 9;
    constexpr int ICC = IC / 64;
    __shared__ __align__(16) u16 Xl[3][50][72];   // [row][px(-1..48)][ch]
    int t = threadIdx.x;
    int gx = blockIdx.x;
    int mt = gx / 384;
    int r = gx % 384;
    int n = r / 192;
    int rr = r % 192;
    int y = rr >> 1, px0 = (rr & 1) * 48;
    int w = t >> 6, lane = t & 63, lm = lane & 15, q = lane >> 4;
    const u16* Arow = A + (size_t)(mt * 64 + w * 16 + lm) * K + q * 8;
    floatx4 acc[3];
#pragma unroll
    for (int a = 0; a < 3; ++a) acc[a] = {0.f, 0.f, 0.f, 0.f};
    const short8 zz = {0, 0, 0, 0, 0, 0, 0, 0};

    for (int icc = 0; icc < ICC; ++icc) {
        short8 af[9][2];
#pragma unroll
        for (int tap = 0; tap < 9; ++tap)
#pragma unroll
            for (int ks = 0; ks < 2; ++ks)
                af[tap][ks] = *reinterpret_cast<const short8*>(Arow + tap * IC + icc * 64 + ks * 32);
        __syncthreads();
#pragma unroll
        for (int it = 0; it < 5; ++it) {
            int id = it * 256 + t;
            if (id < 1200) {
                int ch8 = id & 7;
                int tmp = id >> 3;
                int pxl = tmp % 50, row = tmp / 50;
                int xg = px0 - 1 + pxl;
                int yg = y - 1 + row;
                bool vld = (yg >= 0) && (yg < 96) && (xg >= 0) && (xg < 96);
                short8 vv = zz;
                if (vld)
                    vv = *reinterpret_cast<const short8*>(
                        X + ((size_t)(n * HW_ + yg * 96 + xg)) * IC + icc * 64 + ch8 * 8);
                *reinterpret_cast<short8*>(&Xl[row][pxl][ch8 * 8]) = vv;
            }
        }
        __syncthreads();
#pragma unroll
        for (int tap = 0; tap < 9; ++tap) {
            int ky = tap / 3, kx = tap % 3;
#pragma unroll
            for (int ks = 0; ks < 2; ++ks) {
#pragma unroll
                for (int nf = 0; nf < 3; ++nf) {
                    short8 bv = *reinterpret_cast<const short8*>(&Xl[ky][nf * 16 + lm + kx][ks * 32 + q * 8]);
                    acc[nf] = __builtin_amdgcn_mfma_f32_16x16x32_bf16(af[tap][ks], bv, acc[nf], 0, 0, 0);
                }
            }
        }
    }
    int ocb = mt * 64 + w * 16 + q * 4;
#pragma unroll
    for (int nf = 0; nf < 3; ++nf) {
        int px = px0 + nf * 16 + lm;
#pragma unroll
        for (int rr2 = 0; rr2 < 4; ++rr2) {
            int oc = ocb + rr2;
            if (oc < OCST)
                out[((size_t)(n * OCST + oc)) * HW_ + y * 96 + px] = acc[nf][rr2] + bias[oc];
        }
    }
}

// ---------- fused deformable conv: NHWC bf16 gather, tap-major K ----------
__global__ __launch_bounds__(256) void dcn_gemm(const u16* __restrict__ txh,
                                                const float* __restrict__ om,
                                                const u16* __restrict__ A,
                                                const float* __restrict__ bias,
                                                float* __restrict__ out) {
    __shared__ __align__(16) u16 Bl[48][72];
    __shared__ float s_wy[432], s_wx[432], s_m[432];
    __shared__ int s_y0[432], s_x0[432];
    int t = threadIdx.x;
    int r = blockIdx.x;
    int n = r / 192;
    int rr = r % 192;
    int y = rr >> 1, px0 = (rr & 1) * 48;
    for (int e = t; e < 432; e += 256) {
        int k9 = e / 48, xl = e % 48;
        int x = px0 + xl;
        const float* ob = om + (size_t)n * 27 * HW_ + y * 96 + x;
        float dy = ob[(size_t)k9 * HW_];
        float dx = ob[(size_t)(9 + k9) * HW_];
        float ml = ob[(size_t)(18 + k9) * HW_];
        float py = (float)y + (float)(k9 / 3 - 1) + dy;
        float px = (float)x + (float)(k9 % 3 - 1) + dx;
        float fy = floorf(py), fx = floorf(px);
        s_y0[e] = (int)fy; s_x0[e] = (int)fx;
        s_wy[e] = py - fy; s_wx[e] = px - fx; s_m[e] = sigm(ml);
    }
    int w = t >> 6, lane = t & 63, lm = lane & 15, q = lane >> 4;
    const u16* Arow = A + (size_t)(w * 16 + lm) * 1152 + q * 8;
    floatx4 acc[3];
#pragma unroll
    for (int a = 0; a < 3; ++a) acc[a] = {0.f, 0.f, 0.f, 0.f};
    const u16* txn = txh + (size_t)n * HW_ * 128;
    const short8 zz = {0, 0, 0, 0, 0, 0, 0, 0};

    for (int kc = 0; kc < 18; ++kc) {
        int tap = kc >> 1, c0 = (kc & 1) * 64;
        short8 af[2];
#pragma unroll
        for (int ks = 0; ks < 2; ++ks)
            af[ks] = *reinterpret_cast<const short8*>(Arow + kc * 64 + ks * 32);
        __syncthreads();
#pragma unroll
        for (int i = 0; i < 2; ++i) {
            int id = i * 256 + t;
            if (id < 384) {
                int px = id >> 3, ch8 = id & 7;
                int ce = tap * 48 + px;
                int y0 = s_y0[ce], x0 = s_x0[ce];
                float wy = s_wy[ce], wx = s_wx[ce], m = s_m[ce];
                float w00 = (1.f - wy) * (1.f - wx) * m;
                float w01 = (1.f - wy) * wx * m;
                float w10 = wy * (1.f - wx) * m;
                float w11 = wy * wx * m;
                bool yv0 = (y0 >= 0) & (y0 < 96), yv1 = (y0 >= -1) & (y0 < 95);
                bool xv0 = (x0 >= 0) & (x0 < 96), xv1 = (x0 >= -1) & (x0 < 95);
                const u16* base = txn + (long)(y0 * 96 + x0) * 128 + c0 + ch8 * 8;
                short8 v00 = (yv0 && xv0) ? *reinterpret_cast<const short8*>(base) : zz;
                short8 v01 = (yv0 && xv1) ? *reinterpret_cast<const short8*>(base + 128) : zz;
                short8 v10 = (yv1 && xv0) ? *reinterpret_cast<const short8*>(base + 96 * 128) : zz;
                short8 v11 = (yv1 && xv1) ? *reinterpret_cast<const short8*>(base + 96 * 128 + 128) : zz;
                short8 vv;
#pragma unroll
                for (int j = 0; j < 8; ++j) {
                    float f = b2f(v00[j]) * w00 + b2f(v01[j]) * w01 +
                              b2f(v10[j]) * w10 + b2f(v11[j]) * w11;
                    vv[j] = f2b(f);
                }
                *reinterpret_cast<short8*>(&Bl[px][ch8 * 8]) = vv;
            }
        }
        __syncthreads();
#pragma unroll
        for (int ks = 0; ks < 2; ++ks)
#pragma unroll
            for (int nf = 0; nf < 3; ++nf) {
                short8 bv = *reinterpret_cast<const short8*>(&Bl[nf * 16 + lm][ks * 32 + q * 8]);
                acc[nf] = __builtin_amdgcn_mfma_f32_16x16x32_bf16(af[ks], bv, acc[nf], 0, 0, 0);
            }
    }
    int ocb = w * 16 + q * 4;
#pragma unroll
    for (int nf = 0; nf < 3; ++nf) {
        int px = px0 + nf * 16 + lm;
#pragma unroll
        for (int rr2 = 0; rr2 < 4; ++rr2) {
            int oc = ocb + rr2;
            out[((size_t)(n * CH_ + oc)) * HW_ + y * 96 + px] = acc[nf][rr2] + bias[oc];
        }
    }
}

// ---------- fused NCF: corr(49) + softmax + sample, NHWC bf16 in/out ----------
// txh = concat(f2=x32 [ch 0..63], f1=tt [ch 64..127]) NHWC bf16.
// Writes txh2 = concat(r [ch 0..63], tt [ch 64..127]) NHWC bf16.
// 8 threads per pixel, 8 channels each; corr reduced via 3x shfl_xor.
__global__ __launch_bounds__(256) void ncf_fused(const u16* __restrict__ txh,
                                                 u16* __restrict__ txh2) {
    int t = threadIdx.x;
    int gpx = blockIdx.x * 32 + (t >> 3);
    int ch0 = (t & 7) * 8;
    int n = gpx / HW_, p = gpx % HW_;
    int y = p / 96, x = p % 96;
    const u16* base = txh + (size_t)n * HW_ * 128;
    short8 f1 = *reinterpret_cast<const short8*>(base + (size_t)p * 128 + 64 + ch0);
    float f1f[8];
#pragma unroll
    for (int j = 0; j < 8; ++j) f1f[j] = b2f(f1[j]);

    float corr[49];
#pragma unroll
    for (int k = 0; k < 49; ++k) {
        int yy = y + (k / 7) * 2 - 6, xx = x + (k % 7) * 2 - 6;
        float s = 0.f;
        if (yy >= 0 && yy < 96 && xx >= 0 && xx < 96) {
            short8 f2 = *reinterpret_cast<const short8*>(base + (size_t)(yy * 96 + xx) * 128 + ch0);
#pragma unroll
            for (int j = 0; j < 8; ++j) s += f1f[j] * b2f(f2[j]);
        }
        corr[k] = s;
    }
    // reduce partial dots over the 8 lanes of this pixel group
#pragma unroll
    for (int m = 1; m <= 4; m <<= 1)
#pragma unroll
        for (int k = 0; k < 49; ++k) corr[k] += __shfl_xor(corr[k], m, 64);
    // softmax over 49 (each lane holds the full vector now)
    float mx = -1e30f;
#pragma unroll
    for (int k = 0; k < 49; ++k) { corr[k] *= 0.125f; mx = fmaxf(mx, corr[k]); }
    float sum = 0.f;
#pragma unroll
    for (int k = 0; k < 49; ++k) { corr[k] = __expf(corr[k] - mx); sum += corr[k]; }
    float inv = 1.f / sum;
    // sample: weighted sum of f2 vectors
    float acc[8];
#pragma unroll
    for (int j = 0; j < 8; ++j) acc[j] = 0.f;
#pragma unroll
    for (int k = 0; k < 49; ++k) {
        int yy = y + (k / 7) * 2 - 6, xx = x + (k % 7) * 2 - 6;
        if (yy >= 0 && yy < 96 && xx >= 0 && xx < 96) {
            short8 f2 = *reinterpret_cast<const short8*>(base + (size_t)(yy * 96 + xx) * 128 + ch0);
            float a = corr[k] * inv;
#pragma unroll
            for (int j = 0; j < 8; ++j) acc[j] += a * b2f(f2[j]);
        }
    }
    u16* obase = txh2 + (size_t)n * HW_ * 128 + (size_t)p * 128;
    short8 ro;
#pragma unroll
    for (int j = 0; j < 8; ++j) ro[j] = f2b(acc[j]);
    *reinterpret_cast<short8*>(obase + ch0) = ro;
    *reinterpret_cast<short8*>(obase + 64 + ch0) = f1;   // tt passthrough
}

// ---------------- GRU gate -> NCHW f32 (final template output) ----------------
__global__ __launch_bounds__(256) void gatek_nchw(const float* __restrict__ zpre, const float* __restrict__ hpre,
                                                  const float* __restrict__ t, float* __restrict__ dst) {
    int idx = blockIdx.x * 256 + threadIdx.x;
    if (idx >= N_ * CH_ * HW_) return;
    float z = sigm(zpre[idx]);
    float xt = tanhf(hpre[idx]);
    dst[idx] = (1.f - z) * t[idx] + z * xt;
}

// ---------------- GRU gate -> NHWC bf16 (feeds conv_out) ----------------
__global__ __launch_bounds__(256) void gatek_nhwc(const float* __restrict__ zpre, const float* __restrict__ hpre,
                                                  const float* __restrict__ t, u16* __restrict__ dst) {
    int id = blockIdx.x * 256 + threadIdx.x;
    if (id >= N_ * HW_ * 8) return;
    int c8 = id & 7;
    int pix = id >> 3;
    int n = pix / HW_, p = pix % HW_;
    short8 vv;
#pragma unroll
    for (int j = 0; j < 8; ++j) {
        size_t idx = ((size_t)n * CH_ + c8 * 8 + j) * HW_ + p;
        float z = sigm(zpre[idx]);
        float xt = tanhf(hpre[idx]);
        vv[j] = f2b((1.f - z) * t[idx] + z * xt);
    }
    *reinterpret_cast<short8*>(dst + (size_t)pix * CH_ + c8 * 8) = vv;
}

extern "C" void kernel_launch(void* const* d_in, const int* in_sizes, int n_in,
                              void* d_out, int out_size, void* d_ws, size_t ws_size,
                              hipStream_t stream) {
    const float* x     = (const float*)d_in[0];
    const float* tpl   = (const float*)d_in[1];
    const float* w_in  = (const float*)d_in[2];
    const float* b_in  = (const float*)d_in[3];
    const float* w_out = (const float*)d_in[4];
    const float* b_out = (const float*)d_in[5];
    const float *pw[4], *pb[4], *pow_[4], *pob[4];
    for (int i = 0; i < 4; ++i) {           // 0=enh_z 1=enh_h 2=upd_z 3=upd_h
        pw[i]   = (const float*)d_in[6 + 4 * i];
        pb[i]   = (const float*)d_in[7 + 4 * i];
        pow_[i] = (const float*)d_in[8 + 4 * i];
        pob[i]  = (const float*)d_in[9 + 4 * i];
    }
    float* out_main = (float*)d_out;
    float* out_ntpl = out_main + (size_t)N_ * CIN_ * HW_;

    // ---- workspace layout (~36 MB; same as round 6) ----
    u16* Aws = (u16*)d_ws;
    u16* xT  = Aws + A_TOT;                       // NHWC bf16 (N,96,96,256); dead after conv_in
    u16* txh = xT + (size_t)N_ * HW_ * CIN_;      // NHWC bf16 (N,96,96,128)
    u16* xeh = txh + (size_t)N_ * HW_ * C2_;      // NHWC bf16 (N,96,96,64)
    float* fws = (float*)(xeh + (size_t)N_ * HW_ * CH_);
    size_t off = 0;
    float* xh   = fws + off; off += (size_t)N_ * CH_ * HW_;
    float* omat = fws + off; off += (size_t)N_ * 49 * HW_;
    float* dz   = fws + off; off += (size_t)N_ * CH_ * HW_;
    float* dh   = fws + off; off += (size_t)N_ * CH_ * HW_;
    u16* txh2 = xT;                               // reuse xT region (only needs 128ch of the 256)

    cvt_weights<<<(A_TOT + 255) / 256, 256, 0, stream>>>(
        w_in, w_out, pow_[0], pow_[1], pow_[2], pow_[3], pw[0], pw[1], pw[2], pw[3], Aws);
    to_nhwc<<<2304, 256, 0, stream>>>(x, xT, CIN_);

    auto stargru = [&](const float* x32, const float* tt, int zi, int hi, float* dstf, u16* dsth) {
        float* om = omat;
        concat_nhwc<<<1152, 256, 0, stream>>>(x32, tt, txh);
        conv_gemm<C2_, 27><<<384, 256, 0, stream>>>(txh, Aws + A_OFF_OFF + zi * A_OFF_SZ, pob[zi], om);
        dcn_gemm<<<384, 256, 0, stream>>>(txh, om, Aws + A_DCN_OFF + zi * A_DCN_SZ, pb[zi], dz);
        ncf_fused<<<576, 256, 0, stream>>>(txh, txh2);   // txh2 = concat(r, tt) NHWC bf16
        conv_gemm<C2_, 27><<<384, 256, 0, stream>>>(txh2, Aws + A_OFF_OFF + hi * A_OFF_SZ, pob[hi], om);
        dcn_gemm<<<384, 256, 0, stream>>>(txh2, om, Aws + A_DCN_OFF + hi * A_DCN_SZ, pb[hi], dh);
        if (dsth) gatek_nhwc<<<576, 256, 0, stream>>>(dz, dh, tt, dsth);
        else      gatek_nchw<<<4608, 256, 0, stream>>>(dz, dh, tt, dstf);
    };

    conv_gemm<CIN_, 64><<<384, 256, 0, stream>>>(xT, Aws + A_IN_OFF, b_in, xh);
    stargru(tpl, xh, 0, 1, nullptr, xeh);        // x_enh -> NHWC bf16 (feeds conv_out)
    stargru(xh, tpl, 2, 3, out_ntpl, nullptr);   // new_template -> NCHW f32 output
    conv_gemm<CH_, 256><<<1536, 256, 0, stream>>>(xeh, Aws + A_OUT_OFF, b_out, out_main);
}

// Round 8
// 368.042 us; speedup vs baseline: 11.8753x; 1.2373x over previous
//
#include <hip/hip_runtime.h>
#include <hip/hip_bf16.h>

typedef __hip_bfloat16 bf16;
typedef unsigned short u16;
typedef unsigned int u32;
typedef __attribute__((ext_vector_type(8))) short short8;
typedef __attribute__((ext_vector_type(4))) float floatx4;

constexpr int N_ = 2, H_ = 96, W_ = 96, HW_ = H_ * W_;
constexpr int CIN_ = 256, CH_ = 64, C2_ = 128;

__device__ __forceinline__ float sigm(float v) { return 1.0f / (1.0f + __expf(-v)); }
__device__ __forceinline__ short f2b(float v) { bf16 h = __float2bfloat16(v); return *reinterpret_cast<short*>(&h); }
__device__ __forceinline__ float b2f(short s) {
    union { u32 i; float f; } v; v.i = ((u32)(u16)s) << 16; return v.f;
}

// ---------- bf16 weight regions inside d_ws ----------
// conv A[m][k = tap*IC + ic];  dcn A[m][k = tap*128 + c]  (both tap-major)
constexpr int A_IN_OFF = 0,                         A_IN_SZ  = 64 * 2304;
constexpr int A_OUT_OFF = A_IN_OFF + A_IN_SZ,       A_OUT_SZ = 256 * 576;
constexpr int A_OFF_OFF = A_OUT_OFF + A_OUT_SZ,     A_OFF_SZ = 64 * 1152;   // 27 padded to 64
constexpr int A_DCN_OFF = A_OFF_OFF + 4 * A_OFF_SZ, A_DCN_SZ = 64 * 1152;
constexpr int A_TOT = A_DCN_OFF + 4 * A_DCN_SZ;     // 884736 shorts = 1.77 MB

__global__ __launch_bounds__(256) void cvt_weights(
        const float* __restrict__ w_in, const float* __restrict__ w_out,
        const float* __restrict__ ow0, const float* __restrict__ ow1,
        const float* __restrict__ ow2, const float* __restrict__ ow3,
        const float* __restrict__ w0, const float* __restrict__ w1,
        const float* __restrict__ w2, const float* __restrict__ w3,
        u16* __restrict__ dst) {
    int id = blockIdx.x * 256 + threadIdx.x;
    if (id >= A_TOT) return;
    float v;
    if (id < A_OUT_OFF) {
        int l = id; int m = l / 2304, k = l % 2304; int tap = k >> 8, ic = k & 255;
        v = w_in[m * 2304 + ic * 9 + tap];
    } else if (id < A_OFF_OFF) {
        int l = id - A_OUT_OFF; int m = l / 576, k = l % 576; int tap = k / 64, ic = k & 63;
        v = w_out[m * 576 + ic * 9 + tap];
    } else if (id < A_DCN_OFF) {
        int l = id - A_OFF_OFF; int i = l / A_OFF_SZ, l2 = l % A_OFF_SZ;
        int m = l2 / 1152, k = l2 % 1152; int tap = k >> 7, ic = k & 127;
        const float* s = (i == 0) ? ow0 : (i == 1) ? ow1 : (i == 2) ? ow2 : ow3;
        v = (m < 27) ? s[m * 1152 + ic * 9 + tap] : 0.f;
    } else {
        int l = id - A_DCN_OFF; int i = l / A_DCN_SZ, l2 = l % A_DCN_SZ;
        int m = l2 / 1152, k = l2 % 1152; int tap = k >> 7, c = k & 127;
        const float* s = (i == 0) ? w0 : (i == 1) ? w1 : (i == 2) ? w2 : w3;
        v = s[m * 1152 + c * 9 + tap];
    }
    short sb = f2b(v);
    dst[id] = *reinterpret_cast<u16*>(&sb);
}

// ---------- NCHW f32 -> NHWC bf16 ----------
__global__ __launch_bounds__(256) void to_nhwc(const float* __restrict__ src, u16* __restrict__ dst, int C) {
    int id = blockIdx.x * 256 + threadIdx.x;
    int c8n = C >> 3;
    if (id >= N_ * HW_ * c8n) return;
    int c8 = id % c8n;
    int pix = id / c8n;
    int n = pix / HW_, p = pix % HW_;
    const float* s = src + ((size_t)n * C + c8 * 8) * HW_ + p;
    short8 vv;
#pragma unroll
    for (int j = 0; j < 8; ++j) vv[j] = f2b(s[(size_t)j * HW_]);
    *reinterpret_cast<short8*>(dst + (size_t)pix * C + c8 * 8) = vv;
}

// ---------- dual concat: txh_a = concat(tpl, xh), txh_b = concat(xh, tpl) ----------
__global__ __launch_bounds__(256) void concat_dual(const float* __restrict__ tpl, const float* __restrict__ xh,
                                                   u16* __restrict__ ta, u16* __restrict__ tb) {
    int id = blockIdx.x * 256 + threadIdx.x;
    if (id >= N_ * HW_ * 16) return;
    int c8 = id & 15;
    int pix = id >> 4;
    int n = pix / HW_, p = pix % HW_;
    int c = c8 * 8;
    const float* s = (c < 64) ? tpl + ((size_t)n * 64 + c) * HW_ + p
                              : xh + ((size_t)n * 64 + (c - 64)) * HW_ + p;
    short8 vv;
#pragma unroll
    for (int j = 0; j < 8; ++j) vv[j] = f2b(s[(size_t)j * HW_]);
    *reinterpret_cast<short8*>(ta + (size_t)pix * 128 + c) = vv;
    *reinterpret_cast<short8*>(tb + (size_t)pix * 128 + ((c + 64) & 127)) = vv;
}

// ---------- core implicit-GEMM body (shared by single & dual kernels) ----------
template <int IC, int OCST>
__device__ __forceinline__ void conv_core(const u16* __restrict__ X,
                                          const u16* __restrict__ A,
                                          const float* __restrict__ bias,
                                          float* __restrict__ out,
                                          int r, int mt, int t) {
    constexpr int K = IC * 9;
    constexpr int ICC = IC / 64;
    __shared__ __align__(16) u16 Xl[3][50][72];
    int n = r / 192;
    int rr = r % 192;
    int y = rr >> 1, px0 = (rr & 1) * 48;
    int w = t >> 6, lane = t & 63, lm = lane & 15, q = lane >> 4;
    const u16* Arow = A + (size_t)(mt * 64 + w * 16 + lm) * K + q * 8;
    floatx4 acc[3];
#pragma unroll
    for (int a = 0; a < 3; ++a) acc[a] = {0.f, 0.f, 0.f, 0.f};
    const short8 zz = {0, 0, 0, 0, 0, 0, 0, 0};

    for (int icc = 0; icc < ICC; ++icc) {
        short8 af[9][2];
#pragma unroll
        for (int tap = 0; tap < 9; ++tap)
#pragma unroll
            for (int ks = 0; ks < 2; ++ks)
                af[tap][ks] = *reinterpret_cast<const short8*>(Arow + tap * IC + icc * 64 + ks * 32);
        __syncthreads();
#pragma unroll
        for (int it = 0; it < 5; ++it) {
            int id = it * 256 + t;
            if (id < 1200) {
                int ch8 = id & 7;
                int tmp = id >> 3;
                int pxl = tmp % 50, row = tmp / 50;
                int xg = px0 - 1 + pxl;
                int yg = y - 1 + row;
                bool vld = (yg >= 0) && (yg < 96) && (xg >= 0) && (xg < 96);
                short8 vv = zz;
                if (vld)
                    vv = *reinterpret_cast<const short8*>(
                        X + ((size_t)(n * HW_ + yg * 96 + xg)) * IC + icc * 64 + ch8 * 8);
                *reinterpret_cast<short8*>(&Xl[row][pxl][ch8 * 8]) = vv;
            }
        }
        __syncthreads();
#pragma unroll
        for (int tap = 0; tap < 9; ++tap) {
            int ky = tap / 3, kx = tap % 3;
#pragma unroll
            for (int ks = 0; ks < 2; ++ks) {
#pragma unroll
                for (int nf = 0; nf < 3; ++nf) {
                    short8 bv = *reinterpret_cast<const short8*>(&Xl[ky][nf * 16 + lm + kx][ks * 32 + q * 8]);
                    acc[nf] = __builtin_amdgcn_mfma_f32_16x16x32_bf16(af[tap][ks], bv, acc[nf], 0, 0, 0);
                }
            }
        }
    }
    int ocb = mt * 64 + w * 16 + q * 4;
#pragma unroll
    for (int nf = 0; nf < 3; ++nf) {
        int px = px0 + nf * 16 + lm;
#pragma unroll
        for (int rr2 = 0; rr2 < 4; ++rr2) {
            int oc = ocb + rr2;
            if (oc < OCST)
                out[((size_t)(n * OCST + oc)) * HW_ + y * 96 + px] = acc[nf][rr2] + bias[oc];
        }
    }
}

template <int IC, int OCST>
__global__ __launch_bounds__(256) void conv_gemm(const u16* __restrict__ X,
                                                 const u16* __restrict__ A,
                                                 const float* __restrict__ bias,
                                                 float* __restrict__ out) {
    conv_core<IC, OCST>(X, A, bias, out, blockIdx.x % 384, blockIdx.x / 384, threadIdx.x);
}

// dual-instance offset conv: grid 768, inst = gx/384
__global__ __launch_bounds__(256) void conv_gemm2(const u16* __restrict__ X0, const u16* __restrict__ X1,
                                                  const u16* __restrict__ A0, const u16* __restrict__ A1,
                                                  const float* __restrict__ b0, const float* __restrict__ b1,
                                                  float* __restrict__ o0, float* __restrict__ o1) {
    int inst = blockIdx.x / 384, r = blockIdx.x % 384;
    conv_core<C2_, 27>(inst ? X1 : X0, inst ? A1 : A0, inst ? b1 : b0, inst ? o1 : o0, r, 0, threadIdx.x);
}

// ---------- fused deformable conv core ----------
__device__ __forceinline__ void dcn_core(const u16* __restrict__ txh,
                                         const float* __restrict__ om,
                                         const u16* __restrict__ A,
                                         const float* __restrict__ bias,
                                         float* __restrict__ out,
                                         int r, int t) {
    __shared__ __align__(16) u16 Bl[48][72];
    __shared__ float s_wy[432], s_wx[432], s_m[432];
    __shared__ int s_y0[432], s_x0[432];
    int n = r / 192;
    int rr = r % 192;
    int y = rr >> 1, px0 = (rr & 1) * 48;
    for (int e = t; e < 432; e += 256) {
        int k9 = e / 48, xl = e % 48;
        int x = px0 + xl;
        const float* ob = om + (size_t)n * 27 * HW_ + y * 96 + x;
        float dy = ob[(size_t)k9 * HW_];
        float dx = ob[(size_t)(9 + k9) * HW_];
        float ml = ob[(size_t)(18 + k9) * HW_];
        float py = (float)y + (float)(k9 / 3 - 1) + dy;
        float px = (float)x + (float)(k9 % 3 - 1) + dx;
        float fy = floorf(py), fx = floorf(px);
        s_y0[e] = (int)fy; s_x0[e] = (int)fx;
        s_wy[e] = py - fy; s_wx[e] = px - fx; s_m[e] = sigm(ml);
    }
    int w = t >> 6, lane = t & 63, lm = lane & 15, q = lane >> 4;
    const u16* Arow = A + (size_t)(w * 16 + lm) * 1152 + q * 8;
    floatx4 acc[3];
#pragma unroll
    for (int a = 0; a < 3; ++a) acc[a] = {0.f, 0.f, 0.f, 0.f};
    const u16* txn = txh + (size_t)n * HW_ * 128;
    const short8 zz = {0, 0, 0, 0, 0, 0, 0, 0};

    for (int kc = 0; kc < 18; ++kc) {
        int tap = kc >> 1, c0 = (kc & 1) * 64;
        short8 af[2];
#pragma unroll
        for (int ks = 0; ks < 2; ++ks)
            af[ks] = *reinterpret_cast<const short8*>(Arow + kc * 64 + ks * 32);
        __syncthreads();
#pragma unroll
        for (int i = 0; i < 2; ++i) {
            int id = i * 256 + t;
            if (id < 384) {
                int px = id >> 3, ch8 = id & 7;
                int ce = tap * 48 + px;
                int y0 = s_y0[ce], x0 = s_x0[ce];
                float wy = s_wy[ce], wx = s_wx[ce], m = s_m[ce];
                float w00 = (1.f - wy) * (1.f - wx) * m;
                float w01 = (1.f - wy) * wx * m;
                float w10 = wy * (1.f - wx) * m;
                float w11 = wy * wx * m;
                bool yv0 = (y0 >= 0) & (y0 < 96), yv1 = (y0 >= -1) & (y0 < 95);
                bool xv0 = (x0 >= 0) & (x0 < 96), xv1 = (x0 >= -1) & (x0 < 95);
                const u16* base = txn + (long)(y0 * 96 + x0) * 128 + c0 + ch8 * 8;
                short8 v00 = (yv0 && xv0) ? *reinterpret_cast<const short8*>(base) : zz;
                short8 v01 = (yv0 && xv1) ? *reinterpret_cast<const short8*>(base + 128) : zz;
                short8 v10 = (yv1 && xv0) ? *reinterpret_cast<const short8*>(base + 96 * 128) : zz;
                short8 v11 = (yv1 && xv1) ? *reinterpret_cast<const short8*>(base + 96 * 128 + 128) : zz;
                short8 vv;
#pragma unroll
                for (int j = 0; j < 8; ++j) {
                    float f = b2f(v00[j]) * w00 + b2f(v01[j]) * w01 +
                              b2f(v10[j]) * w10 + b2f(v11[j]) * w11;
                    vv[j] = f2b(f);
                }
                *reinterpret_cast<short8*>(&Bl[px][ch8 * 8]) = vv;
            }
        }
        __syncthreads();
#pragma unroll
        for (int ks = 0; ks < 2; ++ks)
#pragma unroll
            for (int nf = 0; nf < 3; ++nf) {
                short8 bv = *reinterpret_cast<const short8*>(&Bl[nf * 16 + lm][ks * 32 + q * 8]);
                acc[nf] = __builtin_amdgcn_mfma_f32_16x16x32_bf16(af[ks], bv, acc[nf], 0, 0, 0);
            }
    }
    int ocb = w * 16 + q * 4;
#pragma unroll
    for (int nf = 0; nf < 3; ++nf) {
        int px = px0 + nf * 16 + lm;
#pragma unroll
        for (int rr2 = 0; rr2 < 4; ++rr2) {
            int oc = ocb + rr2;
            out[((size_t)(n * CH_ + oc)) * HW_ + y * 96 + px] = acc[nf][rr2] + bias[oc];
        }
    }
}

// dual-instance dcn: grid 768
__global__ __launch_bounds__(256) void dcn_gemm2(const u16* __restrict__ X0, const u16* __restrict__ X1,
                                                 const float* __restrict__ om0, const float* __restrict__ om1,
                                                 const u16* __restrict__ A0, const u16* __restrict__ A1,
                                                 const float* __restrict__ b0, const float* __restrict__ b1,
                                                 float* __restrict__ o0, float* __restrict__ o1) {
    int inst = blockIdx.x / 384, r = blockIdx.x % 384;
    dcn_core(inst ? X1 : X0, inst ? om1 : om0, inst ? A1 : A0, inst ? b1 : b0, inst ? o1 : o0, r, threadIdx.x);
}

// ---------- fused NCF dual: corr(49)+softmax+sample; writes txh2 = concat(r, tt) ----------
__global__ __launch_bounds__(256) void ncf2(const u16* __restrict__ in0, const u16* __restrict__ in1,
                                            u16* __restrict__ out0, u16* __restrict__ out1) {
    int t = threadIdx.x;
    int inst = blockIdx.x / 576, bb = blockIdx.x % 576;
    const u16* txh = inst ? in1 : in0;
    u16* txh2 = inst ? out1 : out0;
    int gpx = bb * 32 + (t >> 3);
    int ch0 = (t & 7) * 8;
    int n = gpx / HW_, p = gpx % HW_;
    int y = p / 96, x = p % 96;
    const u16* base = txh + (size_t)n * HW_ * 128;
    short8 f1 = *reinterpret_cast<const short8*>(base + (size_t)p * 128 + 64 + ch0);
    float f1f[8];
#pragma unroll
    for (int j = 0; j < 8; ++j) f1f[j] = b2f(f1[j]);

    float corr[49];
#pragma unroll
    for (int k = 0; k < 49; ++k) {
        int yy = y + (k / 7) * 2 - 6, xx = x + (k % 7) * 2 - 6;
        float s = 0.f;
        if (yy >= 0 && yy < 96 && xx >= 0 && xx < 96) {
            short8 f2 = *reinterpret_cast<const short8*>(base + (size_t)(yy * 96 + xx) * 128 + ch0);
#pragma unroll
            for (int j = 0; j < 8; ++j) s += f1f[j] * b2f(f2[j]);
        }
        corr[k] = s;
    }
#pragma unroll
    for (int m = 1; m <= 4; m <<= 1)
#pragma unroll
        for (int k = 0; k < 49; ++k) corr[k] += __shfl_xor(corr[k], m, 64);
    float mx = -1e30f;
#pragma unroll
    for (int k = 0; k < 49; ++k) { corr[k] *= 0.125f; mx = fmaxf(mx, corr[k]); }
    float sum = 0.f;
#pragma unroll
    for (int k = 0; k < 49; ++k) { corr[k] = __expf(corr[k] - mx); sum += corr[k]; }
    float inv = 1.f / sum;
    float acc[8];
#pragma unroll
    for (int j = 0; j < 8; ++j) acc[j] = 0.f;
#pragma unroll
    for (int k = 0; k < 49; ++k) {
        int yy = y + (k / 7) * 2 - 6, xx = x + (k % 7) * 2 - 6;
        if (yy >= 0 && yy < 96 && xx >= 0 && xx < 96) {
            short8 f2 = *reinterpret_cast<const short8*>(base + (size_t)(yy * 96 + xx) * 128 + ch0);
            float a = corr[k] * inv;
#pragma unroll
            for (int j = 0; j < 8; ++j) acc[j] += a * b2f(f2[j]);
        }
    }
    u16* obase = txh2 + (size_t)n * HW_ * 128 + (size_t)p * 128;
    short8 ro;
#pragma unroll
    for (int j = 0; j < 8; ++j) ro[j] = f2b(acc[j]);
    *reinterpret_cast<short8*>(obase + ch0) = ro;
    *reinterpret_cast<short8*>(obase + 64 + ch0) = f1;
}

// ---------- dual GRU gate: inst a -> NHWC bf16, inst b -> NCHW f32 ----------
__global__ __launch_bounds__(256) void gate_dual(const float* __restrict__ dz_a, const float* __restrict__ dh_a,
                                                 const float* __restrict__ t_a, u16* __restrict__ dst_a,
                                                 const float* __restrict__ dz_b, const float* __restrict__ dh_b,
                                                 const float* __restrict__ t_b, float* __restrict__ dst_b) {
    int inst = blockIdx.x / 576, bb = blockIdx.x % 576;
    int id = bb * 256 + threadIdx.x;
    int c8 = id & 7;
    int pix = id >> 3;
    int n = pix / HW_, p = pix % HW_;
    const float* zpre = inst ? dz_b : dz_a;
    const float* hpre = inst ? dh_b : dh_a;
    const float* tt = inst ? t_b : t_a;
    if (!inst) {
        short8 vv;
#pragma unroll
        for (int j = 0; j < 8; ++j) {
            size_t idx = ((size_t)n * CH_ + c8 * 8 + j) * HW_ + p;
            float z = sigm(zpre[idx]);
            float xt = tanhf(hpre[idx]);
            vv[j] = f2b((1.f - z) * tt[idx] + z * xt);
        }
        *reinterpret_cast<short8*>(dst_a + (size_t)pix * CH_ + c8 * 8) = vv;
    } else {
#pragma unroll
        for (int j = 0; j < 8; ++j) {
            size_t idx = ((size_t)n * CH_ + c8 * 8 + j) * HW_ + p;
            float z = sigm(zpre[idx]);
            float xt = tanhf(hpre[idx]);
            dst_b[idx] = (1.f - z) * tt[idx] + z * xt;
        }
    }
}

extern "C" void kernel_launch(void* const* d_in, const int* in_sizes, int n_in,
                              void* d_out, int out_size, void* d_ws, size_t ws_size,
                              hipStream_t stream) {
    const float* x     = (const float*)d_in[0];
    const float* tpl   = (const float*)d_in[1];
    const float* w_in  = (const float*)d_in[2];
    const float* b_in  = (const float*)d_in[3];
    const float* w_out = (const float*)d_in[4];
    const float* b_out = (const float*)d_in[5];
    const float *pw[4], *pb[4], *pow_[4], *pob[4];
    for (int i = 0; i < 4; ++i) {           // 0=enh_z 1=enh_h 2=upd_z 3=upd_h
        pw[i]   = (const float*)d_in[6 + 4 * i];
        pb[i]   = (const float*)d_in[7 + 4 * i];
        pow_[i] = (const float*)d_in[8 + 4 * i];
        pob[i]  = (const float*)d_in[9 + 4 * i];
    }
    float* out_main = (float*)d_out;
    float* out_ntpl = out_main + (size_t)N_ * CIN_ * HW_;

    // ---- workspace (~55 MB of the ~268 MB available; no aliasing) ----
    u16* Aws = (u16*)d_ws;
    u16* xT     = Aws + A_TOT;                        // (N,96,96,256) bf16
    u16* txh_a  = xT + (size_t)N_ * HW_ * CIN_;       // (N,96,96,128) bf16
    u16* txh_b  = txh_a + (size_t)N_ * HW_ * C2_;
    u16* txh2_a = txh_b + (size_t)N_ * HW_ * C2_;
    u16* txh2_b = txh2_a + (size_t)N_ * HW_ * C2_;
    u16* xeh    = txh2_b + (size_t)N_ * HW_ * C2_;    // (N,96,96,64) bf16
    float* fws = (float*)(xeh + (size_t)N_ * HW_ * CH_);
    size_t off = 0;
    float* xh   = fws + off; off += (size_t)N_ * CH_ * HW_;
    float* om_a = fws + off; off += (size_t)N_ * 27 * HW_;
    float* om_b = fws + off; off += (size_t)N_ * 27 * HW_;
    float* dz_a = fws + off; off += (size_t)N_ * CH_ * HW_;
    float* dz_b = fws + off; off += (size_t)N_ * CH_ * HW_;
    float* dh_a = fws + off; off += (size_t)N_ * CH_ * HW_;
    float* dh_b = fws + off; off += (size_t)N_ * CH_ * HW_;

    cvt_weights<<<(A_TOT + 255) / 256, 256, 0, stream>>>(
        w_in, w_out, pow_[0], pow_[1], pow_[2], pow_[3], pw[0], pw[1], pw[2], pw[3], Aws);
    to_nhwc<<<2304, 256, 0, stream>>>(x, xT, CIN_);
    conv_gemm<CIN_, 64><<<384, 256, 0, stream>>>(xT, Aws + A_IN_OFF, b_in, xh);

    // instance a = enh (x32=tpl, tt=xh), instance b = upd (x32=xh, tt=tpl)
    concat_dual<<<1152, 256, 0, stream>>>(tpl, xh, txh_a, txh_b);
    conv_gemm2<<<768, 256, 0, stream>>>(txh_a, txh_b,
        Aws + A_OFF_OFF + 0 * A_OFF_SZ, Aws + A_OFF_OFF + 2 * A_OFF_SZ, pob[0], pob[2], om_a, om_b);
    dcn_gemm2<<<768, 256, 0, stream>>>(txh_a, txh_b, om_a, om_b,
        Aws + A_DCN_OFF + 0 * A_DCN_SZ, Aws + A_DCN_OFF + 2 * A_DCN_SZ, pb[0], pb[2], dz_a, dz_b);
    ncf2<<<1152, 256, 0, stream>>>(txh_a, txh_b, txh2_a, txh2_b);
    conv_gemm2<<<768, 256, 0, stream>>>(txh2_a, txh2_b,
        Aws + A_OFF_OFF + 1 * A_OFF_SZ, Aws + A_OFF_OFF + 3 * A_OFF_SZ, pob[1], pob[3], om_a, om_b);
    dcn_gemm2<<<768, 256, 0, stream>>>(txh2_a, txh2_b, om_a, om_b,
        Aws + A_DCN_OFF + 1 * A_DCN_SZ, Aws + A_DCN_OFF + 3 * A_DCN_SZ, pb[1], pb[3], dh_a, dh_b);
    gate_dual<<<1152, 256, 0, stream>>>(dz_a, dh_a, xh, xeh, dz_b, dh_b, tpl, out_ntpl);

    conv_gemm<CH_, 256><<<1536, 256, 0, stream>>>(xeh, Aws + A_OUT_OFF, b_out, out_main);
}

// Round 9
// 365.831 us; speedup vs baseline: 11.9471x; 1.0060x over previous
//
#include <hip/hip_runtime.h>
#include <hip/hip_bf16.h>

typedef __hip_bfloat16 bf16;
typedef unsigned short u16;
typedef unsigned int u32;
typedef __attribute__((ext_vector_type(8))) short short8;
typedef __attribute__((ext_vector_type(4))) float floatx4;

constexpr int N_ = 2, H_ = 96, W_ = 96, HW_ = H_ * W_;
constexpr int CIN_ = 256, CH_ = 64, C2_ = 128;

__device__ __forceinline__ float sigm(float v) { return 1.0f / (1.0f + __expf(-v)); }
__device__ __forceinline__ short f2b(float v) { bf16 h = __float2bfloat16(v); return *reinterpret_cast<short*>(&h); }
__device__ __forceinline__ float b2f(short s) {
    union { u32 i; float f; } v; v.i = ((u32)(u16)s) << 16; return v.f;
}

// ---------- bf16 weight regions inside d_ws ----------
// conv A[m][k = tap*IC + ic];  dcn A[m][k = tap*128 + c]  (both tap-major)
constexpr int A_IN_OFF = 0,                         A_IN_SZ  = 64 * 2304;
constexpr int A_OUT_OFF = A_IN_OFF + A_IN_SZ,       A_OUT_SZ = 256 * 576;
constexpr int A_OFF_OFF = A_OUT_OFF + A_OUT_SZ,     A_OFF_SZ = 64 * 1152;   // 27 padded to 64
constexpr int A_DCN_OFF = A_OFF_OFF + 4 * A_OFF_SZ, A_DCN_SZ = 64 * 1152;
constexpr int A_TOT = A_DCN_OFF + 4 * A_DCN_SZ;     // 884736 shorts = 1.77 MB

__global__ __launch_bounds__(256) void cvt_weights(
        const float* __restrict__ w_in, const float* __restrict__ w_out,
        const float* __restrict__ ow0, const float* __restrict__ ow1,
        const float* __restrict__ ow2, const float* __restrict__ ow3,
        const float* __restrict__ w0, const float* __restrict__ w1,
        const float* __restrict__ w2, const float* __restrict__ w3,
        u16* __restrict__ dst) {
    int id = blockIdx.x * 256 + threadIdx.x;
    if (id >= A_TOT) return;
    float v;
    if (id < A_OUT_OFF) {
        int l = id; int m = l / 2304, k = l % 2304; int tap = k >> 8, ic = k & 255;
        v = w_in[m * 2304 + ic * 9 + tap];
    } else if (id < A_OFF_OFF) {
        int l = id - A_OUT_OFF; int m = l / 576, k = l % 576; int tap = k / 64, ic = k & 63;
        v = w_out[m * 576 + ic * 9 + tap];
    } else if (id < A_DCN_OFF) {
        int l = id - A_OFF_OFF; int i = l / A_OFF_SZ, l2 = l % A_OFF_SZ;
        int m = l2 / 1152, k = l2 % 1152; int tap = k >> 7, ic = k & 127;
        const float* s = (i == 0) ? ow0 : (i == 1) ? ow1 : (i == 2) ? ow2 : ow3;
        v = (m < 27) ? s[m * 1152 + ic * 9 + tap] : 0.f;
    } else {
        int l = id - A_DCN_OFF; int i = l / A_DCN_SZ, l2 = l % A_DCN_SZ;
        int m = l2 / 1152, k = l2 % 1152; int tap = k >> 7, c = k & 127;
        const float* s = (i == 0) ? w0 : (i == 1) ? w1 : (i == 2) ? w2 : w3;
        v = s[m * 1152 + c * 9 + tap];
    }
    short sb = f2b(v);
    dst[id] = *reinterpret_cast<u16*>(&sb);
}

// ---------- NCHW f32 -> NHWC bf16 ----------
__global__ __launch_bounds__(256) void to_nhwc(const float* __restrict__ src, u16* __restrict__ dst, int C) {
    int id = blockIdx.x * 256 + threadIdx.x;
    int c8n = C >> 3;
    if (id >= N_ * HW_ * c8n) return;
    int c8 = id % c8n;
    int pix = id / c8n;
    int n = pix / HW_, p = pix % HW_;
    const float* s = src + ((size_t)n * C + c8 * 8) * HW_ + p;
    short8 vv;
#pragma unroll
    for (int j = 0; j < 8; ++j) vv[j] = f2b(s[(size_t)j * HW_]);
    *reinterpret_cast<short8*>(dst + (size_t)pix * C + c8 * 8) = vv;
}

// ---------- dual concat: txh_a = concat(tpl, xh), txh_b = concat(xh, tpl) ----------
__global__ __launch_bounds__(256) void concat_dual(const float* __restrict__ tpl, const float* __restrict__ xh,
                                                   u16* __restrict__ ta, u16* __restrict__ tb) {
    int id = blockIdx.x * 256 + threadIdx.x;
    if (id >= N_ * HW_ * 16) return;
    int c8 = id & 15;
    int pix = id >> 4;
    int n = pix / HW_, p = pix % HW_;
    int c = c8 * 8;
    const float* s = (c < 64) ? tpl + ((size_t)n * 64 + c) * HW_ + p
                              : xh + ((size_t)n * 64 + (c - 64)) * HW_ + p;
    short8 vv;
#pragma unroll
    for (int j = 0; j < 8; ++j) vv[j] = f2b(s[(size_t)j * HW_]);
    *reinterpret_cast<short8*>(ta + (size_t)pix * 128 + c) = vv;
    *reinterpret_cast<short8*>(tb + (size_t)pix * 128 + ((c + 64) & 127)) = vv;
}

// ---------- core implicit-GEMM body (shared by single & dual kernels) ----------
template <int IC, int OCST>
__device__ __forceinline__ void conv_core(const u16* __restrict__ X,
                                          const u16* __restrict__ A,
                                          const float* __restrict__ bias,
                                          float* __restrict__ out,
                                          int r, int mt, int t) {
    constexpr int K = IC * 9;
    constexpr int ICC = IC / 64;
    __shared__ __align__(16) u16 Xl[3][50][72];
    int n = r / 192;
    int rr = r % 192;
    int y = rr >> 1, px0 = (rr & 1) * 48;
    int w = t >> 6, lane = t & 63, lm = lane & 15, q = lane >> 4;
    const u16* Arow = A + (size_t)(mt * 64 + w * 16 + lm) * K + q * 8;
    floatx4 acc[3];
#pragma unroll
    for (int a = 0; a < 3; ++a) acc[a] = {0.f, 0.f, 0.f, 0.f};
    const short8 zz = {0, 0, 0, 0, 0, 0, 0, 0};

    for (int icc = 0; icc < ICC; ++icc) {
        short8 af[9][2];
#pragma unroll
        for (int tap = 0; tap < 9; ++tap)
#pragma unroll
            for (int ks = 0; ks < 2; ++ks)
                af[tap][ks] = *reinterpret_cast<const short8*>(Arow + tap * IC + icc * 64 + ks * 32);
        __syncthreads();
#pragma unroll
        for (int it = 0; it < 5; ++it) {
            int id = it * 256 + t;
            if (id < 1200) {
                int ch8 = id & 7;
                int tmp = id >> 3;
                int pxl = tmp % 50, row = tmp / 50;
                int xg = px0 - 1 + pxl;
                int yg = y - 1 + row;
                bool vld = (yg >= 0) && (yg < 96) && (xg >= 0) && (xg < 96);
                short8 vv = zz;
                if (vld)
                    vv = *reinterpret_cast<const short8*>(
                        X + ((size_t)(n * HW_ + yg * 96 + xg)) * IC + icc * 64 + ch8 * 8);
                *reinterpret_cast<short8*>(&Xl[row][pxl][ch8 * 8]) = vv;
            }
        }
        __syncthreads();
#pragma unroll
        for (int tap = 0; tap < 9; ++tap) {
            int ky = tap / 3, kx = tap % 3;
#pragma unroll
            for (int ks = 0; ks < 2; ++ks) {
#pragma unroll
                for (int nf = 0; nf < 3; ++nf) {
                    short8 bv = *reinterpret_cast<const short8*>(&Xl[ky][nf * 16 + lm + kx][ks * 32 + q * 8]);
                    acc[nf] = __builtin_amdgcn_mfma_f32_16x16x32_bf16(af[tap][ks], bv, acc[nf], 0, 0, 0);
                }
            }
        }
    }
    int ocb = mt * 64 + w * 16 + q * 4;
#pragma unroll
    for (int nf = 0; nf < 3; ++nf) {
        int px = px0 + nf * 16 + lm;
#pragma unroll
        for (int rr2 = 0; rr2 < 4; ++rr2) {
            int oc = ocb + rr2;
            if (oc < OCST)
                out[((size_t)(n * OCST + oc)) * HW_ + y * 96 + px] = acc[nf][rr2] + bias[oc];
        }
    }
}

template <int IC, int OCST>
__global__ __launch_bounds__(256) void conv_gemm(const u16* __restrict__ X,
                                                 const u16* __restrict__ A,
                                                 const float* __restrict__ bias,
                                                 float* __restrict__ out) {
    conv_core<IC, OCST>(X, A, bias, out, blockIdx.x % 384, blockIdx.x / 384, threadIdx.x);
}

// dual-instance offset conv: grid 768, inst = gx/384
__global__ __launch_bounds__(256) void conv_gemm2(const u16* __restrict__ X0, const u16* __restrict__ X1,
                                                  const u16* __restrict__ A0, const u16* __restrict__ A1,
                                                  const float* __restrict__ b0, const float* __restrict__ b1,
                                                  float* __restrict__ o0, float* __restrict__ o1) {
    int inst = blockIdx.x / 384, r = blockIdx.x % 384;
    conv_core<C2_, 27>(inst ? X1 : X0, inst ? A1 : A0, inst ? b1 : b0, inst ? o1 : o0, r, 0, threadIdx.x);
}

// ---------- fused deformable conv core ----------
__device__ __forceinline__ void dcn_core(const u16* __restrict__ txh,
                                         const float* __restrict__ om,
                                         const u16* __restrict__ A,
                                         const float* __restrict__ bias,
                                         float* __restrict__ out,
                                         int r, int t) {
    __shared__ __align__(16) u16 Bl[48][72];
    __shared__ float s_wy[432], s_wx[432], s_m[432];
    __shared__ int s_y0[432], s_x0[432];
    int n = r / 192;
    int rr = r % 192;
    int y = rr >> 1, px0 = (rr & 1) * 48;
    for (int e = t; e < 432; e += 256) {
        int k9 = e / 48, xl = e % 48;
        int x = px0 + xl;
        const float* ob = om + (size_t)n * 27 * HW_ + y * 96 + x;
        float dy = ob[(size_t)k9 * HW_];
        float dx = ob[(size_t)(9 + k9) * HW_];
        float ml = ob[(size_t)(18 + k9) * HW_];
        float py = (float)y + (float)(k9 / 3 - 1) + dy;
        float px = (float)x + (float)(k9 % 3 - 1) + dx;
        float fy = floorf(py), fx = floorf(px);
        s_y0[e] = (int)fy; s_x0[e] = (int)fx;
        s_wy[e] = py - fy; s_wx[e] = px - fx; s_m[e] = sigm(ml);
    }
    int w = t >> 6, lane = t & 63, lm = lane & 15, q = lane >> 4;
    const u16* Arow = A + (size_t)(w * 16 + lm) * 1152 + q * 8;
    floatx4 acc[3];
#pragma unroll
    for (int a = 0; a < 3; ++a) acc[a] = {0.f, 0.f, 0.f, 0.f};
    const u16* txn = txh + (size_t)n * HW_ * 128;
    const short8 zz = {0, 0, 0, 0, 0, 0, 0, 0};

    for (int kc = 0; kc < 18; ++kc) {
        int tap = kc >> 1, c0 = (kc & 1) * 64;
        short8 af[2];
#pragma unroll
        for (int ks = 0; ks < 2; ++ks)
            af[ks] = *reinterpret_cast<const short8*>(Arow + kc * 64 + ks * 32);
        __syncthreads();
#pragma unroll
        for (int i = 0; i < 2; ++i) {
            int id = i * 256 + t;
            if (id < 384) {
                int px = id >> 3, ch8 = id & 7;
                int ce = tap * 48 + px;
                int y0 = s_y0[ce], x0 = s_x0[ce];
                float wy = s_wy[ce], wx = s_wx[ce], m = s_m[ce];
                float w00 = (1.f - wy) * (1.f - wx) * m;
                float w01 = (1.f - wy) * wx * m;
                float w10 = wy * (1.f - wx) * m;
                float w11 = wy * wx * m;
                bool yv0 = (y0 >= 0) & (y0 < 96), yv1 = (y0 >= -1) & (y0 < 95);
                bool xv0 = (x0 >= 0) & (x0 < 96), xv1 = (x0 >= -1) & (x0 < 95);
                const u16* base = txn + (long)(y0 * 96 + x0) * 128 + c0 + ch8 * 8;
                short8 v00 = (yv0 && xv0) ? *reinterpret_cast<const short8*>(base) : zz;
                short8 v01 = (yv0 && xv1) ? *reinterpret_cast<const short8*>(base + 128) : zz;
                short8 v10 = (yv1 && xv0) ? *reinterpret_cast<const short8*>(base + 96 * 128) : zz;
                short8 v11 = (yv1 && xv1) ? *reinterpret_cast<const short8*>(base + 96 * 128 + 128) : zz;
                short8 vv;
#pragma unroll
                for (int j = 0; j < 8; ++j) {
                    float f = b2f(v00[j]) * w00 + b2f(v01[j]) * w01 +
                              b2f(v10[j]) * w10 + b2f(v11[j]) * w11;
                    vv[j] = f2b(f);
                }
                *reinterpret_cast<short8*>(&Bl[px][ch8 * 8]) = vv;
            }
        }
        __syncthreads();
#pragma unroll
        for (int ks = 0; ks < 2; ++ks)
#pragma unroll
            for (int nf = 0; nf < 3; ++nf) {
                short8 bv = *reinterpret_cast<const short8*>(&Bl[nf * 16 + lm][ks * 32 + q * 8]);
                acc[nf] = __builtin_amdgcn_mfma_f32_16x16x32_bf16(af[ks], bv, acc[nf], 0, 0, 0);
            }
    }
    int ocb = w * 16 + q * 4;
#pragma unroll
    for (int nf = 0; nf < 3; ++nf) {
        int px = px0 + nf * 16 + lm;
#pragma unroll
        for (int rr2 = 0; rr2 < 4; ++rr2) {
            int oc = ocb + rr2;
            out[((size_t)(n * CH_ + oc)) * HW_ + y * 96 + px] = acc[nf][rr2] + bias[oc];
        }
    }
}

// dual-instance dcn: grid 768
__global__ __launch_bounds__(256) void dcn_gemm2(const u16* __restrict__ X0, const u16* __restrict__ X1,
                                                 const float* __restrict__ om0, const float* __restrict__ om1,
                                                 const u16* __restrict__ A0, const u16* __restrict__ A1,
                                                 const float* __restrict__ b0, const float* __restrict__ b1,
                                                 float* __restrict__ o0, float* __restrict__ o1) {
    int inst = blockIdx.x / 384, r = blockIdx.x % 384;
    dcn_core(inst ? X1 : X0, inst ? om1 : om0, inst ? A1 : A0, inst ? b1 : b0, inst ? o1 : o0, r, threadIdx.x);
}

// ---------- fused NCF v2: taps-in-threads, corr/attn in LDS (no spills, 6 shfls) ----------
// txh = concat(f2 [ch0..63], f1=tt [ch64..127]) NHWC bf16; out txh2 = concat(r, tt).
// 32 px/block, 8 threads/px. Phase1: thread j computes full 64-ch dots for taps j,j+8,..
// Phase2: softmax pieces + 3-stage shfl; attn back to LDS. Phase3: thread j = ch slice j*8.
__global__ __launch_bounds__(256) void ncf2(const u16* __restrict__ in0, const u16* __restrict__ in1,
                                            u16* __restrict__ out0, u16* __restrict__ out1) {
    __shared__ float sc[32][52];
    int t = threadIdx.x;
    int inst = blockIdx.x / 576, bb = blockIdx.x % 576;
    const u16* txh = inst ? in1 : in0;
    u16* txh2 = inst ? out1 : out0;
    int lp = t >> 3, j = t & 7;
    int gpx = bb * 32 + lp;
    int n = gpx / HW_, p = gpx % HW_;
    int y = p / 96, x = p % 96;
    const u16* base = txh + (size_t)n * HW_ * 128;
    const u16* f1p = base + (size_t)p * 128 + 64;

    // f1 -> fp32 regs (64 VGPRs, phase-1 only)
    float f1f[64];
#pragma unroll
    for (int c8 = 0; c8 < 8; ++c8) {
        short8 a = *reinterpret_cast<const short8*>(f1p + c8 * 8);
#pragma unroll
        for (int u = 0; u < 8; ++u) f1f[c8 * 8 + u] = b2f(a[u]);
    }
    // phase 1: full dots for taps j, j+8, ...
    for (int k = j; k < 49; k += 8) {
        int yy = y + (k / 7) * 2 - 6, xx = x + (k % 7) * 2 - 6;
        float s = 0.f;
        if (yy >= 0 && yy < 96 && xx >= 0 && xx < 96) {
            const u16* f2p = base + (size_t)(yy * 96 + xx) * 128;
#pragma unroll
            for (int c8 = 0; c8 < 8; ++c8) {
                short8 b = *reinterpret_cast<const short8*>(f2p + c8 * 8);
#pragma unroll
                for (int u = 0; u < 8; ++u) s += f1f[c8 * 8 + u] * b2f(b[u]);
            }
        }
        sc[lp][k] = s * 0.125f;
    }
    // phase 2: softmax over 49 (thread reads only its own taps; shfl merges the 8 slices)
    float mx = -1e30f;
    for (int k = j; k < 49; k += 8) mx = fmaxf(mx, sc[lp][k]);
#pragma unroll
    for (int m = 1; m <= 4; m <<= 1) mx = fmaxf(mx, __shfl_xor(mx, m, 64));
    float e[7];
    float sum = 0.f;
    int cnt = 0;
    for (int k = j; k < 49; k += 8) { e[cnt] = __expf(sc[lp][k] - mx); sum += e[cnt]; ++cnt; }
#pragma unroll
    for (int m = 1; m <= 4; m <<= 1) sum += __shfl_xor(sum, m, 64);
    float inv = 1.f / sum;
    cnt = 0;
    for (int k = j; k < 49; k += 8) sc[lp][k] = e[cnt++] * inv;
    __syncthreads();
    // phase 3: thread j accumulates channels j*8..j*8+7 over all 49 taps
    int ch0 = j * 8;
    float acc[8];
#pragma unroll
    for (int u = 0; u < 8; ++u) acc[u] = 0.f;
#pragma unroll
    for (int k = 0; k < 49; ++k) {
        int yy = y + (k / 7) * 2 - 6, xx = x + (k % 7) * 2 - 6;
        if (yy >= 0 && yy < 96 && xx >= 0 && xx < 96) {
            float a = sc[lp][k];
            short8 f2 = *reinterpret_cast<const short8*>(base + (size_t)(yy * 96 + xx) * 128 + ch0);
#pragma unroll
            for (int u = 0; u < 8; ++u) acc[u] += a * b2f(f2[u]);
        }
    }
    u16* obase = txh2 + (size_t)n * HW_ * 128 + (size_t)p * 128;
    short8 ro;
#pragma unroll
    for (int u = 0; u < 8; ++u) ro[u] = f2b(acc[u]);
    *reinterpret_cast<short8*>(obase + ch0) = ro;
    *reinterpret_cast<short8*>(obase + 64 + ch0) =
        *reinterpret_cast<const short8*>(f1p + ch0);   // tt passthrough
}

// ---------- dual GRU gate: inst a -> NHWC bf16, inst b -> NCHW f32 ----------
__global__ __launch_bounds__(256) void gate_dual(const float* __restrict__ dz_a, const float* __restrict__ dh_a,
                                                 const float* __restrict__ t_a, u16* __restrict__ dst_a,
                                                 const float* __restrict__ dz_b, const float* __restrict__ dh_b,
                                                 const float* __restrict__ t_b, float* __restrict__ dst_b) {
    int inst = blockIdx.x / 576, bb = blockIdx.x % 576;
    int id = bb * 256 + threadIdx.x;
    int c8 = id & 7;
    int pix = id >> 3;
    int n = pix / HW_, p = pix % HW_;
    const float* zpre = inst ? dz_b : dz_a;
    const float* hpre = inst ? dh_b : dh_a;
    const float* tt = inst ? t_b : t_a;
    if (!inst) {
        short8 vv;
#pragma unroll
        for (int j = 0; j < 8; ++j) {
            size_t idx = ((size_t)n * CH_ + c8 * 8 + j) * HW_ + p;
            float z = sigm(zpre[idx]);
            float xt = tanhf(hpre[idx]);
            vv[j] = f2b((1.f - z) * tt[idx] + z * xt);
        }
        *reinterpret_cast<short8*>(dst_a + (size_t)pix * CH_ + c8 * 8) = vv;
    } else {
#pragma unroll
        for (int j = 0; j < 8; ++j) {
            size_t idx = ((size_t)n * CH_ + c8 * 8 + j) * HW_ + p;
            float z = sigm(zpre[idx]);
            float xt = tanhf(hpre[idx]);
            dst_b[idx] = (1.f - z) * tt[idx] + z * xt;
        }
    }
}

extern "C" void kernel_launch(void* const* d_in, const int* in_sizes, int n_in,
                              void* d_out, int out_size, void* d_ws, size_t ws_size,
                              hipStream_t stream) {
    const float* x     = (const float*)d_in[0];
    const float* tpl   = (const float*)d_in[1];
    const float* w_in  = (const float*)d_in[2];
    const float* b_in  = (const float*)d_in[3];
    const float* w_out = (const float*)d_in[4];
    const float* b_out = (const float*)d_in[5];
    const float *pw[4], *pb[4], *pow_[4], *pob[4];
    for (int i = 0; i < 4; ++i) {           // 0=enh_z 1=enh_h 2=upd_z 3=upd_h
        pw[i]   = (const float*)d_in[6 + 4 * i];
        pb[i]   = (const float*)d_in[7 + 4 * i];
        pow_[i] = (const float*)d_in[8 + 4 * i];
        pob[i]  = (const float*)d_in[9 + 4 * i];
    }
    float* out_main = (float*)d_out;
    float* out_ntpl = out_main + (size_t)N_ * CIN_ * HW_;

    // ---- workspace (~55 MB; no aliasing) ----
    u16* Aws = (u16*)d_ws;
    u16* xT     = Aws + A_TOT;                        // (N,96,96,256) bf16
    u16* txh_a  = xT + (size_t)N_ * HW_ * CIN_;       // (N,96,96,128) bf16
    u16* txh_b  = txh_a + (size_t)N_ * HW_ * C2_;
    u16* txh2_a = txh_b + (size_t)N_ * HW_ * C2_;
    u16* txh2_b = txh2_a + (size_t)N_ * HW_ * C2_;
    u16* xeh    = txh2_b + (size_t)N_ * HW_ * C2_;    // (N,96,96,64) bf16
    float* fws = (float*)(xeh + (size_t)N_ * HW_ * CH_);
    size_t off = 0;
    float* xh   = fws + off; off += (size_t)N_ * CH_ * HW_;
    float* om_a = fws + off; off += (size_t)N_ * 27 * HW_;
    float* om_b = fws + off; off += (size_t)N_ * 27 * HW_;
    float* dz_a = fws + off; off += (size_t)N_ * CH_ * HW_;
    float* dz_b = fws + off; off += (size_t)N_ * CH_ * HW_;
    float* dh_a = fws + off; off += (size_t)N_ * CH_ * HW_;
    float* dh_b = fws + off; off += (size_t)N_ * CH_ * HW_;

    cvt_weights<<<(A_TOT + 255) / 256, 256, 0, stream>>>(
        w_in, w_out, pow_[0], pow_[1], pow_[2], pow_[3], pw[0], pw[1], pw[2], pw[3], Aws);
    to_nhwc<<<2304, 256, 0, stream>>>(x, xT, CIN_);
    conv_gemm<CIN_, 64><<<384, 256, 0, stream>>>(xT, Aws + A_IN_OFF, b_in, xh);

    // instance a = enh (x32=tpl, tt=xh), instance b = upd (x32=xh, tt=tpl)
    concat_dual<<<1152, 256, 0, stream>>>(tpl, xh, txh_a, txh_b);
    conv_gemm2<<<768, 256, 0, stream>>>(txh_a, txh_b,
        Aws + A_OFF_OFF + 0 * A_OFF_SZ, Aws + A_OFF_OFF + 2 * A_OFF_SZ, pob[0], pob[2], om_a, om_b);
    dcn_gemm2<<<768, 256, 0, stream>>>(txh_a, txh_b, om_a, om_b,
        Aws + A_DCN_OFF + 0 * A_DCN_SZ, Aws + A_DCN_OFF + 2 * A_DCN_SZ, pb[0], pb[2], dz_a, dz_b);
    ncf2<<<1152, 256, 0, stream>>>(txh_a, txh_b, txh2_a, txh2_b);
    conv_gemm2<<<768, 256, 0, stream>>>(txh2_a, txh2_b,
        Aws + A_OFF_OFF + 1 * A_OFF_SZ, Aws + A_OFF_OFF + 3 * A_OFF_SZ, pob[1], pob[3], om_a, om_b);
    dcn_gemm2<<<768, 256, 0, stream>>>(txh2_a, txh2_b, om_a, om_b,
        Aws + A_DCN_OFF + 1 * A_DCN_SZ, Aws + A_DCN_OFF + 3 * A_DCN_SZ, pb[1], pb[3], dh_a, dh_b);
    gate_dual<<<1152, 256, 0, stream>>>(dz_a, dh_a, xh, xeh, dz_b, dh_b, tpl, out_ntpl);

    conv_gemm<CH_, 256><<<1536, 256, 0, stream>>>(xeh, Aws + A_OUT_OFF, b_out, out_main);
}

// Round 11
// 364.290 us; speedup vs baseline: 11.9976x; 1.0042x over previous
//
#include <hip/hip_runtime.h>
#include <hip/hip_bf16.h>

typedef __hip_bfloat16 bf16;
typedef unsigned short u16;
typedef unsigned int u32;
typedef __attribute__((ext_vector_type(8))) short short8;
typedef __attribute__((ext_vector_type(4))) short bh4;
typedef __attribute__((ext_vector_type(4))) float floatx4;

constexpr int N_ = 2, H_ = 96, W_ = 96, HW_ = H_ * W_;
constexpr int CIN_ = 256, CH_ = 64, C2_ = 128;

__device__ __forceinline__ float sigm(float v) { return 1.0f / (1.0f + __expf(-v)); }
__device__ __forceinline__ short f2b(float v) { bf16 h = __float2bfloat16(v); return *reinterpret_cast<short*>(&h); }
__device__ __forceinline__ float b2f(short s) {
    union { u32 i; float f; } v; v.i = ((u32)(u16)s) << 16; return v.f;
}

// ---------- bf16 weight regions inside d_ws ----------
// conv A[m][k = tap*IC + ic];  dcn A[m][k = tap*128 + c]  (both tap-major)
constexpr int A_IN_OFF = 0,                         A_IN_SZ  = 64 * 2304;
constexpr int A_OUT_OFF = A_IN_OFF + A_IN_SZ,       A_OUT_SZ = 256 * 576;
constexpr int A_OFF_OFF = A_OUT_OFF + A_OUT_SZ,     A_OFF_SZ = 64 * 1152;   // 27 padded to 64
constexpr int A_DCN_OFF = A_OFF_OFF + 4 * A_OFF_SZ, A_DCN_SZ = 64 * 1152;
constexpr int A_TOT = A_DCN_OFF + 4 * A_DCN_SZ;     // 884736 shorts = 1.77 MB

__global__ __launch_bounds__(256) void cvt_weights(
        const float* __restrict__ w_in, const float* __restrict__ w_out,
        const float* __restrict__ ow0, const float* __restrict__ ow1,
        const float* __restrict__ ow2, const float* __restrict__ ow3,
        const float* __restrict__ w0, const float* __restrict__ w1,
        const float* __restrict__ w2, const float* __restrict__ w3,
        u16* __restrict__ dst) {
    int id = blockIdx.x * 256 + threadIdx.x;
    if (id >= A_TOT) return;
    float v;
    if (id < A_OUT_OFF) {
        int l = id; int m = l / 2304, k = l % 2304; int tap = k >> 8, ic = k & 255;
        v = w_in[m * 2304 + ic * 9 + tap];
    } else if (id < A_OFF_OFF) {
        int l = id - A_OUT_OFF; int m = l / 576, k = l % 576; int tap = k / 64, ic = k & 63;
        v = w_out[m * 576 + ic * 9 + tap];
    } else if (id < A_DCN_OFF) {
        int l = id - A_OFF_OFF; int i = l / A_OFF_SZ, l2 = l % A_OFF_SZ;
        int m = l2 / 1152, k = l2 % 1152; int tap = k >> 7, ic = k & 127;
        const float* s = (i == 0) ? ow0 : (i == 1) ? ow1 : (i == 2) ? ow2 : ow3;
        v = (m < 27) ? s[m * 1152 + ic * 9 + tap] : 0.f;
    } else {
        int l = id - A_DCN_OFF; int i = l / A_DCN_SZ, l2 = l % A_DCN_SZ;
        int m = l2 / 1152, k = l2 % 1152; int tap = k >> 7, c = k & 127;
        const float* s = (i == 0) ? w0 : (i == 1) ? w1 : (i == 2) ? w2 : w3;
        v = s[m * 1152 + c * 9 + tap];
    }
    short sb = f2b(v);
    dst[id] = *reinterpret_cast<u16*>(&sb);
}

// ---------- NCHW f32 -> NHWC bf16 ----------
__global__ __launch_bounds__(256) void to_nhwc(const float* __restrict__ src, u16* __restrict__ dst, int C) {
    int id = blockIdx.x * 256 + threadIdx.x;
    int c8n = C >> 3;
    if (id >= N_ * HW_ * c8n) return;
    int c8 = id % c8n;
    int pix = id / c8n;
    int n = pix / HW_, p = pix % HW_;
    const float* s = src + ((size_t)n * C + c8 * 8) * HW_ + p;
    short8 vv;
#pragma unroll
    for (int j = 0; j < 8; ++j) vv[j] = f2b(s[(size_t)j * HW_]);
    *reinterpret_cast<short8*>(dst + (size_t)pix * C + c8 * 8) = vv;
}

// ---------- dual concat: txh_a = concat(tpl, xh), txh_b = concat(xh, tpl) ----------
__global__ __launch_bounds__(256) void concat_dual(const float* __restrict__ tpl, const float* __restrict__ xh,
                                                   u16* __restrict__ ta, u16* __restrict__ tb) {
    int id = blockIdx.x * 256 + threadIdx.x;
    if (id >= N_ * HW_ * 16) return;
    int c8 = id & 15;
    int pix = id >> 4;
    int n = pix / HW_, p = pix % HW_;
    int c = c8 * 8;
    const float* s = (c < 64) ? tpl + ((size_t)n * 64 + c) * HW_ + p
                              : xh + ((size_t)n * 64 + (c - 64)) * HW_ + p;
    short8 vv;
#pragma unroll
    for (int j = 0; j < 8; ++j) vv[j] = f2b(s[(size_t)j * HW_]);
    *reinterpret_cast<short8*>(ta + (size_t)pix * 128 + c) = vv;
    *reinterpret_cast<short8*>(tb + (size_t)pix * 128 + ((c + 64) & 127)) = vv;
}

// ---------- core implicit-GEMM body (shared by single & dual kernels) ----------
template <int IC, int OCST>
__device__ __forceinline__ void conv_core(const u16* __restrict__ X,
                                          const u16* __restrict__ A,
                                          const float* __restrict__ bias,
                                          float* __restrict__ out,
                                          int r, int mt, int t) {
    constexpr int K = IC * 9;
    constexpr int ICC = IC / 64;
    __shared__ __align__(16) u16 Xl[3][50][72];
    int n = r / 192;
    int rr = r % 192;
    int y = rr >> 1, px0 = (rr & 1) * 48;
    int w = t >> 6, lane = t & 63, lm = lane & 15, q = lane >> 4;
    const u16* Arow = A + (size_t)(mt * 64 + w * 16 + lm) * K + q * 8;
    floatx4 acc[3];
#pragma unroll
    for (int a = 0; a < 3; ++a) acc[a] = {0.f, 0.f, 0.f, 0.f};
    const short8 zz = {0, 0, 0, 0, 0, 0, 0, 0};

    for (int icc = 0; icc < ICC; ++icc) {
        short8 af[9][2];
#pragma unroll
        for (int tap = 0; tap < 9; ++tap)
#pragma unroll
            for (int ks = 0; ks < 2; ++ks)
                af[tap][ks] = *reinterpret_cast<const short8*>(Arow + tap * IC + icc * 64 + ks * 32);
        __syncthreads();
#pragma unroll
        for (int it = 0; it < 5; ++it) {
            int id = it * 256 + t;
            if (id < 1200) {
                int ch8 = id & 7;
                int tmp = id >> 3;
                int pxl = tmp % 50, row = tmp / 50;
                int xg = px0 - 1 + pxl;
                int yg = y - 1 + row;
                bool vld = (yg >= 0) && (yg < 96) && (xg >= 0) && (xg < 96);
                short8 vv = zz;
                if (vld)
                    vv = *reinterpret_cast<const short8*>(
                        X + ((size_t)(n * HW_ + yg * 96 + xg)) * IC + icc * 64 + ch8 * 8);
                *reinterpret_cast<short8*>(&Xl[row][pxl][ch8 * 8]) = vv;
            }
        }
        __syncthreads();
#pragma unroll
        for (int tap = 0; tap < 9; ++tap) {
            int ky = tap / 3, kx = tap % 3;
#pragma unroll
            for (int ks = 0; ks < 2; ++ks) {
#pragma unroll
                for (int nf = 0; nf < 3; ++nf) {
                    short8 bv = *reinterpret_cast<const short8*>(&Xl[ky][nf * 16 + lm + kx][ks * 32 + q * 8]);
                    acc[nf] = __builtin_amdgcn_mfma_f32_16x16x32_bf16(af[tap][ks], bv, acc[nf], 0, 0, 0);
                }
            }
        }
    }
    int ocb = mt * 64 + w * 16 + q * 4;
#pragma unroll
    for (int nf = 0; nf < 3; ++nf) {
        int px = px0 + nf * 16 + lm;
#pragma unroll
        for (int rr2 = 0; rr2 < 4; ++rr2) {
            int oc = ocb + rr2;
            if (oc < OCST)
                out[((size_t)(n * OCST + oc)) * HW_ + y * 96 + px] = acc[nf][rr2] + bias[oc];
        }
    }
}

template <int IC, int OCST>
__global__ __launch_bounds__(256) void conv_gemm(const u16* __restrict__ X,
                                                 const u16* __restrict__ A,
                                                 const float* __restrict__ bias,
                                                 float* __restrict__ out) {
    conv_core<IC, OCST>(X, A, bias, out, blockIdx.x % 384, blockIdx.x / 384, threadIdx.x);
}

// dual-instance offset conv: grid 768, inst = gx/384
__global__ __launch_bounds__(256) void conv_gemm2(const u16* __restrict__ X0, const u16* __restrict__ X1,
                                                  const u16* __restrict__ A0, const u16* __restrict__ A1,
                                                  const float* __restrict__ b0, const float* __restrict__ b1,
                                                  float* __restrict__ o0, float* __restrict__ o1) {
    int inst = blockIdx.x / 384, r = blockIdx.x % 384;
    conv_core<C2_, 27>(inst ? X1 : X0, inst ? A1 : A0, inst ? b1 : b0, inst ? o1 : o0, r, 0, threadIdx.x);
}

// ---------- fused deformable conv core ----------
__device__ __forceinline__ void dcn_core(const u16* __restrict__ txh,
                                         const float* __restrict__ om,
                                         const u16* __restrict__ A,
                                         const float* __restrict__ bias,
                                         float* __restrict__ out,
                                         int r, int t) {
    __shared__ __align__(16) u16 Bl[48][72];
    __shared__ float s_wy[432], s_wx[432], s_m[432];
    __shared__ int s_y0[432], s_x0[432];
    int n = r / 192;
    int rr = r % 192;
    int y = rr >> 1, px0 = (rr & 1) * 48;
    for (int e = t; e < 432; e += 256) {
        int k9 = e / 48, xl = e % 48;
        int x = px0 + xl;
        const float* ob = om + (size_t)n * 27 * HW_ + y * 96 + x;
        float dy = ob[(size_t)k9 * HW_];
        float dx = ob[(size_t)(9 + k9) * HW_];
        float ml = ob[(size_t)(18 + k9) * HW_];
        float py = (float)y + (float)(k9 / 3 - 1) + dy;
        float px = (float)x + (float)(k9 % 3 - 1) + dx;
        float fy = floorf(py), fx = floorf(px);
        s_y0[e] = (int)fy; s_x0[e] = (int)fx;
        s_wy[e] = py - fy; s_wx[e] = px - fx; s_m[e] = sigm(ml);
    }
    int w = t >> 6, lane = t & 63, lm = lane & 15, q = lane >> 4;
    const u16* Arow = A + (size_t)(w * 16 + lm) * 1152 + q * 8;
    floatx4 acc[3];
#pragma unroll
    for (int a = 0; a < 3; ++a) acc[a] = {0.f, 0.f, 0.f, 0.f};
    const u16* txn = txh + (size_t)n * HW_ * 128;
    const short8 zz = {0, 0, 0, 0, 0, 0, 0, 0};

    for (int kc = 0; kc < 18; ++kc) {
        int tap = kc >> 1, c0 = (kc & 1) * 64;
        short8 af[2];
#pragma unroll
        for (int ks = 0; ks < 2; ++ks)
            af[ks] = *reinterpret_cast<const short8*>(Arow + kc * 64 + ks * 32);
        __syncthreads();
#pragma unroll
        for (int i = 0; i < 2; ++i) {
            int id = i * 256 + t;
            if (id < 384) {
                int px = id >> 3, ch8 = id & 7;
                int ce = tap * 48 + px;
                int y0 = s_y0[ce], x0 = s_x0[ce];
                float wy = s_wy[ce], wx = s_wx[ce], m = s_m[ce];
                float w00 = (1.f - wy) * (1.f - wx) * m;
                float w01 = (1.f - wy) * wx * m;
                float w10 = wy * (1.f - wx) * m;
                float w11 = wy * wx * m;
                bool yv0 = (y0 >= 0) & (y0 < 96), yv1 = (y0 >= -1) & (y0 < 95);
                bool xv0 = (x0 >= 0) & (x0 < 96), xv1 = (x0 >= -1) & (x0 < 95);
                const u16* base = txn + (long)(y0 * 96 + x0) * 128 + c0 + ch8 * 8;
                short8 v00 = (yv0 && xv0) ? *reinterpret_cast<const short8*>(base) : zz;
                short8 v01 = (yv0 && xv1) ? *reinterpret_cast<const short8*>(base + 128) : zz;
                short8 v10 = (yv1 && xv0) ? *reinterpret_cast<const short8*>(base + 96 * 128) : zz;
                short8 v11 = (yv1 && xv1) ? *reinterpret_cast<const short8*>(base + 96 * 128 + 128) : zz;
                short8 vv;
#pragma unroll
                for (int j = 0; j < 8; ++j) {
                    float f = b2f(v00[j]) * w00 + b2f(v01[j]) * w01 +
                              b2f(v10[j]) * w10 + b2f(v11[j]) * w11;
                    vv[j] = f2b(f);
                }
                *reinterpret_cast<short8*>(&Bl[px][ch8 * 8]) = vv;
            }
        }
        __syncthreads();
#pragma unroll
        for (int ks = 0; ks < 2; ++ks)
#pragma unroll
            for (int nf = 0; nf < 3; ++nf) {
                short8 bv = *reinterpret_cast<const short8*>(&Bl[nf * 16 + lm][ks * 32 + q * 8]);
                acc[nf] = __builtin_amdgcn_mfma_f32_16x16x32_bf16(af[ks], bv, acc[nf], 0, 0, 0);
            }
    }
    int ocb = w * 16 + q * 4;
#pragma unroll
    for (int nf = 0; nf < 3; ++nf) {
        int px = px0 + nf * 16 + lm;
#pragma unroll
        for (int rr2 = 0; rr2 < 4; ++rr2) {
            int oc = ocb + rr2;
            out[((size_t)(n * CH_ + oc)) * HW_ + y * 96 + px] = acc[nf][rr2] + bias[oc];
        }
    }
}

// dual-instance dcn: grid 768
__global__ __launch_bounds__(256) void dcn_gemm2(const u16* __restrict__ X0, const u16* __restrict__ X1,
                                                 const float* __restrict__ om0, const float* __restrict__ om1,
                                                 const u16* __restrict__ A0, const u16* __restrict__ A1,
                                                 const float* __restrict__ b0, const float* __restrict__ b1,
                                                 float* __restrict__ o0, float* __restrict__ o1) {
    int inst = blockIdx.x / 384, r = blockIdx.x % 384;
    dcn_core(inst ? X1 : X0, inst ? om1 : om0, inst ? A1 : A0, inst ? b1 : b0, inst ? o1 : o0, r, threadIdx.x);
}

// ---------- fused NCF v3: 16 threads/px, 16 px/block, f1 held in fp32 regs ----------
// txh = concat(f2 [ch0..63], f1=tt [ch64..127]) NHWC bf16; out txh2 = concat(r, tt).
// Phase1: thread j computes full 64-ch dots for taps j, j+16, ... (3-4 taps).
// Phase2: softmax via 4-stage shfl within the 16-lane pixel group.
// Phase3: thread j accumulates channel slice j*4 over 49 taps.
__global__ __launch_bounds__(256, 4) void ncf2(const u16* __restrict__ in0, const u16* __restrict__ in1,
                                               u16* __restrict__ out0, u16* __restrict__ out1) {
    __shared__ float sc[16][52];
    int t = threadIdx.x;
    int inst = blockIdx.x / 1152, bb = blockIdx.x % 1152;
    const u16* txh = inst ? in1 : in0;
    u16* txh2 = inst ? out1 : out0;
    int lp = t >> 4, j = t & 15;
    int gpx = bb * 16 + lp;
    int n = gpx / HW_, p = gpx % HW_;
    int y = p / 96, x = p % 96;
    const u16* base = txh + (size_t)n * HW_ * 128;
    const u16* f1p = base + (size_t)p * 128 + 64;

    // f1 -> fp32 regs; __launch_bounds__(256,4) gives the allocator room (<=128 VGPR)
    float f1f[64];
#pragma unroll
    for (int c8 = 0; c8 < 8; ++c8) {
        short8 a = *reinterpret_cast<const short8*>(f1p + c8 * 8);
#pragma unroll
        for (int u = 0; u < 8; ++u) f1f[c8 * 8 + u] = b2f(a[u]);
    }
    // phase 1: full dots for taps j, j+16, ...
    for (int k = j; k < 49; k += 16) {
        int yy = y + (k / 7) * 2 - 6, xx = x + (k % 7) * 2 - 6;
        float s = 0.f;
        if (yy >= 0 && yy < 96 && xx >= 0 && xx < 96) {
            const u16* f2p = base + (size_t)(yy * 96 + xx) * 128;
#pragma unroll
            for (int c8 = 0; c8 < 8; ++c8) {
                short8 b = *reinterpret_cast<const short8*>(f2p + c8 * 8);
#pragma unroll
                for (int u = 0; u < 8; ++u) s += f1f[c8 * 8 + u] * b2f(b[u]);
            }
        }
        sc[lp][k] = s * 0.125f;
    }
    // phase 2: softmax over 49 (16-lane group reduce; masks 1/2/4/8 stay in-group)
    float mx = -1e30f;
    for (int k = j; k < 49; k += 16) mx = fmaxf(mx, sc[lp][k]);
#pragma unroll
    for (int m = 1; m <= 8; m <<= 1) mx = fmaxf(mx, __shfl_xor(mx, m, 64));
    float e[4];
    float sum = 0.f;
    int cnt = 0;
    for (int k = j; k < 49; k += 16) { e[cnt] = __expf(sc[lp][k] - mx); sum += e[cnt]; ++cnt; }
#pragma unroll
    for (int m = 1; m <= 8; m <<= 1) sum += __shfl_xor(sum, m, 64);
    float inv = 1.f / sum;
    cnt = 0;
    for (int k = j; k < 49; k += 16) sc[lp][k] = e[cnt++] * inv;
    __syncthreads();
    // phase 3: thread j accumulates channels j*4..j*4+3 over all 49 taps
    int ch0 = j * 4;
    float acc[4];
#pragma unroll
    for (int u = 0; u < 4; ++u) acc[u] = 0.f;
#pragma unroll
    for (int k = 0; k < 49; ++k) {
        int yy = y + (k / 7) * 2 - 6, xx = x + (k % 7) * 2 - 6;
        if (yy >= 0 && yy < 96 && xx >= 0 && xx < 96) {
            float a = sc[lp][k];
            bh4 f2 = *reinterpret_cast<const bh4*>(base + (size_t)(yy * 96 + xx) * 128 + ch0);
#pragma unroll
            for (int u = 0; u < 4; ++u) acc[u] += a * b2f(f2[u]);
        }
    }
    u16* obase = txh2 + (size_t)n * HW_ * 128 + (size_t)p * 128;
    bh4 ro;
#pragma unroll
    for (int u = 0; u < 4; ++u) ro[u] = f2b(acc[u]);
    *reinterpret_cast<bh4*>(obase + ch0) = ro;
    *reinterpret_cast<bh4*>(obase + 64 + ch0) =
        *reinterpret_cast<const bh4*>(f1p + ch0);   // tt passthrough
}

// ---------- dual GRU gate: inst a -> NHWC bf16, inst b -> NCHW f32 ----------
__global__ __launch_bounds__(256) void gate_dual(const float* __restrict__ dz_a, const float* __restrict__ dh_a,
                                                 const float* __restrict__ t_a, u16* __restrict__ dst_a,
                                                 const float* __restrict__ dz_b, const float* __restrict__ dh_b,
                                                 const float* __restrict__ t_b, float* __restrict__ dst_b) {
    int inst = blockIdx.x / 576, bb = blockIdx.x % 576;
    int id = bb * 256 + threadIdx.x;
    int c8 = id & 7;
    int pix = id >> 3;
    int n = pix / HW_, p = pix % HW_;
    const float* zpre = inst ? dz_b : dz_a;
    const float* hpre = inst ? dh_b : dh_a;
    const float* tt = inst ? t_b : t_a;
    if (!inst) {
        short8 vv;
#pragma unroll
        for (int j = 0; j < 8; ++j) {
            size_t idx = ((size_t)n * CH_ + c8 * 8 + j) * HW_ + p;
            float z = sigm(zpre[idx]);
            float xt = tanhf(hpre[idx]);
            vv[j] = f2b((1.f - z) * tt[idx] + z * xt);
        }
        *reinterpret_cast<short8*>(dst_a + (size_t)pix * CH_ + c8 * 8) = vv;
    } else {
#pragma unroll
        for (int j = 0; j < 8; ++j) {
            size_t idx = ((size_t)n * CH_ + c8 * 8 + j) * HW_ + p;
            float z = sigm(zpre[idx]);
            float xt = tanhf(hpre[idx]);
            dst_b[idx] = (1.f - z) * tt[idx] + z * xt;
        }
    }
}

extern "C" void kernel_launch(void* const* d_in, const int* in_sizes, int n_in,
                              void* d_out, int out_size, void* d_ws, size_t ws_size,
                              hipStream_t stream) {
    const float* x     = (const float*)d_in[0];
    const float* tpl   = (const float*)d_in[1];
    const float* w_in  = (const float*)d_in[2];
    const float* b_in  = (const float*)d_in[3];
    const float* w_out = (const float*)d_in[4];
    const float* b_out = (const float*)d_in[5];
    const float *pw[4], *pb[4], *pow_[4], *pob[4];
    for (int i = 0; i < 4; ++i) {           // 0=enh_z 1=enh_h 2=upd_z 3=upd_h
        pw[i]   = (const float*)d_in[6 + 4 * i];
        pb[i]   = (const float*)d_in[7 + 4 * i];
        pow_[i] = (const float*)d_in[8 + 4 * i];
        pob[i]  = (const float*)d_in[9 + 4 * i];
    }
    float* out_main = (float*)d_out;
    float* out_ntpl = out_main + (size_t)N_ * CIN_ * HW_;

    // ---- workspace (~55 MB; no aliasing) ----
    u16* Aws = (u16*)d_ws;
    u16* xT     = Aws + A_TOT;                        // (N,96,96,256) bf16
    u16* txh_a  = xT + (size_t)N_ * HW_ * CIN_;       // (N,96,96,128) bf16
    u16* txh_b  = txh_a + (size_t)N_ * HW_ * C2_;
    u16* txh2_a = txh_b + (size_t)N_ * HW_ * C2_;
    u16* txh2_b = txh2_a + (size_t)N_ * HW_ * C2_;
    u16* xeh    = txh2_b + (size_t)N_ * HW_ * C2_;    // (N,96,96,64) bf16
    float* fws = (float*)(xeh + (size_t)N_ * HW_ * CH_);
    size_t off = 0;
    float* xh   = fws + off; off += (size_t)N_ * CH_ * HW_;
    float* om_a = fws + off; off += (size_t)N_ * 27 * HW_;
    float* om_b = fws + off; off += (size_t)N_ * 27 * HW_;
    float* dz_a = fws + off; off += (size_t)N_ * CH_ * HW_;
    float* dz_b = fws + off; off += (size_t)N_ * CH_ * HW_;
    float* dh_a = fws + off; off += (size_t)N_ * CH_ * HW_;
    float* dh_b = fws + off; off += (size_t)N_ * CH_ * HW_;

    cvt_weights<<<(A_TOT + 255) / 256, 256, 0, stream>>>(
        w_in, w_out, pow_[0], pow_[1], pow_[2], pow_[3], pw[0], pw[1], pw[2], pw[3], Aws);
    to_nhwc<<<2304, 256, 0, stream>>>(x, xT, CIN_);
    conv_gemm<CIN_, 64><<<384, 256, 0, stream>>>(xT, Aws + A_IN_OFF, b_in, xh);

    // instance a = enh (x32=tpl, tt=xh), instance b = upd (x32=xh, tt=tpl)
    concat_dual<<<1152, 256, 0, stream>>>(tpl, xh, txh_a, txh_b);
    conv_gemm2<<<768, 256, 0, stream>>>(txh_a, txh_b,
        Aws + A_OFF_OFF + 0 * A_OFF_SZ, Aws + A_OFF_OFF + 2 * A_OFF_SZ, pob[0], pob[2], om_a, om_b);
    dcn_gemm2<<<768, 256, 0, stream>>>(txh_a, txh_b, om_a, om_b,
        Aws + A_DCN_OFF + 0 * A_DCN_SZ, Aws + A_DCN_OFF + 2 * A_DCN_SZ, pb[0], pb[2], dz_a, dz_b);
    ncf2<<<2304, 256, 0, stream>>>(txh_a, txh_b, txh2_a, txh2_b);
    conv_gemm2<<<768, 256, 0, stream>>>(txh2_a, txh2_b,
        Aws + A_OFF_OFF + 1 * A_OFF_SZ, Aws + A_OFF_OFF + 3 * A_OFF_SZ, pob[1], pob[3], om_a, om_b);
    dcn_gemm2<<<768, 256, 0, stream>>>(txh2_a, txh2_b, om_a, om_b,
        Aws + A_DCN_OFF + 1 * A_DCN_SZ, Aws + A_DCN_OFF + 3 * A_DCN_SZ, pb[1], pb[3], dh_a, dh_b);
    gate_dual<<<1152, 256, 0, stream>>>(dz_a, dh_a, xh, xeh, dz_b, dh_b, tpl, out_ntpl);

    conv_gemm<CH_, 256><<<1536, 256, 0, stream>>>(xeh, Aws + A_OUT_OFF, b_out, out_main);
}

// Round 12
// 343.966 us; speedup vs baseline: 12.7065x; 1.0591x over previous
//
#include <hip/hip_runtime.h>
#include <hip/hip_bf16.h>

typedef __hip_bfloat16 bf16;
typedef unsigned short u16;
typedef unsigned int u32;
typedef __attribute__((ext_vector_type(8))) short short8;
typedef __attribute__((ext_vector_type(4))) short bh4;
typedef __attribute__((ext_vector_type(4))) float floatx4;

constexpr int N_ = 2, H_ = 96, W_ = 96, HW_ = H_ * W_;
constexpr int CIN_ = 256, CH_ = 64, C2_ = 128;

__device__ __forceinline__ float sigm(float v) { return 1.0f / (1.0f + __expf(-v)); }
__device__ __forceinline__ short f2b(float v) { bf16 h = __float2bfloat16(v); return *reinterpret_cast<short*>(&h); }
__device__ __forceinline__ float b2f(short s) {
    union { u32 i; float f; } v; v.i = ((u32)(u16)s) << 16; return v.f;
}

// ---------- bf16 weight regions inside d_ws ----------
// conv A[m][k = tap*IC + ic];  dcn A[m][k = tap*128 + c]  (both tap-major)
constexpr int A_IN_OFF = 0,                         A_IN_SZ  = 64 * 2304;
constexpr int A_OUT_OFF = A_IN_OFF + A_IN_SZ,       A_OUT_SZ = 256 * 576;
constexpr int A_OFF_OFF = A_OUT_OFF + A_OUT_SZ,     A_OFF_SZ = 64 * 1152;   // 27 padded to 64
constexpr int A_DCN_OFF = A_OFF_OFF + 4 * A_OFF_SZ, A_DCN_SZ = 64 * 1152;
constexpr int A_TOT = A_DCN_OFF + 4 * A_DCN_SZ;     // 884736 shorts = 1.77 MB

__global__ __launch_bounds__(256) void cvt_weights(
        const float* __restrict__ w_in, const float* __restrict__ w_out,
        const float* __restrict__ ow0, const float* __restrict__ ow1,
        const float* __restrict__ ow2, const float* __restrict__ ow3,
        const float* __restrict__ w0, const float* __restrict__ w1,
        const float* __restrict__ w2, const float* __restrict__ w3,
        u16* __restrict__ dst) {
    int id = blockIdx.x * 256 + threadIdx.x;
    if (id >= A_TOT) return;
    float v;
    if (id < A_OUT_OFF) {
        int l = id; int m = l / 2304, k = l % 2304; int tap = k >> 8, ic = k & 255;
        v = w_in[m * 2304 + ic * 9 + tap];
    } else if (id < A_OFF_OFF) {
        int l = id - A_OUT_OFF; int m = l / 576, k = l % 576; int tap = k / 64, ic = k & 63;
        v = w_out[m * 576 + ic * 9 + tap];
    } else if (id < A_DCN_OFF) {
        int l = id - A_OFF_OFF; int i = l / A_OFF_SZ, l2 = l % A_OFF_SZ;
        int m = l2 / 1152, k = l2 % 1152; int tap = k >> 7, ic = k & 127;
        const float* s = (i == 0) ? ow0 : (i == 1) ? ow1 : (i == 2) ? ow2 : ow3;
        v = (m < 27) ? s[m * 1152 + ic * 9 + tap] : 0.f;
    } else {
        int l = id - A_DCN_OFF; int i = l / A_DCN_SZ, l2 = l % A_DCN_SZ;
        int m = l2 / 1152, k = l2 % 1152; int tap = k >> 7, c = k & 127;
        const float* s = (i == 0) ? w0 : (i == 1) ? w1 : (i == 2) ? w2 : w3;
        v = s[m * 1152 + c * 9 + tap];
    }
    short sb = f2b(v);
    dst[id] = *reinterpret_cast<u16*>(&sb);
}

// ---------- NCHW f32 -> NHWC bf16 ----------
__global__ __launch_bounds__(256) void to_nhwc(const float* __restrict__ src, u16* __restrict__ dst, int C) {
    int id = blockIdx.x * 256 + threadIdx.x;
    int c8n = C >> 3;
    if (id >= N_ * HW_ * c8n) return;
    int c8 = id % c8n;
    int pix = id / c8n;
    int n = pix / HW_, p = pix % HW_;
    const float* s = src + ((size_t)n * C + c8 * 8) * HW_ + p;
    short8 vv;
#pragma unroll
    for (int j = 0; j < 8; ++j) vv[j] = f2b(s[(size_t)j * HW_]);
    *reinterpret_cast<short8*>(dst + (size_t)pix * C + c8 * 8) = vv;
}

// ---------- dual concat: txh_a = concat(tpl, xh), txh_b = concat(xh, tpl) ----------
__global__ __launch_bounds__(256) void concat_dual(const float* __restrict__ tpl, const float* __restrict__ xh,
                                                   u16* __restrict__ ta, u16* __restrict__ tb) {
    int id = blockIdx.x * 256 + threadIdx.x;
    if (id >= N_ * HW_ * 16) return;
    int c8 = id & 15;
    int pix = id >> 4;
    int n = pix / HW_, p = pix % HW_;
    int c = c8 * 8;
    const float* s = (c < 64) ? tpl + ((size_t)n * 64 + c) * HW_ + p
                              : xh + ((size_t)n * 64 + (c - 64)) * HW_ + p;
    short8 vv;
#pragma unroll
    for (int j = 0; j < 8; ++j) vv[j] = f2b(s[(size_t)j * HW_]);
    *reinterpret_cast<short8*>(ta + (size_t)pix * 128 + c) = vv;
    *reinterpret_cast<short8*>(tb + (size_t)pix * 128 + ((c + 64) & 127)) = vv;
}

// ---------- core implicit-GEMM body (shared by single & dual kernels) ----------
template <int IC, int OCST>
__device__ __forceinline__ void conv_core(const u16* __restrict__ X,
                                          const u16* __restrict__ A,
                                          const float* __restrict__ bias,
                                          float* __restrict__ out,
                                          int r, int mt, int t) {
    constexpr int K = IC * 9;
    constexpr int ICC = IC / 64;
    __shared__ __align__(16) u16 Xl[3][50][72];
    int n = r / 192;
    int rr = r % 192;
    int y = rr >> 1, px0 = (rr & 1) * 48;
    int w = t >> 6, lane = t & 63, lm = lane & 15, q = lane >> 4;
    const u16* Arow = A + (size_t)(mt * 64 + w * 16 + lm) * K + q * 8;
    floatx4 acc[3];
#pragma unroll
    for (int a = 0; a < 3; ++a) acc[a] = {0.f, 0.f, 0.f, 0.f};
    const short8 zz = {0, 0, 0, 0, 0, 0, 0, 0};

    for (int icc = 0; icc < ICC; ++icc) {
        short8 af[9][2];
#pragma unroll
        for (int tap = 0; tap < 9; ++tap)
#pragma unroll
            for (int ks = 0; ks < 2; ++ks)
                af[tap][ks] = *reinterpret_cast<const short8*>(Arow + tap * IC + icc * 64 + ks * 32);
        __syncthreads();
#pragma unroll
        for (int it = 0; it < 5; ++it) {
            int id = it * 256 + t;
            if (id < 1200) {
                int ch8 = id & 7;
                int tmp = id >> 3;
                int pxl = tmp % 50, row = tmp / 50;
                int xg = px0 - 1 + pxl;
                int yg = y - 1 + row;
                bool vld = (yg >= 0) && (yg < 96) && (xg >= 0) && (xg < 96);
                short8 vv = zz;
                if (vld)
                    vv = *reinterpret_cast<const short8*>(
                        X + ((size_t)(n * HW_ + yg * 96 + xg)) * IC + icc * 64 + ch8 * 8);
                *reinterpret_cast<short8*>(&Xl[row][pxl][ch8 * 8]) = vv;
            }
        }
        __syncthreads();
#pragma unroll
        for (int tap = 0; tap < 9; ++tap) {
            int ky = tap / 3, kx = tap % 3;
#pragma unroll
            for (int ks = 0; ks < 2; ++ks) {
#pragma unroll
                for (int nf = 0; nf < 3; ++nf) {
                    short8 bv = *reinterpret_cast<const short8*>(&Xl[ky][nf * 16 + lm + kx][ks * 32 + q * 8]);
                    acc[nf] = __builtin_amdgcn_mfma_f32_16x16x32_bf16(af[tap][ks], bv, acc[nf], 0, 0, 0);
                }
            }
        }
    }
    int ocb = mt * 64 + w * 16 + q * 4;
#pragma unroll
    for (int nf = 0; nf < 3; ++nf) {
        int px = px0 + nf * 16 + lm;
#pragma unroll
        for (int rr2 = 0; rr2 < 4; ++rr2) {
            int oc = ocb + rr2;
            if (oc < OCST)
                out[((size_t)(n * OCST + oc)) * HW_ + y * 96 + px] = acc[nf][rr2] + bias[oc];
        }
    }
}

template <int IC, int OCST>
__global__ __launch_bounds__(256) void conv_gemm(const u16* __restrict__ X,
                                                 const u16* __restrict__ A,
                                                 const float* __restrict__ bias,
                                                 float* __restrict__ out) {
    conv_core<IC, OCST>(X, A, bias, out, blockIdx.x % 384, blockIdx.x / 384, threadIdx.x);
}

// dual-instance offset conv: grid 768, inst = gx/384
__global__ __launch_bounds__(256) void conv_gemm2(const u16* __restrict__ X0, const u16* __restrict__ X1,
                                                  const u16* __restrict__ A0, const u16* __restrict__ A1,
                                                  const float* __restrict__ b0, const float* __restrict__ b1,
                                                  float* __restrict__ o0, float* __restrict__ o1) {
    int inst = blockIdx.x / 384, r = blockIdx.x % 384;
    conv_core<C2_, 27>(inst ? X1 : X0, inst ? A1 : A0, inst ? b1 : b0, inst ? o1 : o0, r, 0, threadIdx.x);
}

// ---------- fused deformable conv core ----------
__device__ __forceinline__ void dcn_core(const u16* __restrict__ txh,
                                         const float* __restrict__ om,
                                         const u16* __restrict__ A,
                                         const float* __restrict__ bias,
                                         float* __restrict__ out,
                                         int r, int t) {
    __shared__ __align__(16) u16 Bl[48][72];
    __shared__ float s_wy[432], s_wx[432], s_m[432];
    __shared__ int s_y0[432], s_x0[432];
    int n = r / 192;
    int rr = r % 192;
    int y = rr >> 1, px0 = (rr & 1) * 48;
    for (int e = t; e < 432; e += 256) {
        int k9 = e / 48, xl = e % 48;
        int x = px0 + xl;
        const float* ob = om + (size_t)n * 27 * HW_ + y * 96 + x;
        float dy = ob[(size_t)k9 * HW_];
        float dx = ob[(size_t)(9 + k9) * HW_];
        float ml = ob[(size_t)(18 + k9) * HW_];
        float py = (float)y + (float)(k9 / 3 - 1) + dy;
        float px = (float)x + (float)(k9 % 3 - 1) + dx;
        float fy = floorf(py), fx = floorf(px);
        s_y0[e] = (int)fy; s_x0[e] = (int)fx;
        s_wy[e] = py - fy; s_wx[e] = px - fx; s_m[e] = sigm(ml);
    }
    int w = t >> 6, lane = t & 63, lm = lane & 15, q = lane >> 4;
    const u16* Arow = A + (size_t)(w * 16 + lm) * 1152 + q * 8;
    floatx4 acc[3];
#pragma unroll
    for (int a = 0; a < 3; ++a) acc[a] = {0.f, 0.f, 0.f, 0.f};
    const u16* txn = txh + (size_t)n * HW_ * 128;
    const short8 zz = {0, 0, 0, 0, 0, 0, 0, 0};

    for (int kc = 0; kc < 18; ++kc) {
        int tap = kc >> 1, c0 = (kc & 1) * 64;
        short8 af[2];
#pragma unroll
        for (int ks = 0; ks < 2; ++ks)
            af[ks] = *reinterpret_cast<const short8*>(Arow + kc * 64 + ks * 32);
        __syncthreads();
#pragma unroll
        for (int i = 0; i < 2; ++i) {
            int id = i * 256 + t;
            if (id < 384) {
                int px = id >> 3, ch8 = id & 7;
                int ce = tap * 48 + px;
                int y0 = s_y0[ce], x0 = s_x0[ce];
                float wy = s_wy[ce], wx = s_wx[ce], m = s_m[ce];
                float w00 = (1.f - wy) * (1.f - wx) * m;
                float w01 = (1.f - wy) * wx * m;
                float w10 = wy * (1.f - wx) * m;
                float w11 = wy * wx * m;
                bool yv0 = (y0 >= 0) & (y0 < 96), yv1 = (y0 >= -1) & (y0 < 95);
                bool xv0 = (x0 >= 0) & (x0 < 96), xv1 = (x0 >= -1) & (x0 < 95);
                const u16* base = txn + (long)(y0 * 96 + x0) * 128 + c0 + ch8 * 8;
                short8 v00 = (yv0 && xv0) ? *reinterpret_cast<const short8*>(base) : zz;
                short8 v01 = (yv0 && xv1) ? *reinterpret_cast<const short8*>(base + 128) : zz;
                short8 v10 = (yv1 && xv0) ? *reinterpret_cast<const short8*>(base + 96 * 128) : zz;
                short8 v11 = (yv1 && xv1) ? *reinterpret_cast<const short8*>(base + 96 * 128 + 128) : zz;
                short8 vv;
#pragma unroll
                for (int j = 0; j < 8; ++j) {
                    float f = b2f(v00[j]) * w00 + b2f(v01[j]) * w01 +
                              b2f(v10[j]) * w10 + b2f(v11[j]) * w11;
                    vv[j] = f2b(f);
                }
                *reinterpret_cast<short8*>(&Bl[px][ch8 * 8]) = vv;
            }
        }
        __syncthreads();
#pragma unroll
        for (int ks = 0; ks < 2; ++ks)
#pragma unroll
            for (int nf = 0; nf < 3; ++nf) {
                short8 bv = *reinterpret_cast<const short8*>(&Bl[nf * 16 + lm][ks * 32 + q * 8]);
                acc[nf] = __builtin_amdgcn_mfma_f32_16x16x32_bf16(af[ks], bv, acc[nf], 0, 0, 0);
            }
    }
    int ocb = w * 16 + q * 4;
#pragma unroll
    for (int nf = 0; nf < 3; ++nf) {
        int px = px0 + nf * 16 + lm;
#pragma unroll
        for (int rr2 = 0; rr2 < 4; ++rr2) {
            int oc = ocb + rr2;
            out[((size_t)(n * CH_ + oc)) * HW_ + y * 96 + px] = acc[nf][rr2] + bias[oc];
        }
    }
}

// dual-instance dcn: grid 768
__global__ __launch_bounds__(256) void dcn_gemm2(const u16* __restrict__ X0, const u16* __restrict__ X1,
                                                 const float* __restrict__ om0, const float* __restrict__ om1,
                                                 const u16* __restrict__ A0, const u16* __restrict__ A1,
                                                 const float* __restrict__ b0, const float* __restrict__ b1,
                                                 float* __restrict__ o0, float* __restrict__ o1) {
    int inst = blockIdx.x / 384, r = blockIdx.x % 384;
    dcn_core(inst ? X1 : X0, inst ? om1 : om0, inst ? A1 : A0, inst ? b1 : b0, inst ? o1 : o0, r, threadIdx.x);
}

// ---------- fused NCF v4: LDS-staged window ----------
// Block = 16-px strip. Stage f2 window [7 rows x 28 px x 64 ch] + f1 strip into LDS once
// (coalesced), then corr/softmax/sample run entirely from LDS. Out-of-bounds staged as 0
// == reference's zero-padding (corr contribution 0, sample contribution 0).
__global__ __launch_bounds__(256, 4) void ncf2(const u16* __restrict__ in0, const u16* __restrict__ in1,
                                               u16* __restrict__ out0, u16* __restrict__ out1) {
    __shared__ __align__(16) u16 sF2[7][28][72];   // pitch 72 shorts = 144 B
    __shared__ __align__(16) u16 sF1[16][72];
    __shared__ float sc[16][52];
    int t = threadIdx.x;
    int inst = blockIdx.x / 1152, bb = blockIdx.x % 1152;
    const u16* txh = inst ? in1 : in0;
    u16* txh2 = inst ? out1 : out0;
    int n = bb / 576, rem = bb % 576;
    int y = rem / 6, x0 = (rem % 6) * 16;
    const u16* base = txh + (size_t)n * HW_ * 128;
    const short8 zz = {0, 0, 0, 0, 0, 0, 0, 0};

    // stage f2 window: 7*28*8 = 1568 short8s
    for (int id = t; id < 1568; id += 256) {
        int ch8 = id & 7;
        int tmp = id >> 3;
        int px = tmp % 28, row = tmp / 28;
        int yy = y + row * 2 - 6;
        int xg = x0 - 6 + px;
        short8 vv = zz;
        if (yy >= 0 && yy < 96 && xg >= 0 && xg < 96)
            vv = *reinterpret_cast<const short8*>(base + (size_t)(yy * 96 + xg) * 128 + ch8 * 8);
        *reinterpret_cast<short8*>(&sF2[row][px][ch8 * 8]) = vv;
    }
    // stage f1 strip (ch 64..127 of each pixel)
    if (t < 128) {
        int ch8 = t & 7, lp0 = t >> 3;
        short8 vv = *reinterpret_cast<const short8*>(base + (size_t)(y * 96 + x0 + lp0) * 128 + 64 + ch8 * 8);
        *reinterpret_cast<short8*>(&sF1[lp0][ch8 * 8]) = vv;
    }
    __syncthreads();

    int lp = t >> 4, j = t & 15;
    // phase 1: thread j -> taps j, j+16, j+32, j+48 (full 64-ch dot from LDS, no branches)
    for (int k = j; k < 49; k += 16) {
        int ky = k / 7, kx = k % 7;
        const u16* f2p = &sF2[ky][lp + 2 * kx][0];
        const u16* f1p = &sF1[lp][0];
        float s = 0.f;
#pragma unroll
        for (int c8 = 0; c8 < 8; ++c8) {
            short8 a = *reinterpret_cast<const short8*>(f1p + c8 * 8);
            short8 b = *reinterpret_cast<const short8*>(f2p + c8 * 8);
#pragma unroll
            for (int u = 0; u < 8; ++u) s += b2f(a[u]) * b2f(b[u]);
        }
        sc[lp][k] = s * 0.125f;
    }
    // phase 2: softmax over 49 (16-lane group shfl reduce; each thread touches only its taps)
    float mx = -1e30f;
    for (int k = j; k < 49; k += 16) mx = fmaxf(mx, sc[lp][k]);
#pragma unroll
    for (int m = 1; m <= 8; m <<= 1) mx = fmaxf(mx, __shfl_xor(mx, m, 64));
    float e[4];
    float sum = 0.f;
    int cnt = 0;
    for (int k = j; k < 49; k += 16) { e[cnt] = __expf(sc[lp][k] - mx); sum += e[cnt]; ++cnt; }
#pragma unroll
    for (int m = 1; m <= 8; m <<= 1) sum += __shfl_xor(sum, m, 64);
    float inv = 1.f / sum;
    cnt = 0;
    for (int k = j; k < 49; k += 16) sc[lp][k] = e[cnt++] * inv;
    __syncthreads();
    // phase 3: thread j accumulates channels j*4..j*4+3 over all 49 taps (LDS reads)
    int ch0 = j * 4;
    float acc[4];
#pragma unroll
    for (int u = 0; u < 4; ++u) acc[u] = 0.f;
#pragma unroll
    for (int k = 0; k < 49; ++k) {
        int ky = k / 7, kx = k % 7;
        float a = sc[lp][k];
        bh4 f2 = *reinterpret_cast<const bh4*>(&sF2[ky][lp + 2 * kx][ch0]);
#pragma unroll
        for (int u = 0; u < 4; ++u) acc[u] += a * b2f(f2[u]);
    }
    int p = y * 96 + x0 + lp;
    u16* obase = txh2 + (size_t)n * HW_ * 128 + (size_t)p * 128;
    bh4 ro;
#pragma unroll
    for (int u = 0; u < 4; ++u) ro[u] = f2b(acc[u]);
    *reinterpret_cast<bh4*>(obase + ch0) = ro;
    *reinterpret_cast<bh4*>(obase + 64 + ch0) =
        *reinterpret_cast<const bh4*>(&sF1[lp][ch0]);   // tt passthrough
}

// ---------- dual GRU gate: inst a -> NHWC bf16, inst b -> NCHW f32 ----------
__global__ __launch_bounds__(256) void gate_dual(const float* __restrict__ dz_a, const float* __restrict__ dh_a,
                                                 const float* __restrict__ t_a, u16* __restrict__ dst_a,
                                                 const float* __restrict__ dz_b, const float* __restrict__ dh_b,
                                                 const float* __restrict__ t_b, float* __restrict__ dst_b) {
    int inst = blockIdx.x / 576, bb = blockIdx.x % 576;
    int id = bb * 256 + threadIdx.x;
    int c8 = id & 7;
    int pix = id >> 3;
    int n = pix / HW_, p = pix % HW_;
    const float* zpre = inst ? dz_b : dz_a;
    const float* hpre = inst ? dh_b : dh_a;
    const float* tt = inst ? t_b : t_a;
    if (!inst) {
        short8 vv;
#pragma unroll
        for (int j = 0; j < 8; ++j) {
            size_t idx = ((size_t)n * CH_ + c8 * 8 + j) * HW_ + p;
            float z = sigm(zpre[idx]);
            float xt = tanhf(hpre[idx]);
            vv[j] = f2b((1.f - z) * tt[idx] + z * xt);
        }
        *reinterpret_cast<short8*>(dst_a + (size_t)pix * CH_ + c8 * 8) = vv;
    } else {
#pragma unroll
        for (int j = 0; j < 8; ++j) {
            size_t idx = ((size_t)n * CH_ + c8 * 8 + j) * HW_ + p;
            float z = sigm(zpre[idx]);
            float xt = tanhf(hpre[idx]);
            dst_b[idx] = (1.f - z) * tt[idx] + z * xt;
        }
    }
}

extern "C" void kernel_launch(void* const* d_in, const int* in_sizes, int n_in,
                              void* d_out, int out_size, void* d_ws, size_t ws_size,
                              hipStream_t stream) {
    const float* x     = (const float*)d_in[0];
    const float* tpl   = (const float*)d_in[1];
    const float* w_in  = (const float*)d_in[2];
    const float* b_in  = (const float*)d_in[3];
    const float* w_out = (const float*)d_in[4];
    const float* b_out = (const float*)d_in[5];
    const float *pw[4], *pb[4], *pow_[4], *pob[4];
    for (int i = 0; i < 4; ++i) {           // 0=enh_z 1=enh_h 2=upd_z 3=upd_h
        pw[i]   = (const float*)d_in[6 + 4 * i];
        pb[i]   = (const float*)d_in[7 + 4 * i];
        pow_[i] = (const float*)d_in[8 + 4 * i];
        pob[i]  = (const float*)d_in[9 + 4 * i];
    }
    float* out_main = (float*)d_out;
    float* out_ntpl = out_main + (size_t)N_ * CIN_ * HW_;

    // ---- workspace (~55 MB; no aliasing) ----
    u16* Aws = (u16*)d_ws;
    u16* xT     = Aws + A_TOT;                        // (N,96,96,256) bf16
    u16* txh_a  = xT + (size_t)N_ * HW_ * CIN_;       // (N,96,96,128) bf16
    u16* txh_b  = txh_a + (size_t)N_ * HW_ * C2_;
    u16* txh2_a = txh_b + (size_t)N_ * HW_ * C2_;
    u16* txh2_b = txh2_a + (size_t)N_ * HW_ * C2_;
    u16* xeh    = txh2_b + (size_t)N_ * HW_ * C2_;    // (N,96,96,64) bf16
    float* fws = (float*)(xeh + (size_t)N_ * HW_ * CH_);
    size_t off = 0;
    float* xh   = fws + off; off += (size_t)N_ * CH_ * HW_;
    float* om_a = fws + off; off += (size_t)N_ * 27 * HW_;
    float* om_b = fws + off; off += (size_t)N_ * 27 * HW_;
    float* dz_a = fws + off; off += (size_t)N_ * CH_ * HW_;
    float* dz_b = fws + off; off += (size_t)N_ * CH_ * HW_;
    float* dh_a = fws + off; off += (size_t)N_ * CH_ * HW_;
    float* dh_b = fws + off; off += (size_t)N_ * CH_ * HW_;

    cvt_weights<<<(A_TOT + 255) / 256, 256, 0, stream>>>(
        w_in, w_out, pow_[0], pow_[1], pow_[2], pow_[3], pw[0], pw[1], pw[2], pw[3], Aws);
    to_nhwc<<<2304, 256, 0, stream>>>(x, xT, CIN_);
    conv_gemm<CIN_, 64><<<384, 256, 0, stream>>>(xT, Aws + A_IN_OFF, b_in, xh);

    // instance a = enh (x32=tpl, tt=xh), instance b = upd (x32=xh, tt=tpl)
    concat_dual<<<1152, 256, 0, stream>>>(tpl, xh, txh_a, txh_b);
    conv_gemm2<<<768, 256, 0, stream>>>(txh_a, txh_b,
        Aws + A_OFF_OFF + 0 * A_OFF_SZ, Aws + A_OFF_OFF + 2 * A_OFF_SZ, pob[0], pob[2], om_a, om_b);
    dcn_gemm2<<<768, 256, 0, stream>>>(txh_a, txh_b, om_a, om_b,
        Aws + A_DCN_OFF + 0 * A_DCN_SZ, Aws + A_DCN_OFF + 2 * A_DCN_SZ, pb[0], pb[2], dz_a, dz_b);
    ncf2<<<2304, 256, 0, stream>>>(txh_a, txh_b, txh2_a, txh2_b);
    conv_gemm2<<<768, 256, 0, stream>>>(txh2_a, txh2_b,
        Aws + A_OFF_OFF + 1 * A_OFF_SZ, Aws + A_OFF_OFF + 3 * A_OFF_SZ, pob[1], pob[3], om_a, om_b);
    dcn_gemm2<<<768, 256, 0, stream>>>(txh2_a, txh2_b, om_a, om_b,
        Aws + A_DCN_OFF + 1 * A_DCN_SZ, Aws + A_DCN_OFF + 3 * A_DCN_SZ, pb[1], pb[3], dh_a, dh_b);
    gate_dual<<<1152, 256, 0, stream>>>(dz_a, dh_a, xh, xeh, dz_b, dh_b, tpl, out_ntpl);

    conv_gemm<CH_, 256><<<1536, 256, 0, stream>>>(xeh, Aws + A_OUT_OFF, b_out, out_main);
}